// Round 6
// baseline (372.411 us; speedup 1.0000x reference)
//
#include <hip/hip_runtime.h>
#include <hip/hip_bf16.h>
#include <math.h>

namespace {
constexpr int NN  = 16384;
constexpr int NE  = 262144;
constexpr int DIM = 40;

constexpr float INV_SQRT3   = 0.5773502691896258f;
constexpr float A_PATH      = 0.2041241452319315f;      // 1/sqrt(24)
constexpr float INV_SQRT_NB = 0.31622776601683794f;     // 1/sqrt(10)
constexpr float H_SCALE     = 0.25f;                    // 1/sqrt(16)
constexpr float QSC_S       = 0.25f;
constexpr float QV_S        = 0.35355339059327373f;
constexpr float D00_S       = 1.0f / (16.0f * 1.4142135623730951f);
constexpr float D11_S       = 1.0f / (8.0f * 1.7320508075688772f * 1.4142135623730951f);

constexpr int BKP = 392;  // padded k-stride for Bt (bf16)
}

typedef __attribute__((ext_vector_type(8))) short bf16x8;
typedef __attribute__((ext_vector_type(4))) float f32x4;

static __device__ inline short f2bf(float x) {
  __hip_bfloat16 h = __float2bfloat16(x);
  return __builtin_bit_cast(short, h);
}
static __device__ inline float bf2f(short b) {
  unsigned u = ((unsigned)(unsigned short)b) << 16;
  return __builtin_bit_cast(float, u);
}

// ---------------------------------------------------------------------------
// node_qd: per-node qd0[16] (+D00_S) and qdv[8][3] (+D11_S), stored as 40
// floats: [0..15]=qd0, [16+j*3+c]=qdv[j][c]. 1 thread/node (tiny kernel).
// ---------------------------------------------------------------------------
__global__ __launch_bounds__(256) void node_qd_kernel(
    const float* __restrict__ f,
    const float* __restrict__ Wq0, const float* __restrict__ Wq1,
    const float* __restrict__ Wd00, const float* __restrict__ Wd11,
    float* __restrict__ qd)
{
  const int n = blockIdx.x * 256 + threadIdx.x;

  float fs[16], fv[8][3];
  {
    const float4* fn4 = reinterpret_cast<const float4*>(f + (size_t)n * DIM);
#pragma unroll
    for (int i = 0; i < 10; i++) {
      float4 t = fn4[i];
      int base = i * 4;
#pragma unroll
      for (int k = 0; k < 4; k++) {
        float v = (k == 0) ? t.x : (k == 1) ? t.y : (k == 2) ? t.z : t.w;
        int idx = base + k;
        if (idx < 16) fs[idx] = v;
        else { int r = idx - 16; fv[r / 3][r % 3] = v; }
      }
    }
  }

  float out[40];
  {
    float qsc[16];
#pragma unroll
    for (int o = 0; o < 16; o++) {
      float a = 0.f;
#pragma unroll
      for (int i = 0; i < 16; i++) a += fs[i] * Wq0[i * 16 + o];
      qsc[o] = a * QSC_S;
    }
#pragma unroll
    for (int j = 0; j < 16; j++) {
      float a = 0.f;
#pragma unroll
      for (int i = 0; i < 16; i++) a += qsc[i] * Wd00[i * 16 + j];
      out[j] = a * D00_S;
    }
  }
  {
    float qv[8][3];
#pragma unroll
    for (int o = 0; o < 8; o++)
#pragma unroll
      for (int c = 0; c < 3; c++) {
        float a = 0.f;
#pragma unroll
        for (int i = 0; i < 8; i++) a += fv[i][c] * Wq1[i * 8 + o];
        qv[o][c] = a * QV_S;
      }
#pragma unroll
    for (int j = 0; j < 8; j++)
#pragma unroll
      for (int c = 0; c < 3; c++) {
        float a = 0.f;
#pragma unroll
        for (int i = 0; i < 8; i++) a += qv[i][c] * Wd11[i * 8 + j];
        out[16 + j * 3 + c] = a * D11_S;
      }
  }

  float4* op = reinterpret_cast<float4*>(qd + (size_t)n * DIM);
#pragma unroll
  for (int i = 0; i < 10; i++)
    op[i] = make_float4(out[4 * i], out[4 * i + 1], out[4 * i + 2], out[4 * i + 3]);
}

// ---------------------------------------------------------------------------
// qq_kernel: one thread per (n,r). Same math as the round-2-verified
// node_qq inner body for a single r (scales identical; A_PATH on write).
// ---------------------------------------------------------------------------
__global__ __launch_bounds__(256, 3) void qq_kernel(
    const float* __restrict__ f,
    const float* __restrict__ qd,
    const float* __restrict__ w2k,
    float* __restrict__ qq)
{
  const int gid = blockIdx.x * 256 + threadIdx.x;   // NN*16 threads
  const int n = gid >> 4, r = gid & 15;

  float fs[16], fv[8][3];
  {
    const float4* fn4 = reinterpret_cast<const float4*>(f + (size_t)n * DIM);
#pragma unroll
    for (int i = 0; i < 10; i++) {
      float4 t = fn4[i];
      int base = i * 4;
#pragma unroll
      for (int k = 0; k < 4; k++) {
        float v = (k == 0) ? t.x : (k == 1) ? t.y : (k == 2) ? t.z : t.w;
        int idx = base + k;
        if (idx < 16) fs[idx] = v;
        else { int rr = idx - 16; fv[rr / 3][rr % 3] = v; }
      }
    }
  }
  float qd0[16], qdv[8][3];
  {
    const float4* qp = reinterpret_cast<const float4*>(qd + (size_t)n * DIM);
#pragma unroll
    for (int i = 0; i < 10; i++) {
      float4 t = qp[i];
      int base = i * 4;
#pragma unroll
      for (int k = 0; k < 4; k++) {
        float v = (k == 0) ? t.x : (k == 1) ? t.y : (k == 2) ? t.z : t.w;
        int idx = base + k;
        if (idx < 16) qd0[idx] = v;
        else { int rr = idx - 16; qdv[rr / 3][rr % 3] = v; }
      }
    }
  }

  const float4* __restrict__ w4 = reinterpret_cast<const float4*>(w2k + (size_t)r * 576);
  float q0 = 0.f, qc0 = 0.f, qc1 = 0.f, qc2 = 0.f;

  // w00 block [0,256)
#pragma unroll
  for (int i = 0; i < 16; i++) {
    float t = 0.f;
#pragma unroll
    for (int o4 = 0; o4 < 4; o4++) {
      float4 w = w4[i * 4 + o4];
      t += qd0[o4 * 4 + 0] * w.x + qd0[o4 * 4 + 1] * w.y
         + qd0[o4 * 4 + 2] * w.z + qd0[o4 * 4 + 3] * w.w;
    }
    q0 += fs[i] * t;
  }
  // w11 block [256,384)
#pragma unroll
  for (int i = 0; i < 8; i++) {
    float t = 0.f;
#pragma unroll
    for (int o4 = 0; o4 < 4; o4++) {
      float4 w = w4[64 + i * 4 + o4];
      t += qd0[o4 * 4 + 0] * w.x + qd0[o4 * 4 + 1] * w.y
         + qd0[o4 * 4 + 2] * w.z + qd0[o4 * 4 + 3] * w.w;
    }
    t *= INV_SQRT3;
    qc0 += fv[i][0] * t; qc1 += fv[i][1] * t; qc2 += fv[i][2] * t;
  }
  // w01 block [384,512)
#pragma unroll
  for (int i = 0; i < 16; i++) {
    float t0 = 0.f, t1 = 0.f, t2 = 0.f;
#pragma unroll
    for (int o4 = 0; o4 < 2; o4++) {
      float4 w = w4[96 + i * 2 + o4];
#pragma unroll
      for (int k = 0; k < 4; k++) {
        float wk = (k == 0) ? w.x : (k == 1) ? w.y : (k == 2) ? w.z : w.w;
        int o = o4 * 4 + k;
        t0 += qdv[o][0] * wk; t1 += qdv[o][1] * wk; t2 += qdv[o][2] * wk;
      }
    }
    qc0 += fs[i] * t0; qc1 += fs[i] * t1; qc2 += fs[i] * t2;
  }
  // w10 block [512,576)
#pragma unroll
  for (int i = 0; i < 8; i++) {
    float t0 = 0.f, t1 = 0.f, t2 = 0.f;
#pragma unroll
    for (int o4 = 0; o4 < 2; o4++) {
      float4 w = w4[128 + i * 2 + o4];
#pragma unroll
      for (int k = 0; k < 4; k++) {
        float wk = (k == 0) ? w.x : (k == 1) ? w.y : (k == 2) ? w.z : w.w;
        int o = o4 * 4 + k;
        t0 += qdv[o][0] * wk; t1 += qdv[o][1] * wk; t2 += qdv[o][2] * wk;
      }
    }
    q0 += fv[i][0] * t0 + fv[i][1] * t1 + fv[i][2] * t2;
  }

  reinterpret_cast<float4*>(qq)[gid] =
      make_float4(A_PATH * q0, A_PATH * qc0, A_PATH * qc1, A_PATH * qc2);
}

// ---------------------------------------------------------------------------
// K-pass (round-2 verified)
// ---------------------------------------------------------------------------
__global__ __launch_bounds__(256) void k_pass_kernel(
    const int*   __restrict__ ei,
    const float* __restrict__ elen,
    const float* __restrict__ esh,
    const float* __restrict__ emb,
    const float* __restrict__ w1,
    const float* __restrict__ qq,
    float* __restrict__ expv,
    float* __restrict__ z)
{
  const int e = blockIdx.x * 256 + threadIdx.x;
  const int dst = ei[NE + e];

  float el[10];
  const float2* e2 = reinterpret_cast<const float2*>(emb + (size_t)e * 10);
#pragma unroll
  for (int b = 0; b < 5; b++) { float2 t = e2[b]; el[2 * b] = t.x; el[2 * b + 1] = t.y; }

  float h[16];
#pragma unroll
  for (int j = 0; j < 16; j++) {
    float a = 0.f;
#pragma unroll
    for (int b = 0; b < 10; b++) a += el[b] * w1[b * 16 + j];
    a *= INV_SQRT_NB;
    float sig = 1.0f / (1.0f + __expf(-a));
    h[j] = a * sig * H_SCALE;
  }

  float4 sh4 = reinterpret_cast<const float4*>(esh)[e];
  const float4* q4 = reinterpret_cast<const float4*>(qq + (size_t)dst * 64);
  float s = 0.f;
#pragma unroll
  for (int r = 0; r < 16; r++) {
    float4 qv = q4[r];
    s += h[r] * (sh4.x * qv.x + sh4.y * qv.y + sh4.z * qv.z + sh4.w * qv.w);
  }

  float len = elen[e];
  float x = 10.0f * (1.0f - len * (1.0f / 1.3f));
  float cut = (x > 0.f) ? __expf(-1.0f / x) : 0.f;
  float ev = cut * __expf(s);
  expv[e] = ev;
  atomicAdd(&z[dst], ev);
}

// ---------------------------------------------------------------------------
// Counting sort by dst
// ---------------------------------------------------------------------------
__global__ __launch_bounds__(256) void hist_kernel(const int* __restrict__ ei,
                                                   int* __restrict__ cnt)
{
  const int e = blockIdx.x * 256 + threadIdx.x;
  atomicAdd(&cnt[ei[NE + e]], 1);
}

__global__ __launch_bounds__(1024) void scan_kernel(const int* __restrict__ cnt,
                                                    int* __restrict__ start,
                                                    int* __restrict__ off)
{
  __shared__ int part[1024];
  const int t = threadIdx.x;
  const int base = t * 16;
  int loc[16];
  int s = 0;
#pragma unroll
  for (int k = 0; k < 16; k++) { loc[k] = s; s += cnt[base + k]; }
  part[t] = s;
  __syncthreads();
  for (int d = 1; d < 1024; d <<= 1) {
    int v = (t >= d) ? part[t - d] : 0;
    __syncthreads();
    part[t] += v;
    __syncthreads();
  }
  int excl = (t == 0) ? 0 : part[t - 1];
#pragma unroll
  for (int k = 0; k < 16; k++) {
    int v = excl + loc[k];
    start[base + k] = v;
    off[base + k] = v;
  }
}

__global__ __launch_bounds__(256) void scatter_kernel(const int* __restrict__ ei,
                                                      int* __restrict__ off,
                                                      int* __restrict__ eperm)
{
  const int e = blockIdx.x * 256 + threadIdx.x;
  int rk = atomicAdd(&off[ei[NE + e]], 1);
  eperm[rk] = e;
}

// ---------------------------------------------------------------------------
// prep_B: hi/lo bf16 split planes. Bt[col][kp] hi; Bt[32+col][kp] lo.
// ---------------------------------------------------------------------------
__global__ __launch_bounds__(256) void prep_B_kernel(const float* __restrict__ w2v,
                                                     unsigned short* __restrict__ Bt)
{
  int t = blockIdx.x * 256 + threadIdx.x;   // 32*BKP threads
  int col = t / BKP, kp = t % BKP;
  float val = 0.f;
  if (kp < 384 && col < 24) {
    if (kp < 256) {
      int r = kp >> 4, i = kp & 15;
      if (col < 16) val = A_PATH * w2v[r * 576 + i * 16 + col];
      else          val = A_PATH * w2v[r * 576 + 384 + i * 8 + (col - 16)];
    } else {
      int k2 = kp - 256; int r = k2 >> 3, i = k2 & 7;
      if (col < 16) val = A_PATH * INV_SQRT3 * w2v[r * 576 + 256 + i * 16 + col];
      else          val = A_PATH * w2v[r * 576 + 512 + i * 8 + (col - 16)];
    }
  }
  short hi = f2bf(val);
  short lo = f2bf(val - bf2f(hi));
  Bt[t] = (unsigned short)hi;
  Bt[32 * BKP + t] = (unsigned short)lo;
}

// ---------------------------------------------------------------------------
// V-pass via MFMA, split-precision (round-5 verified, unchanged)
// ---------------------------------------------------------------------------
__global__ __launch_bounds__(256) void v_mfma_kernel(
    const int*   __restrict__ ei,
    const float* __restrict__ esh,
    const float* __restrict__ emb,
    const float* __restrict__ w1,      // fcv_w1
    const float* __restrict__ f,
    const float* __restrict__ expv,
    const float* __restrict__ z,
    const int*   __restrict__ eperm,
    const unsigned short* __restrict__ Bt,
    float* __restrict__ vbuf)
{
  __shared__ float h_s[64][17];
  __shared__ float fsT[16][65];
  __shared__ float fvT[24][65];
  __shared__ float scal[64][5];
  __shared__ __attribute__((aligned(16))) unsigned short BtL[64][BKP];
  __shared__ float rows[64][41];

  const int tid  = threadIdx.x;
  const int base = blockIdx.x * 64;

  // stage Bt (hi+lo planes) -> LDS (50 KB)
  {
    const unsigned* sp = reinterpret_cast<const unsigned*>(Bt);
    unsigned* dp = reinterpret_cast<unsigned*>(&BtL[0][0]);
    for (int i = tid; i < 64 * BKP / 2; i += 256) dp[i] = sp[i];
  }

  const int m = tid & 63;
  const int q = tid >> 6;
  const int e = eperm[base + m];

  if (q == 0) {
    int dn = ei[NE + e];
    float4 sh4 = reinterpret_cast<const float4*>(esh)[e];
    float zz = z[dn]; zz = (zz == 0.f) ? 1.f : zz;
    float ev = expv[e];
    float wgt = sqrtf(fmaxf(ev / zz, 0.f));
    scal[m][0] = sh4.x; scal[m][1] = sh4.y; scal[m][2] = sh4.z; scal[m][3] = sh4.w;
    scal[m][4] = wgt;
  } else if (q == 3) {
    int sn = ei[e];
    const float4* f4 = reinterpret_cast<const float4*>(f + (size_t)sn * DIM);
    float v[40];
#pragma unroll
    for (int i = 0; i < 10; i++) {
      float4 t = f4[i];
      v[4 * i] = t.x; v[4 * i + 1] = t.y; v[4 * i + 2] = t.z; v[4 * i + 3] = t.w;
    }
#pragma unroll
    for (int i = 0; i < 16; i++) fsT[i][m] = v[i];
#pragma unroll
    for (int k = 0; k < 24; k++) fvT[(k % 3) * 8 + (k / 3)][m] = v[16 + k];  // fvT[c*8+i]
  } else {
    // q=1: h[0..7], q=2: h[8..15]
    float el[10];
    const float2* e2 = reinterpret_cast<const float2*>(emb + (size_t)e * 10);
#pragma unroll
    for (int b = 0; b < 5; b++) { float2 t = e2[b]; el[2 * b] = t.x; el[2 * b + 1] = t.y; }
    const int j0 = (q == 1) ? 0 : 8;
#pragma unroll
    for (int jj = 0; jj < 8; jj++) {
      int j = j0 + jj;
      float a = 0.f;
#pragma unroll
      for (int b = 0; b < 10; b++) a += el[b] * w1[b * 16 + j];
      a *= INV_SQRT_NB;
      float sig = 1.0f / (1.0f + __expf(-a));
      h_s[m][j] = a * sig * H_SCALE;
    }
  }
  __syncthreads();

  // ---- MFMA phase: wave w computes its 16-edge M-tile (split precision) ----
  const int w    = tid >> 6;
  const int l    = tid & 63;
  const int row  = l & 15;
  const int kb   = l >> 4;
  const int mrow = w * 16 + row;
  const int col  = l & 15;

  f32x4 pfs0 = {0.f, 0.f, 0.f, 0.f}, pfs1 = {0.f, 0.f, 0.f, 0.f};
  f32x4 pc0_0 = {0.f, 0.f, 0.f, 0.f}, pc0_1 = {0.f, 0.f, 0.f, 0.f}, pc0_2 = {0.f, 0.f, 0.f, 0.f};
  f32x4 pc1_0 = {0.f, 0.f, 0.f, 0.f}, pc1_1 = {0.f, 0.f, 0.f, 0.f}, pc1_2 = {0.f, 0.f, 0.f, 0.f};

  // fs path: K=256, 8 K-steps. k = s*32 + kb*8 + j; r = k>>4, i = k&15.
#pragma unroll
  for (int s = 0; s < 8; s++) {
    const int r  = 2 * s + (kb >> 1);
    const int i0 = (kb & 1) * 8;
    const float hr = h_s[mrow][r];
    bf16x8 ah, al;
#pragma unroll
    for (int j = 0; j < 8; j++) {
      float v = hr * fsT[i0 + j][mrow];
      short hi = f2bf(v);
      ah[j] = hi;
      al[j] = f2bf(v - bf2f(hi));
    }
    const int k0 = s * 32 + kb * 8;
    bf16x8 bh0 = *reinterpret_cast<const bf16x8*>(&BtL[col][k0]);
    bf16x8 bh1 = *reinterpret_cast<const bf16x8*>(&BtL[16 + col][k0]);
    bf16x8 bl0 = *reinterpret_cast<const bf16x8*>(&BtL[32 + col][k0]);
    bf16x8 bl1 = *reinterpret_cast<const bf16x8*>(&BtL[48 + col][k0]);
    pfs0 = __builtin_amdgcn_mfma_f32_16x16x32_bf16(ah, bh0, pfs0, 0, 0, 0);
    pfs0 = __builtin_amdgcn_mfma_f32_16x16x32_bf16(al, bh0, pfs0, 0, 0, 0);
    pfs0 = __builtin_amdgcn_mfma_f32_16x16x32_bf16(ah, bl0, pfs0, 0, 0, 0);
    pfs1 = __builtin_amdgcn_mfma_f32_16x16x32_bf16(ah, bh1, pfs1, 0, 0, 0);
    pfs1 = __builtin_amdgcn_mfma_f32_16x16x32_bf16(al, bh1, pfs1, 0, 0, 0);
    pfs1 = __builtin_amdgcn_mfma_f32_16x16x32_bf16(ah, bl1, pfs1, 0, 0, 0);
  }

  // fv path: K=128 per c, 4 K-steps; r = 4s+kb, i = j.
#pragma unroll
  for (int s = 0; s < 4; s++) {
    const int r = 4 * s + kb;
    const float hr = h_s[mrow][r];
    const int k0 = 256 + s * 32 + kb * 8;
    bf16x8 bh0 = *reinterpret_cast<const bf16x8*>(&BtL[col][k0]);
    bf16x8 bh1 = *reinterpret_cast<const bf16x8*>(&BtL[16 + col][k0]);
    bf16x8 bl0 = *reinterpret_cast<const bf16x8*>(&BtL[32 + col][k0]);
    bf16x8 bl1 = *reinterpret_cast<const bf16x8*>(&BtL[48 + col][k0]);
#pragma unroll
    for (int c = 0; c < 3; c++) {
      bf16x8 ah, al;
#pragma unroll
      for (int j = 0; j < 8; j++) {
        float v = hr * fvT[c * 8 + j][mrow];
        short hi = f2bf(v);
        ah[j] = hi;
        al[j] = f2bf(v - bf2f(hi));
      }
      f32x4* p0 = (c == 0) ? &pc0_0 : (c == 1) ? &pc0_1 : &pc0_2;
      f32x4* p1 = (c == 0) ? &pc1_0 : (c == 1) ? &pc1_1 : &pc1_2;
      *p0 = __builtin_amdgcn_mfma_f32_16x16x32_bf16(ah, bh0, *p0, 0, 0, 0);
      *p0 = __builtin_amdgcn_mfma_f32_16x16x32_bf16(al, bh0, *p0, 0, 0, 0);
      *p0 = __builtin_amdgcn_mfma_f32_16x16x32_bf16(ah, bl0, *p0, 0, 0, 0);
      *p1 = __builtin_amdgcn_mfma_f32_16x16x32_bf16(ah, bh1, *p1, 0, 0, 0);
      *p1 = __builtin_amdgcn_mfma_f32_16x16x32_bf16(al, bh1, *p1, 0, 0, 0);
      *p1 = __builtin_amdgcn_mfma_f32_16x16x32_bf16(ah, bl1, *p1, 0, 0, 0);
    }
  }

  // ---- epilogue: combine with per-edge sh scalars, weighted rows -> LDS ----
#pragma unroll
  for (int j = 0; j < 4; j++) {
    const int me = w * 16 + kb * 4 + j;          // D row = (l>>4)*4 + reg
    const float sh0 = scal[me][0], sh1 = scal[me][1], sh2 = scal[me][2], sh3 = scal[me][3];
    const float wg = scal[me][4];
    float vsc = sh0 * pfs0[j] + sh1 * pc0_0[j] + sh2 * pc0_1[j] + sh3 * pc0_2[j];
    rows[me][col] = wg * vsc;
    if (col < 8) {
      rows[me][16 + col * 3 + 0] = wg * (sh1 * pfs1[j] + sh0 * pc1_0[j]);
      rows[me][16 + col * 3 + 1] = wg * (sh2 * pfs1[j] + sh0 * pc1_1[j]);
      rows[me][16 + col * 3 + 2] = wg * (sh3 * pfs1[j] + sh0 * pc1_2[j]);
    }
  }
  __syncthreads();

  // ---- copy rows to vbuf in sorted-rank order (coalesced) ----
  for (int idx = tid; idx < 64 * DIM; idx += 256) {
    int rr = idx / DIM, dd = idx % DIM;
    vbuf[(size_t)(base + rr) * DIM + dd] = rows[rr][dd];
  }
}

// ---------------------------------------------------------------------------
// Gather (round-2 verified verbatim)
// ---------------------------------------------------------------------------
__global__ __launch_bounds__(256) void gather_kernel(
    const float* __restrict__ vbuf,
    const int* __restrict__ start,
    const int* __restrict__ cnt,
    float* __restrict__ fout)
{
  const int tid = threadIdx.x;
  const int node = blockIdx.x * 4 + (tid >> 6);
  const int lane = tid & 63;
  if (lane >= DIM) return;
  const int s0 = start[node];
  const int c = cnt[node];
  float acc = 0.f;
  for (int j = 0; j < c; j++)
    acc += vbuf[(size_t)(s0 + j) * DIM + lane];
  fout[(size_t)node * DIM + lane] = acc;
}

extern "C" void kernel_launch(void* const* d_in, const int* in_sizes, int n_in,
                              void* d_out, int out_size, void* d_ws, size_t ws_size,
                              hipStream_t stream) {
  const float* f      = (const float*)d_in[0];
  const int*   ei     = (const int*)d_in[1];
  const float* elen   = (const float*)d_in[2];
  const float* esh    = (const float*)d_in[3];
  const float* emb    = (const float*)d_in[4];
  const float* Wq0    = (const float*)d_in[5];
  const float* Wq1    = (const float*)d_in[6];
  const float* fck_w1 = (const float*)d_in[7];
  const float* fck_w2 = (const float*)d_in[8];
  const float* fcv_w1 = (const float*)d_in[9];
  const float* fcv_w2 = (const float*)d_in[10];
  const float* Wd00   = (const float*)d_in[11];
  const float* Wd11   = (const float*)d_in[12];

  float* out = (float*)d_out;

  char* ws = (char*)d_ws;
  float* qq    = (float*)ws;  ws += (size_t)NN * 64 * 4;
  float* qd    = (float*)ws;  ws += (size_t)NN * DIM * 4;
  float* z     = (float*)ws;  ws += (size_t)NN * 4;
  float* expv  = (float*)ws;  ws += (size_t)NE * 4;
  int*   cnt   = (int*)ws;    ws += (size_t)NN * 4;
  int*   startb= (int*)ws;    ws += (size_t)NN * 4;
  int*   off   = (int*)ws;    ws += (size_t)NN * 4;
  int*   eperm = (int*)ws;    ws += (size_t)NE * 4;
  unsigned short* Bt = (unsigned short*)ws;  ws += (size_t)64 * BKP * 2;
  ws = (char*)(((size_t)ws + 255) & ~(size_t)255);
  float* vbuf  = (float*)ws;  // NE * DIM * 4 = 42 MB

  hipMemsetAsync(z, 0, (size_t)NN * 4, stream);
  hipMemsetAsync(cnt, 0, (size_t)NN * 4, stream);

  prep_B_kernel<<<32 * BKP / 256, 256, 0, stream>>>(fcv_w2, Bt);
  node_qd_kernel<<<NN / 256, 256, 0, stream>>>(f, Wq0, Wq1, Wd00, Wd11, qd);
  qq_kernel<<<NN * 16 / 256, 256, 0, stream>>>(f, qd, fck_w2, qq);
  hist_kernel<<<NE / 256, 256, 0, stream>>>(ei, cnt);
  scan_kernel<<<1, 1024, 0, stream>>>(cnt, startb, off);
  scatter_kernel<<<NE / 256, 256, 0, stream>>>(ei, off, eperm);
  k_pass_kernel<<<NE / 256, 256, 0, stream>>>(ei, elen, esh, emb, fck_w1, qq, expv, z);
  v_mfma_kernel<<<NE / 64, 256, 0, stream>>>(ei, esh, emb, fcv_w1, f, expv, z,
                                             eperm, Bt, vbuf);
  gather_kernel<<<NN / 4, 256, 0, stream>>>(vbuf, startb, cnt, out);
}

// Round 7
// 239.836 us; speedup vs baseline: 1.5528x; 1.5528x over previous
//
#include <hip/hip_runtime.h>
#include <hip/hip_bf16.h>
#include <math.h>

namespace {
constexpr int NN  = 16384;
constexpr int NE  = 262144;
constexpr int DIM = 40;

constexpr float INV_SQRT3   = 0.5773502691896258f;
constexpr float A_PATH      = 0.2041241452319315f;      // 1/sqrt(24)
constexpr float INV_SQRT_NB = 0.31622776601683794f;     // 1/sqrt(10)
constexpr float H_SCALE     = 0.25f;                    // 1/sqrt(16)
constexpr float QSC_S       = 0.25f;
constexpr float QV_S        = 0.35355339059327373f;
constexpr float D00_S       = 1.0f / (16.0f * 1.4142135623730951f);
constexpr float D11_S       = 1.0f / (8.0f * 1.7320508075688772f * 1.4142135623730951f);

constexpr int BKP = 392;  // padded k-stride for Bt (bf16)
}

typedef __attribute__((ext_vector_type(8))) short bf16x8;
typedef __attribute__((ext_vector_type(4))) float f32x4;

static __device__ inline short f2bf(float x) {
  __hip_bfloat16 h = __float2bfloat16(x);
  return __builtin_bit_cast(short, h);
}
static __device__ inline float bf2f(short b) {
  unsigned u = ((unsigned)(unsigned short)b) << 16;
  return __builtin_bit_cast(float, u);
}

// ---------------------------------------------------------------------------
// node_qd: per-node qd0[16] (+D00_S) and qdv[8][3] (+D11_S), stored as 40
// floats: [0..15]=qd0, [16+j*3+c]=qdv[j][c]. 1 thread/node (tiny kernel).
// ---------------------------------------------------------------------------
__global__ __launch_bounds__(256) void node_qd_kernel(
    const float* __restrict__ f,
    const float* __restrict__ Wq0, const float* __restrict__ Wq1,
    const float* __restrict__ Wd00, const float* __restrict__ Wd11,
    float* __restrict__ qd)
{
  const int n = blockIdx.x * 256 + threadIdx.x;

  float fs[16], fv[8][3];
  {
    const float4* fn4 = reinterpret_cast<const float4*>(f + (size_t)n * DIM);
#pragma unroll
    for (int i = 0; i < 10; i++) {
      float4 t = fn4[i];
      int base = i * 4;
#pragma unroll
      for (int k = 0; k < 4; k++) {
        float v = (k == 0) ? t.x : (k == 1) ? t.y : (k == 2) ? t.z : t.w;
        int idx = base + k;
        if (idx < 16) fs[idx] = v;
        else { int r = idx - 16; fv[r / 3][r % 3] = v; }
      }
    }
  }

  float out[40];
  {
    float qsc[16];
#pragma unroll
    for (int o = 0; o < 16; o++) {
      float a = 0.f;
#pragma unroll
      for (int i = 0; i < 16; i++) a += fs[i] * Wq0[i * 16 + o];
      qsc[o] = a * QSC_S;
    }
#pragma unroll
    for (int j = 0; j < 16; j++) {
      float a = 0.f;
#pragma unroll
      for (int i = 0; i < 16; i++) a += qsc[i] * Wd00[i * 16 + j];
      out[j] = a * D00_S;
    }
  }
  {
    float qv[8][3];
#pragma unroll
    for (int o = 0; o < 8; o++)
#pragma unroll
      for (int c = 0; c < 3; c++) {
        float a = 0.f;
#pragma unroll
        for (int i = 0; i < 8; i++) a += fv[i][c] * Wq1[i * 8 + o];
        qv[o][c] = a * QV_S;
      }
#pragma unroll
    for (int j = 0; j < 8; j++)
#pragma unroll
      for (int c = 0; c < 3; c++) {
        float a = 0.f;
#pragma unroll
        for (int i = 0; i < 8; i++) a += qv[i][c] * Wd11[i * 8 + j];
        out[16 + j * 3 + c] = a * D11_S;
      }
  }

  float4* op = reinterpret_cast<float4*>(qd + (size_t)n * DIM);
#pragma unroll
  for (int i = 0; i < 10; i++)
    op[i] = make_float4(out[4 * i], out[4 * i + 1], out[4 * i + 2], out[4 * i + 3]);
}

// ---------------------------------------------------------------------------
// qq_kernel: one thread per (n,r). Same math as the round-2-verified
// node_qq inner body for a single r (scales identical; A_PATH on write).
// NOTE: no occupancy bound — round-6's (256,3) capped VGPR at 84 and spilled
// ~350 MB to scratch. Let the allocator take ~130 VGPR; 4096 waves is ample.
// ---------------------------------------------------------------------------
__global__ __launch_bounds__(256) void qq_kernel(
    const float* __restrict__ f,
    const float* __restrict__ qd,
    const float* __restrict__ w2k,
    float* __restrict__ qq)
{
  const int gid = blockIdx.x * 256 + threadIdx.x;   // NN*16 threads
  const int n = gid >> 4, r = gid & 15;

  float fs[16], fv[8][3];
  {
    const float4* fn4 = reinterpret_cast<const float4*>(f + (size_t)n * DIM);
#pragma unroll
    for (int i = 0; i < 10; i++) {
      float4 t = fn4[i];
      int base = i * 4;
#pragma unroll
      for (int k = 0; k < 4; k++) {
        float v = (k == 0) ? t.x : (k == 1) ? t.y : (k == 2) ? t.z : t.w;
        int idx = base + k;
        if (idx < 16) fs[idx] = v;
        else { int rr = idx - 16; fv[rr / 3][rr % 3] = v; }
      }
    }
  }
  float qd0[16], qdv[8][3];
  {
    const float4* qp = reinterpret_cast<const float4*>(qd + (size_t)n * DIM);
#pragma unroll
    for (int i = 0; i < 10; i++) {
      float4 t = qp[i];
      int base = i * 4;
#pragma unroll
      for (int k = 0; k < 4; k++) {
        float v = (k == 0) ? t.x : (k == 1) ? t.y : (k == 2) ? t.z : t.w;
        int idx = base + k;
        if (idx < 16) qd0[idx] = v;
        else { int rr = idx - 16; qdv[rr / 3][rr % 3] = v; }
      }
    }
  }

  const float4* __restrict__ w4 = reinterpret_cast<const float4*>(w2k + (size_t)r * 576);
  float q0 = 0.f, qc0 = 0.f, qc1 = 0.f, qc2 = 0.f;

  // w00 block [0,256)
#pragma unroll
  for (int i = 0; i < 16; i++) {
    float t = 0.f;
#pragma unroll
    for (int o4 = 0; o4 < 4; o4++) {
      float4 w = w4[i * 4 + o4];
      t += qd0[o4 * 4 + 0] * w.x + qd0[o4 * 4 + 1] * w.y
         + qd0[o4 * 4 + 2] * w.z + qd0[o4 * 4 + 3] * w.w;
    }
    q0 += fs[i] * t;
  }
  // w11 block [256,384)
#pragma unroll
  for (int i = 0; i < 8; i++) {
    float t = 0.f;
#pragma unroll
    for (int o4 = 0; o4 < 4; o4++) {
      float4 w = w4[64 + i * 4 + o4];
      t += qd0[o4 * 4 + 0] * w.x + qd0[o4 * 4 + 1] * w.y
         + qd0[o4 * 4 + 2] * w.z + qd0[o4 * 4 + 3] * w.w;
    }
    t *= INV_SQRT3;
    qc0 += fv[i][0] * t; qc1 += fv[i][1] * t; qc2 += fv[i][2] * t;
  }
  // w01 block [384,512)
#pragma unroll
  for (int i = 0; i < 16; i++) {
    float t0 = 0.f, t1 = 0.f, t2 = 0.f;
#pragma unroll
    for (int o4 = 0; o4 < 2; o4++) {
      float4 w = w4[96 + i * 2 + o4];
#pragma unroll
      for (int k = 0; k < 4; k++) {
        float wk = (k == 0) ? w.x : (k == 1) ? w.y : (k == 2) ? w.z : w.w;
        int o = o4 * 4 + k;
        t0 += qdv[o][0] * wk; t1 += qdv[o][1] * wk; t2 += qdv[o][2] * wk;
      }
    }
    qc0 += fs[i] * t0; qc1 += fs[i] * t1; qc2 += fs[i] * t2;
  }
  // w10 block [512,576)
#pragma unroll
  for (int i = 0; i < 8; i++) {
    float t0 = 0.f, t1 = 0.f, t2 = 0.f;
#pragma unroll
    for (int o4 = 0; o4 < 2; o4++) {
      float4 w = w4[128 + i * 2 + o4];
#pragma unroll
      for (int k = 0; k < 4; k++) {
        float wk = (k == 0) ? w.x : (k == 1) ? w.y : (k == 2) ? w.z : w.w;
        int o = o4 * 4 + k;
        t0 += qdv[o][0] * wk; t1 += qdv[o][1] * wk; t2 += qdv[o][2] * wk;
      }
    }
    q0 += fv[i][0] * t0 + fv[i][1] * t1 + fv[i][2] * t2;
  }

  reinterpret_cast<float4*>(qq)[gid] =
      make_float4(A_PATH * q0, A_PATH * qc0, A_PATH * qc1, A_PATH * qc2);
}

// ---------------------------------------------------------------------------
// K-pass (round-2 verified)
// ---------------------------------------------------------------------------
__global__ __launch_bounds__(256) void k_pass_kernel(
    const int*   __restrict__ ei,
    const float* __restrict__ elen,
    const float* __restrict__ esh,
    const float* __restrict__ emb,
    const float* __restrict__ w1,
    const float* __restrict__ qq,
    float* __restrict__ expv,
    float* __restrict__ z)
{
  const int e = blockIdx.x * 256 + threadIdx.x;
  const int dst = ei[NE + e];

  float el[10];
  const float2* e2 = reinterpret_cast<const float2*>(emb + (size_t)e * 10);
#pragma unroll
  for (int b = 0; b < 5; b++) { float2 t = e2[b]; el[2 * b] = t.x; el[2 * b + 1] = t.y; }

  float h[16];
#pragma unroll
  for (int j = 0; j < 16; j++) {
    float a = 0.f;
#pragma unroll
    for (int b = 0; b < 10; b++) a += el[b] * w1[b * 16 + j];
    a *= INV_SQRT_NB;
    float sig = 1.0f / (1.0f + __expf(-a));
    h[j] = a * sig * H_SCALE;
  }

  float4 sh4 = reinterpret_cast<const float4*>(esh)[e];
  const float4* q4 = reinterpret_cast<const float4*>(qq + (size_t)dst * 64);
  float s = 0.f;
#pragma unroll
  for (int r = 0; r < 16; r++) {
    float4 qv = q4[r];
    s += h[r] * (sh4.x * qv.x + sh4.y * qv.y + sh4.z * qv.z + sh4.w * qv.w);
  }

  float len = elen[e];
  float x = 10.0f * (1.0f - len * (1.0f / 1.3f));
  float cut = (x > 0.f) ? __expf(-1.0f / x) : 0.f;
  float ev = cut * __expf(s);
  expv[e] = ev;
  atomicAdd(&z[dst], ev);
}

// ---------------------------------------------------------------------------
// Counting sort by dst
// ---------------------------------------------------------------------------
__global__ __launch_bounds__(256) void hist_kernel(const int* __restrict__ ei,
                                                   int* __restrict__ cnt)
{
  const int e = blockIdx.x * 256 + threadIdx.x;
  atomicAdd(&cnt[ei[NE + e]], 1);
}

__global__ __launch_bounds__(1024) void scan_kernel(const int* __restrict__ cnt,
                                                    int* __restrict__ start,
                                                    int* __restrict__ off)
{
  __shared__ int part[1024];
  const int t = threadIdx.x;
  const int base = t * 16;
  int loc[16];
  int s = 0;
#pragma unroll
  for (int k = 0; k < 16; k++) { loc[k] = s; s += cnt[base + k]; }
  part[t] = s;
  __syncthreads();
  for (int d = 1; d < 1024; d <<= 1) {
    int v = (t >= d) ? part[t - d] : 0;
    __syncthreads();
    part[t] += v;
    __syncthreads();
  }
  int excl = (t == 0) ? 0 : part[t - 1];
#pragma unroll
  for (int k = 0; k < 16; k++) {
    int v = excl + loc[k];
    start[base + k] = v;
    off[base + k] = v;
  }
}

__global__ __launch_bounds__(256) void scatter_kernel(const int* __restrict__ ei,
                                                      int* __restrict__ off,
                                                      int* __restrict__ eperm)
{
  const int e = blockIdx.x * 256 + threadIdx.x;
  int rk = atomicAdd(&off[ei[NE + e]], 1);
  eperm[rk] = e;
}

// ---------------------------------------------------------------------------
// prep_B: hi/lo bf16 split planes. Bt[col][kp] hi; Bt[32+col][kp] lo.
// ---------------------------------------------------------------------------
__global__ __launch_bounds__(256) void prep_B_kernel(const float* __restrict__ w2v,
                                                     unsigned short* __restrict__ Bt)
{
  int t = blockIdx.x * 256 + threadIdx.x;   // 32*BKP threads
  int col = t / BKP, kp = t % BKP;
  float val = 0.f;
  if (kp < 384 && col < 24) {
    if (kp < 256) {
      int r = kp >> 4, i = kp & 15;
      if (col < 16) val = A_PATH * w2v[r * 576 + i * 16 + col];
      else          val = A_PATH * w2v[r * 576 + 384 + i * 8 + (col - 16)];
    } else {
      int k2 = kp - 256; int r = k2 >> 3, i = k2 & 7;
      if (col < 16) val = A_PATH * INV_SQRT3 * w2v[r * 576 + 256 + i * 16 + col];
      else          val = A_PATH * w2v[r * 576 + 512 + i * 8 + (col - 16)];
    }
  }
  short hi = f2bf(val);
  short lo = f2bf(val - bf2f(hi));
  Bt[t] = (unsigned short)hi;
  Bt[32 * BKP + t] = (unsigned short)lo;
}

// ---------------------------------------------------------------------------
// V-pass via MFMA, split-precision (round-5 verified, unchanged)
// ---------------------------------------------------------------------------
__global__ __launch_bounds__(256) void v_mfma_kernel(
    const int*   __restrict__ ei,
    const float* __restrict__ esh,
    const float* __restrict__ emb,
    const float* __restrict__ w1,      // fcv_w1
    const float* __restrict__ f,
    const float* __restrict__ expv,
    const float* __restrict__ z,
    const int*   __restrict__ eperm,
    const unsigned short* __restrict__ Bt,
    float* __restrict__ vbuf)
{
  __shared__ float h_s[64][17];
  __shared__ float fsT[16][65];
  __shared__ float fvT[24][65];
  __shared__ float scal[64][5];
  __shared__ int   nid[64];
  __shared__ __attribute__((aligned(16))) unsigned short BtL[64][BKP];
  __shared__ float rows[64][41];

  const int tid  = threadIdx.x;
  const int base = blockIdx.x * 64;

  // stage Bt (hi+lo planes) -> LDS (50 KB)
  {
    const unsigned* sp = reinterpret_cast<const unsigned*>(Bt);
    unsigned* dp = reinterpret_cast<unsigned*>(&BtL[0][0]);
    for (int i = tid; i < 64 * BKP / 2; i += 256) dp[i] = sp[i];
  }

  const int m = tid & 63;
  const int q = tid >> 6;
  const int e = eperm[base + m];

  if (q == 0) {
    int dn = ei[NE + e];
    float4 sh4 = reinterpret_cast<const float4*>(esh)[e];
    float zz = z[dn]; zz = (zz == 0.f) ? 1.f : zz;
    float ev = expv[e];
    float wgt = sqrtf(fmaxf(ev / zz, 0.f));
    scal[m][0] = sh4.x; scal[m][1] = sh4.y; scal[m][2] = sh4.z; scal[m][3] = sh4.w;
    scal[m][4] = wgt;
    nid[m] = dn;
  } else if (q == 3) {
    int sn = ei[e];
    const float4* f4 = reinterpret_cast<const float4*>(f + (size_t)sn * DIM);
    float v[40];
#pragma unroll
    for (int i = 0; i < 10; i++) {
      float4 t = f4[i];
      v[4 * i] = t.x; v[4 * i + 1] = t.y; v[4 * i + 2] = t.z; v[4 * i + 3] = t.w;
    }
#pragma unroll
    for (int i = 0; i < 16; i++) fsT[i][m] = v[i];
#pragma unroll
    for (int k = 0; k < 24; k++) fvT[(k % 3) * 8 + (k / 3)][m] = v[16 + k];  // fvT[c*8+i]
  } else {
    // q=1: h[0..7], q=2: h[8..15]
    float el[10];
    const float2* e2 = reinterpret_cast<const float2*>(emb + (size_t)e * 10);
#pragma unroll
    for (int b = 0; b < 5; b++) { float2 t = e2[b]; el[2 * b] = t.x; el[2 * b + 1] = t.y; }
    const int j0 = (q == 1) ? 0 : 8;
#pragma unroll
    for (int jj = 0; jj < 8; jj++) {
      int j = j0 + jj;
      float a = 0.f;
#pragma unroll
      for (int b = 0; b < 10; b++) a += el[b] * w1[b * 16 + j];
      a *= INV_SQRT_NB;
      float sig = 1.0f / (1.0f + __expf(-a));
      h_s[m][j] = a * sig * H_SCALE;
    }
  }
  __syncthreads();

  // ---- MFMA phase: wave w computes its 16-edge M-tile (split precision) ----
  const int w    = tid >> 6;
  const int l    = tid & 63;
  const int row  = l & 15;
  const int kb   = l >> 4;
  const int mrow = w * 16 + row;
  const int col  = l & 15;

  f32x4 pfs0 = {0.f, 0.f, 0.f, 0.f}, pfs1 = {0.f, 0.f, 0.f, 0.f};
  f32x4 pc0_0 = {0.f, 0.f, 0.f, 0.f}, pc0_1 = {0.f, 0.f, 0.f, 0.f}, pc0_2 = {0.f, 0.f, 0.f, 0.f};
  f32x4 pc1_0 = {0.f, 0.f, 0.f, 0.f}, pc1_1 = {0.f, 0.f, 0.f, 0.f}, pc1_2 = {0.f, 0.f, 0.f, 0.f};

  // fs path: K=256, 8 K-steps. k = s*32 + kb*8 + j; r = k>>4, i = k&15.
#pragma unroll
  for (int s = 0; s < 8; s++) {
    const int r  = 2 * s + (kb >> 1);
    const int i0 = (kb & 1) * 8;
    const float hr = h_s[mrow][r];
    bf16x8 ah, al;
#pragma unroll
    for (int j = 0; j < 8; j++) {
      float v = hr * fsT[i0 + j][mrow];
      short hi = f2bf(v);
      ah[j] = hi;
      al[j] = f2bf(v - bf2f(hi));
    }
    const int k0 = s * 32 + kb * 8;
    bf16x8 bh0 = *reinterpret_cast<const bf16x8*>(&BtL[col][k0]);
    bf16x8 bh1 = *reinterpret_cast<const bf16x8*>(&BtL[16 + col][k0]);
    bf16x8 bl0 = *reinterpret_cast<const bf16x8*>(&BtL[32 + col][k0]);
    bf16x8 bl1 = *reinterpret_cast<const bf16x8*>(&BtL[48 + col][k0]);
    pfs0 = __builtin_amdgcn_mfma_f32_16x16x32_bf16(ah, bh0, pfs0, 0, 0, 0);
    pfs0 = __builtin_amdgcn_mfma_f32_16x16x32_bf16(al, bh0, pfs0, 0, 0, 0);
    pfs0 = __builtin_amdgcn_mfma_f32_16x16x32_bf16(ah, bl0, pfs0, 0, 0, 0);
    pfs1 = __builtin_amdgcn_mfma_f32_16x16x32_bf16(ah, bh1, pfs1, 0, 0, 0);
    pfs1 = __builtin_amdgcn_mfma_f32_16x16x32_bf16(al, bh1, pfs1, 0, 0, 0);
    pfs1 = __builtin_amdgcn_mfma_f32_16x16x32_bf16(ah, bl1, pfs1, 0, 0, 0);
  }

  // fv path: K=128 per c, 4 K-steps; r = 4s+kb, i = j.
#pragma unroll
  for (int s = 0; s < 4; s++) {
    const int r = 4 * s + kb;
    const float hr = h_s[mrow][r];
    const int k0 = 256 + s * 32 + kb * 8;
    bf16x8 bh0 = *reinterpret_cast<const bf16x8*>(&BtL[col][k0]);
    bf16x8 bh1 = *reinterpret_cast<const bf16x8*>(&BtL[16 + col][k0]);
    bf16x8 bl0 = *reinterpret_cast<const bf16x8*>(&BtL[32 + col][k0]);
    bf16x8 bl1 = *reinterpret_cast<const bf16x8*>(&BtL[48 + col][k0]);
#pragma unroll
    for (int c = 0; c < 3; c++) {
      bf16x8 ah, al;
#pragma unroll
      for (int j = 0; j < 8; j++) {
        float v = hr * fvT[c * 8 + j][mrow];
        short hi = f2bf(v);
        ah[j] = hi;
        al[j] = f2bf(v - bf2f(hi));
      }
      f32x4* p0 = (c == 0) ? &pc0_0 : (c == 1) ? &pc0_1 : &pc0_2;
      f32x4* p1 = (c == 0) ? &pc1_0 : (c == 1) ? &pc1_1 : &pc1_2;
      *p0 = __builtin_amdgcn_mfma_f32_16x16x32_bf16(ah, bh0, *p0, 0, 0, 0);
      *p0 = __builtin_amdgcn_mfma_f32_16x16x32_bf16(al, bh0, *p0, 0, 0, 0);
      *p0 = __builtin_amdgcn_mfma_f32_16x16x32_bf16(ah, bl0, *p0, 0, 0, 0);
      *p1 = __builtin_amdgcn_mfma_f32_16x16x32_bf16(ah, bh1, *p1, 0, 0, 0);
      *p1 = __builtin_amdgcn_mfma_f32_16x16x32_bf16(al, bh1, *p1, 0, 0, 0);
      *p1 = __builtin_amdgcn_mfma_f32_16x16x32_bf16(ah, bl1, *p1, 0, 0, 0);
    }
  }

  // ---- epilogue: combine with per-edge sh scalars, weighted rows -> LDS ----
#pragma unroll
  for (int j = 0; j < 4; j++) {
    const int me = w * 16 + kb * 4 + j;          // D row = (l>>4)*4 + reg
    const float sh0 = scal[me][0], sh1 = scal[me][1], sh2 = scal[me][2], sh3 = scal[me][3];
    const float wg = scal[me][4];
    float vsc = sh0 * pfs0[j] + sh1 * pc0_0[j] + sh2 * pc0_1[j] + sh3 * pc0_2[j];
    rows[me][col] = wg * vsc;
    if (col < 8) {
      rows[me][16 + col * 3 + 0] = wg * (sh1 * pfs1[j] + sh0 * pc1_0[j]);
      rows[me][16 + col * 3 + 1] = wg * (sh2 * pfs1[j] + sh0 * pc1_1[j]);
      rows[me][16 + col * 3 + 2] = wg * (sh3 * pfs1[j] + sh0 * pc1_2[j]);
    }
  }
  __syncthreads();

  // ---- copy rows to vbuf in sorted-rank order (coalesced) ----
  for (int idx = tid; idx < 64 * DIM; idx += 256) {
    int rr = idx / DIM, dd = idx % DIM;
    vbuf[(size_t)(base + rr) * DIM + dd] = rows[rr][dd];
  }
}

// ---------------------------------------------------------------------------
// Gather (round-2 verified verbatim)
// ---------------------------------------------------------------------------
__global__ __launch_bounds__(256) void gather_kernel(
    const float* __restrict__ vbuf,
    const int* __restrict__ start,
    const int* __restrict__ cnt,
    float* __restrict__ fout)
{
  const int tid = threadIdx.x;
  const int node = blockIdx.x * 4 + (tid >> 6);
  const int lane = tid & 63;
  if (lane >= DIM) return;
  const int s0 = start[node];
  const int c = cnt[node];
  float acc = 0.f;
  for (int j = 0; j < c; j++)
    acc += vbuf[(size_t)(s0 + j) * DIM + lane];
  fout[(size_t)node * DIM + lane] = acc;
}

extern "C" void kernel_launch(void* const* d_in, const int* in_sizes, int n_in,
                              void* d_out, int out_size, void* d_ws, size_t ws_size,
                              hipStream_t stream) {
  const float* f      = (const float*)d_in[0];
  const int*   ei     = (const int*)d_in[1];
  const float* elen   = (const float*)d_in[2];
  const float* esh    = (const float*)d_in[3];
  const float* emb    = (const float*)d_in[4];
  const float* Wq0    = (const float*)d_in[5];
  const float* Wq1    = (const float*)d_in[6];
  const float* fck_w1 = (const float*)d_in[7];
  const float* fck_w2 = (const float*)d_in[8];
  const float* fcv_w1 = (const float*)d_in[9];
  const float* fcv_w2 = (const float*)d_in[10];
  const float* Wd00   = (const float*)d_in[11];
  const float* Wd11   = (const float*)d_in[12];

  float* out = (float*)d_out;

  char* ws = (char*)d_ws;
  float* qq    = (float*)ws;  ws += (size_t)NN * 64 * 4;
  float* qd    = (float*)ws;  ws += (size_t)NN * DIM * 4;
  float* z     = (float*)ws;  ws += (size_t)NN * 4;
  float* expv  = (float*)ws;  ws += (size_t)NE * 4;
  int*   cnt   = (int*)ws;    ws += (size_t)NN * 4;
  int*   startb= (int*)ws;    ws += (size_t)NN * 4;
  int*   off   = (int*)ws;    ws += (size_t)NN * 4;
  int*   eperm = (int*)ws;    ws += (size_t)NE * 4;
  unsigned short* Bt = (unsigned short*)ws;  ws += (size_t)64 * BKP * 2;
  ws = (char*)(((size_t)ws + 255) & ~(size_t)255);
  float* vbuf  = (float*)ws;  // NE * DIM * 4 = 42 MB

  hipMemsetAsync(z, 0, (size_t)NN * 4, stream);
  hipMemsetAsync(cnt, 0, (size_t)NN * 4, stream);

  prep_B_kernel<<<32 * BKP / 256, 256, 0, stream>>>(fcv_w2, Bt);
  node_qd_kernel<<<NN / 256, 256, 0, stream>>>(f, Wq0, Wq1, Wd00, Wd11, qd);
  qq_kernel<<<NN * 16 / 256, 256, 0, stream>>>(f, qd, fck_w2, qq);
  hist_kernel<<<NE / 256, 256, 0, stream>>>(ei, cnt);
  scan_kernel<<<1, 1024, 0, stream>>>(cnt, startb, off);
  scatter_kernel<<<NE / 256, 256, 0, stream>>>(ei, off, eperm);
  k_pass_kernel<<<NE / 256, 256, 0, stream>>>(ei, elen, esh, emb, fck_w1, qq, expv, z);
  v_mfma_kernel<<<NE / 64, 256, 0, stream>>>(ei, esh, emb, fcv_w1, f, expv, z,
                                             eperm, Bt, vbuf);
  gather_kernel<<<NN / 4, 256, 0, stream>>>(vbuf, startb, cnt, out);
}

// Round 8
// 215.816 us; speedup vs baseline: 1.7256x; 1.1113x over previous
//
#include <hip/hip_runtime.h>
#include <hip/hip_bf16.h>
#include <math.h>

namespace {
constexpr int NN  = 16384;
constexpr int NE  = 262144;
constexpr int DIM = 40;

constexpr float INV_SQRT3   = 0.5773502691896258f;
constexpr float A_PATH      = 0.2041241452319315f;      // 1/sqrt(24)
constexpr float INV_SQRT_NB = 0.31622776601683794f;     // 1/sqrt(10)
constexpr float H_SCALE     = 0.25f;                    // 1/sqrt(16)
constexpr float QSC_S       = 0.25f;
constexpr float QV_S        = 0.35355339059327373f;
constexpr float D00_S       = 1.0f / (16.0f * 1.4142135623730951f);
constexpr float D11_S       = 1.0f / (8.0f * 1.7320508075688772f * 1.4142135623730951f);

constexpr int BKP = 392;  // padded k-stride for Bt (bf16)
}

typedef __attribute__((ext_vector_type(8))) short bf16x8;
typedef __attribute__((ext_vector_type(4))) float f32x4;

static __device__ inline short f2bf(float x) {
  __hip_bfloat16 h = __float2bfloat16(x);
  return __builtin_bit_cast(short, h);
}
static __device__ inline float bf2f(short b) {
  unsigned u = ((unsigned)(unsigned short)b) << 16;
  return __builtin_bit_cast(float, u);
}

// ---------------------------------------------------------------------------
// node_qd: per-node qd0[16] (+D00_S) and qdv[8][3] (+D11_S), stored as 40
// floats: [0..15]=qd0, [16+j*3+c]=qdv[j][c]. 1 thread/node (tiny kernel).
// ---------------------------------------------------------------------------
__global__ __launch_bounds__(256) void node_qd_kernel(
    const float* __restrict__ f,
    const float* __restrict__ Wq0, const float* __restrict__ Wq1,
    const float* __restrict__ Wd00, const float* __restrict__ Wd11,
    float* __restrict__ qd)
{
  const int n = blockIdx.x * 256 + threadIdx.x;

  float fs[16], fv[8][3];
  {
    const float4* fn4 = reinterpret_cast<const float4*>(f + (size_t)n * DIM);
#pragma unroll
    for (int i = 0; i < 10; i++) {
      float4 t = fn4[i];
      int base = i * 4;
#pragma unroll
      for (int k = 0; k < 4; k++) {
        float v = (k == 0) ? t.x : (k == 1) ? t.y : (k == 2) ? t.z : t.w;
        int idx = base + k;
        if (idx < 16) fs[idx] = v;
        else { int r = idx - 16; fv[r / 3][r % 3] = v; }
      }
    }
  }

  float out[40];
  {
    float qsc[16];
#pragma unroll
    for (int o = 0; o < 16; o++) {
      float a = 0.f;
#pragma unroll
      for (int i = 0; i < 16; i++) a += fs[i] * Wq0[i * 16 + o];
      qsc[o] = a * QSC_S;
    }
#pragma unroll
    for (int j = 0; j < 16; j++) {
      float a = 0.f;
#pragma unroll
      for (int i = 0; i < 16; i++) a += qsc[i] * Wd00[i * 16 + j];
      out[j] = a * D00_S;
    }
  }
  {
    float qv[8][3];
#pragma unroll
    for (int o = 0; o < 8; o++)
#pragma unroll
      for (int c = 0; c < 3; c++) {
        float a = 0.f;
#pragma unroll
        for (int i = 0; i < 8; i++) a += fv[i][c] * Wq1[i * 8 + o];
        qv[o][c] = a * QV_S;
      }
#pragma unroll
    for (int j = 0; j < 8; j++)
#pragma unroll
      for (int c = 0; c < 3; c++) {
        float a = 0.f;
#pragma unroll
        for (int i = 0; i < 8; i++) a += qv[i][c] * Wd11[i * 8 + j];
        out[16 + j * 3 + c] = a * D11_S;
      }
  }

  float4* op = reinterpret_cast<float4*>(qd + (size_t)n * DIM);
#pragma unroll
  for (int i = 0; i < 10; i++)
    op[i] = make_float4(out[4 * i], out[4 * i + 1], out[4 * i + 2], out[4 * i + 3]);
}

// ---------------------------------------------------------------------------
// qq_kernel: r is BLOCK-uniform (r = blockIdx>>6) so all w2k reads are
// scalar (s_load, zero VGPR cost); n varies across threads. Same math as the
// round-2-verified body; A_PATH folded at the write.
// ---------------------------------------------------------------------------
__global__ __launch_bounds__(256) void qq_kernel(
    const float* __restrict__ f,
    const float* __restrict__ qd,
    const float* __restrict__ w2k,
    float* __restrict__ qq)
{
  const int r = blockIdx.x >> 6;                       // wave-uniform
  const int n = (blockIdx.x & 63) * 256 + threadIdx.x;

  float fs[16], fv[8][3];
  {
    const float4* fn4 = reinterpret_cast<const float4*>(f + (size_t)n * DIM);
#pragma unroll
    for (int i = 0; i < 10; i++) {
      float4 t = fn4[i];
      int base = i * 4;
#pragma unroll
      for (int k = 0; k < 4; k++) {
        float v = (k == 0) ? t.x : (k == 1) ? t.y : (k == 2) ? t.z : t.w;
        int idx = base + k;
        if (idx < 16) fs[idx] = v;
        else { int rr = idx - 16; fv[rr / 3][rr % 3] = v; }
      }
    }
  }
  float qd0[16], qdv[8][3];
  {
    const float4* qp = reinterpret_cast<const float4*>(qd + (size_t)n * DIM);
#pragma unroll
    for (int i = 0; i < 10; i++) {
      float4 t = qp[i];
      int base = i * 4;
#pragma unroll
      for (int k = 0; k < 4; k++) {
        float v = (k == 0) ? t.x : (k == 1) ? t.y : (k == 2) ? t.z : t.w;
        int idx = base + k;
        if (idx < 16) qd0[idx] = v;
        else { int rr = idx - 16; qdv[rr / 3][rr % 3] = v; }
      }
    }
  }

  const float* __restrict__ wr = w2k + (size_t)r * 576;  // scalar base
  float q0 = 0.f, qc0 = 0.f, qc1 = 0.f, qc2 = 0.f;

  // w00 block [0,256): q0 += fs[i] * (w00[i][o] . qd0[o])
#pragma unroll
  for (int i = 0; i < 16; i++) {
    float t = 0.f;
#pragma unroll
    for (int o = 0; o < 16; o++) t += qd0[o] * wr[i * 16 + o];
    q0 += fs[i] * t;
  }
  // w11 block [256,384)
#pragma unroll
  for (int i = 0; i < 8; i++) {
    float t = 0.f;
#pragma unroll
    for (int o = 0; o < 16; o++) t += qd0[o] * wr[256 + i * 16 + o];
    t *= INV_SQRT3;
    qc0 += fv[i][0] * t; qc1 += fv[i][1] * t; qc2 += fv[i][2] * t;
  }
  // w01 block [384,512)
#pragma unroll
  for (int i = 0; i < 16; i++) {
    float t0 = 0.f, t1 = 0.f, t2 = 0.f;
#pragma unroll
    for (int o = 0; o < 8; o++) {
      float wk = wr[384 + i * 8 + o];
      t0 += qdv[o][0] * wk; t1 += qdv[o][1] * wk; t2 += qdv[o][2] * wk;
    }
    qc0 += fs[i] * t0; qc1 += fs[i] * t1; qc2 += fs[i] * t2;
  }
  // w10 block [512,576)
#pragma unroll
  for (int i = 0; i < 8; i++) {
    float t0 = 0.f, t1 = 0.f, t2 = 0.f;
#pragma unroll
    for (int o = 0; o < 8; o++) {
      float wk = wr[512 + i * 8 + o];
      t0 += qdv[o][0] * wk; t1 += qdv[o][1] * wk; t2 += qdv[o][2] * wk;
    }
    q0 += fv[i][0] * t0 + fv[i][1] * t1 + fv[i][2] * t2;
  }

  reinterpret_cast<float4*>(qq)[n * 16 + r] =
      make_float4(A_PATH * q0, A_PATH * qc0, A_PATH * qc1, A_PATH * qc2);
}

// ---------------------------------------------------------------------------
// K-pass (round-2 verified)
// ---------------------------------------------------------------------------
__global__ __launch_bounds__(256) void k_pass_kernel(
    const int*   __restrict__ ei,
    const float* __restrict__ elen,
    const float* __restrict__ esh,
    const float* __restrict__ emb,
    const float* __restrict__ w1,
    const float* __restrict__ qq,
    float* __restrict__ expv,
    float* __restrict__ z)
{
  const int e = blockIdx.x * 256 + threadIdx.x;
  const int dst = ei[NE + e];

  float el[10];
  const float2* e2 = reinterpret_cast<const float2*>(emb + (size_t)e * 10);
#pragma unroll
  for (int b = 0; b < 5; b++) { float2 t = e2[b]; el[2 * b] = t.x; el[2 * b + 1] = t.y; }

  float h[16];
#pragma unroll
  for (int j = 0; j < 16; j++) {
    float a = 0.f;
#pragma unroll
    for (int b = 0; b < 10; b++) a += el[b] * w1[b * 16 + j];
    a *= INV_SQRT_NB;
    float sig = 1.0f / (1.0f + __expf(-a));
    h[j] = a * sig * H_SCALE;
  }

  float4 sh4 = reinterpret_cast<const float4*>(esh)[e];
  const float4* q4 = reinterpret_cast<const float4*>(qq + (size_t)dst * 64);
  float s = 0.f;
#pragma unroll
  for (int r = 0; r < 16; r++) {
    float4 qv = q4[r];
    s += h[r] * (sh4.x * qv.x + sh4.y * qv.y + sh4.z * qv.z + sh4.w * qv.w);
  }

  float len = elen[e];
  float x = 10.0f * (1.0f - len * (1.0f / 1.3f));
  float cut = (x > 0.f) ? __expf(-1.0f / x) : 0.f;
  float ev = cut * __expf(s);
  expv[e] = ev;
  atomicAdd(&z[dst], ev);
}

// ---------------------------------------------------------------------------
// Counting sort by dst
// ---------------------------------------------------------------------------
__global__ __launch_bounds__(256) void hist_kernel(const int* __restrict__ ei,
                                                   int* __restrict__ cnt)
{
  const int e = blockIdx.x * 256 + threadIdx.x;
  atomicAdd(&cnt[ei[NE + e]], 1);
}

__global__ __launch_bounds__(1024) void scan_kernel(const int* __restrict__ cnt,
                                                    int* __restrict__ start,
                                                    int* __restrict__ off)
{
  __shared__ int part[1024];
  const int t = threadIdx.x;
  const int base = t * 16;
  int loc[16];
  int s = 0;
#pragma unroll
  for (int k = 0; k < 16; k++) { loc[k] = s; s += cnt[base + k]; }
  part[t] = s;
  __syncthreads();
  for (int d = 1; d < 1024; d <<= 1) {
    int v = (t >= d) ? part[t - d] : 0;
    __syncthreads();
    part[t] += v;
    __syncthreads();
  }
  int excl = (t == 0) ? 0 : part[t - 1];
#pragma unroll
  for (int k = 0; k < 16; k++) {
    int v = excl + loc[k];
    start[base + k] = v;
    off[base + k] = v;
  }
}

__global__ __launch_bounds__(256) void scatter_kernel(const int* __restrict__ ei,
                                                      int* __restrict__ off,
                                                      int* __restrict__ eperm)
{
  const int e = blockIdx.x * 256 + threadIdx.x;
  int rk = atomicAdd(&off[ei[NE + e]], 1);
  eperm[rk] = e;
}

// ---------------------------------------------------------------------------
// prep_B: hi/lo bf16 split planes. Bt[col][kp] hi; Bt[32+col][kp] lo.
// ---------------------------------------------------------------------------
__global__ __launch_bounds__(256) void prep_B_kernel(const float* __restrict__ w2v,
                                                     unsigned short* __restrict__ Bt)
{
  int t = blockIdx.x * 256 + threadIdx.x;   // 32*BKP threads
  int col = t / BKP, kp = t % BKP;
  float val = 0.f;
  if (kp < 384 && col < 24) {
    if (kp < 256) {
      int r = kp >> 4, i = kp & 15;
      if (col < 16) val = A_PATH * w2v[r * 576 + i * 16 + col];
      else          val = A_PATH * w2v[r * 576 + 384 + i * 8 + (col - 16)];
    } else {
      int k2 = kp - 256; int r = k2 >> 3, i = k2 & 7;
      if (col < 16) val = A_PATH * INV_SQRT3 * w2v[r * 576 + 256 + i * 16 + col];
      else          val = A_PATH * w2v[r * 576 + 512 + i * 8 + (col - 16)];
    }
  }
  short hi = f2bf(val);
  short lo = f2bf(val - bf2f(hi));
  Bt[t] = (unsigned short)hi;
  Bt[32 * BKP + t] = (unsigned short)lo;
}

// ---------------------------------------------------------------------------
// V-pass via MFMA, split-precision (round-5 verified, unchanged)
// ---------------------------------------------------------------------------
__global__ __launch_bounds__(256) void v_mfma_kernel(
    const int*   __restrict__ ei,
    const float* __restrict__ esh,
    const float* __restrict__ emb,
    const float* __restrict__ w1,      // fcv_w1
    const float* __restrict__ f,
    const float* __restrict__ expv,
    const float* __restrict__ z,
    const int*   __restrict__ eperm,
    const unsigned short* __restrict__ Bt,
    float* __restrict__ vbuf)
{
  __shared__ float h_s[64][17];
  __shared__ float fsT[16][65];
  __shared__ float fvT[24][65];
  __shared__ float scal[64][5];
  __shared__ __attribute__((aligned(16))) unsigned short BtL[64][BKP];
  __shared__ float rows[64][41];

  const int tid  = threadIdx.x;
  const int base = blockIdx.x * 64;

  // stage Bt (hi+lo planes) -> LDS (50 KB)
  {
    const unsigned* sp = reinterpret_cast<const unsigned*>(Bt);
    unsigned* dp = reinterpret_cast<unsigned*>(&BtL[0][0]);
    for (int i = tid; i < 64 * BKP / 2; i += 256) dp[i] = sp[i];
  }

  const int m = tid & 63;
  const int q = tid >> 6;
  const int e = eperm[base + m];

  if (q == 0) {
    int dn = ei[NE + e];
    float4 sh4 = reinterpret_cast<const float4*>(esh)[e];
    float zz = z[dn]; zz = (zz == 0.f) ? 1.f : zz;
    float ev = expv[e];
    float wgt = sqrtf(fmaxf(ev / zz, 0.f));
    scal[m][0] = sh4.x; scal[m][1] = sh4.y; scal[m][2] = sh4.z; scal[m][3] = sh4.w;
    scal[m][4] = wgt;
  } else if (q == 3) {
    int sn = ei[e];
    const float4* f4 = reinterpret_cast<const float4*>(f + (size_t)sn * DIM);
    float v[40];
#pragma unroll
    for (int i = 0; i < 10; i++) {
      float4 t = f4[i];
      v[4 * i] = t.x; v[4 * i + 1] = t.y; v[4 * i + 2] = t.z; v[4 * i + 3] = t.w;
    }
#pragma unroll
    for (int i = 0; i < 16; i++) fsT[i][m] = v[i];
#pragma unroll
    for (int k = 0; k < 24; k++) fvT[(k % 3) * 8 + (k / 3)][m] = v[16 + k];  // fvT[c*8+i]
  } else {
    // q=1: h[0..7], q=2: h[8..15]
    float el[10];
    const float2* e2 = reinterpret_cast<const float2*>(emb + (size_t)e * 10);
#pragma unroll
    for (int b = 0; b < 5; b++) { float2 t = e2[b]; el[2 * b] = t.x; el[2 * b + 1] = t.y; }
    const int j0 = (q == 1) ? 0 : 8;
#pragma unroll
    for (int jj = 0; jj < 8; jj++) {
      int j = j0 + jj;
      float a = 0.f;
#pragma unroll
      for (int b = 0; b < 10; b++) a += el[b] * w1[b * 16 + j];
      a *= INV_SQRT_NB;
      float sig = 1.0f / (1.0f + __expf(-a));
      h_s[m][j] = a * sig * H_SCALE;
    }
  }
  __syncthreads();

  // ---- MFMA phase: wave w computes its 16-edge M-tile (split precision) ----
  const int w    = tid >> 6;
  const int l    = tid & 63;
  const int row  = l & 15;
  const int kb   = l >> 4;
  const int mrow = w * 16 + row;
  const int col  = l & 15;

  f32x4 pfs0 = {0.f, 0.f, 0.f, 0.f}, pfs1 = {0.f, 0.f, 0.f, 0.f};
  f32x4 pc0_0 = {0.f, 0.f, 0.f, 0.f}, pc0_1 = {0.f, 0.f, 0.f, 0.f}, pc0_2 = {0.f, 0.f, 0.f, 0.f};
  f32x4 pc1_0 = {0.f, 0.f, 0.f, 0.f}, pc1_1 = {0.f, 0.f, 0.f, 0.f}, pc1_2 = {0.f, 0.f, 0.f, 0.f};

  // fs path: K=256, 8 K-steps. k = s*32 + kb*8 + j; r = k>>4, i = k&15.
#pragma unroll
  for (int s = 0; s < 8; s++) {
    const int r  = 2 * s + (kb >> 1);
    const int i0 = (kb & 1) * 8;
    const float hr = h_s[mrow][r];
    bf16x8 ah, al;
#pragma unroll
    for (int j = 0; j < 8; j++) {
      float v = hr * fsT[i0 + j][mrow];
      short hi = f2bf(v);
      ah[j] = hi;
      al[j] = f2bf(v - bf2f(hi));
    }
    const int k0 = s * 32 + kb * 8;
    bf16x8 bh0 = *reinterpret_cast<const bf16x8*>(&BtL[col][k0]);
    bf16x8 bh1 = *reinterpret_cast<const bf16x8*>(&BtL[16 + col][k0]);
    bf16x8 bl0 = *reinterpret_cast<const bf16x8*>(&BtL[32 + col][k0]);
    bf16x8 bl1 = *reinterpret_cast<const bf16x8*>(&BtL[48 + col][k0]);
    pfs0 = __builtin_amdgcn_mfma_f32_16x16x32_bf16(ah, bh0, pfs0, 0, 0, 0);
    pfs0 = __builtin_amdgcn_mfma_f32_16x16x32_bf16(al, bh0, pfs0, 0, 0, 0);
    pfs0 = __builtin_amdgcn_mfma_f32_16x16x32_bf16(ah, bl0, pfs0, 0, 0, 0);
    pfs1 = __builtin_amdgcn_mfma_f32_16x16x32_bf16(ah, bh1, pfs1, 0, 0, 0);
    pfs1 = __builtin_amdgcn_mfma_f32_16x16x32_bf16(al, bh1, pfs1, 0, 0, 0);
    pfs1 = __builtin_amdgcn_mfma_f32_16x16x32_bf16(ah, bl1, pfs1, 0, 0, 0);
  }

  // fv path: K=128 per c, 4 K-steps; r = 4s+kb, i = j.
#pragma unroll
  for (int s = 0; s < 4; s++) {
    const int r = 4 * s + kb;
    const float hr = h_s[mrow][r];
    const int k0 = 256 + s * 32 + kb * 8;
    bf16x8 bh0 = *reinterpret_cast<const bf16x8*>(&BtL[col][k0]);
    bf16x8 bh1 = *reinterpret_cast<const bf16x8*>(&BtL[16 + col][k0]);
    bf16x8 bl0 = *reinterpret_cast<const bf16x8*>(&BtL[32 + col][k0]);
    bf16x8 bl1 = *reinterpret_cast<const bf16x8*>(&BtL[48 + col][k0]);
#pragma unroll
    for (int c = 0; c < 3; c++) {
      bf16x8 ah, al;
#pragma unroll
      for (int j = 0; j < 8; j++) {
        float v = hr * fvT[c * 8 + j][mrow];
        short hi = f2bf(v);
        ah[j] = hi;
        al[j] = f2bf(v - bf2f(hi));
      }
      f32x4* p0 = (c == 0) ? &pc0_0 : (c == 1) ? &pc0_1 : &pc0_2;
      f32x4* p1 = (c == 0) ? &pc1_0 : (c == 1) ? &pc1_1 : &pc1_2;
      *p0 = __builtin_amdgcn_mfma_f32_16x16x32_bf16(ah, bh0, *p0, 0, 0, 0);
      *p0 = __builtin_amdgcn_mfma_f32_16x16x32_bf16(al, bh0, *p0, 0, 0, 0);
      *p0 = __builtin_amdgcn_mfma_f32_16x16x32_bf16(ah, bl0, *p0, 0, 0, 0);
      *p1 = __builtin_amdgcn_mfma_f32_16x16x32_bf16(ah, bh1, *p1, 0, 0, 0);
      *p1 = __builtin_amdgcn_mfma_f32_16x16x32_bf16(al, bh1, *p1, 0, 0, 0);
      *p1 = __builtin_amdgcn_mfma_f32_16x16x32_bf16(ah, bl1, *p1, 0, 0, 0);
    }
  }

  // ---- epilogue: combine with per-edge sh scalars, weighted rows -> LDS ----
#pragma unroll
  for (int j = 0; j < 4; j++) {
    const int me = w * 16 + kb * 4 + j;          // D row = (l>>4)*4 + reg
    const float sh0 = scal[me][0], sh1 = scal[me][1], sh2 = scal[me][2], sh3 = scal[me][3];
    const float wg = scal[me][4];
    float vsc = sh0 * pfs0[j] + sh1 * pc0_0[j] + sh2 * pc0_1[j] + sh3 * pc0_2[j];
    rows[me][col] = wg * vsc;
    if (col < 8) {
      rows[me][16 + col * 3 + 0] = wg * (sh1 * pfs1[j] + sh0 * pc1_0[j]);
      rows[me][16 + col * 3 + 1] = wg * (sh2 * pfs1[j] + sh0 * pc1_1[j]);
      rows[me][16 + col * 3 + 2] = wg * (sh3 * pfs1[j] + sh0 * pc1_2[j]);
    }
  }
  __syncthreads();

  // ---- copy rows to vbuf in sorted-rank order (coalesced) ----
  for (int idx = tid; idx < 64 * DIM; idx += 256) {
    int rr = idx / DIM, dd = idx % DIM;
    vbuf[(size_t)(base + rr) * DIM + dd] = rows[rr][dd];
  }
}

// ---------------------------------------------------------------------------
// Gather (round-2 verified verbatim)
// ---------------------------------------------------------------------------
__global__ __launch_bounds__(256) void gather_kernel(
    const float* __restrict__ vbuf,
    const int* __restrict__ start,
    const int* __restrict__ cnt,
    float* __restrict__ fout)
{
  const int tid = threadIdx.x;
  const int node = blockIdx.x * 4 + (tid >> 6);
  const int lane = tid & 63;
  if (lane >= DIM) return;
  const int s0 = start[node];
  const int c = cnt[node];
  float acc = 0.f;
  for (int j = 0; j < c; j++)
    acc += vbuf[(size_t)(s0 + j) * DIM + lane];
  fout[(size_t)node * DIM + lane] = acc;
}

extern "C" void kernel_launch(void* const* d_in, const int* in_sizes, int n_in,
                              void* d_out, int out_size, void* d_ws, size_t ws_size,
                              hipStream_t stream) {
  const float* f      = (const float*)d_in[0];
  const int*   ei     = (const int*)d_in[1];
  const float* elen   = (const float*)d_in[2];
  const float* esh    = (const float*)d_in[3];
  const float* emb    = (const float*)d_in[4];
  const float* Wq0    = (const float*)d_in[5];
  const float* Wq1    = (const float*)d_in[6];
  const float* fck_w1 = (const float*)d_in[7];
  const float* fck_w2 = (const float*)d_in[8];
  const float* fcv_w1 = (const float*)d_in[9];
  const float* fcv_w2 = (const float*)d_in[10];
  const float* Wd00   = (const float*)d_in[11];
  const float* Wd11   = (const float*)d_in[12];

  float* out = (float*)d_out;

  char* ws = (char*)d_ws;
  float* qq    = (float*)ws;  ws += (size_t)NN * 64 * 4;
  float* qd    = (float*)ws;  ws += (size_t)NN * DIM * 4;
  float* z     = (float*)ws;  ws += (size_t)NN * 4;
  float* expv  = (float*)ws;  ws += (size_t)NE * 4;
  int*   cnt   = (int*)ws;    ws += (size_t)NN * 4;
  int*   startb= (int*)ws;    ws += (size_t)NN * 4;
  int*   off   = (int*)ws;    ws += (size_t)NN * 4;
  int*   eperm = (int*)ws;    ws += (size_t)NE * 4;
  unsigned short* Bt = (unsigned short*)ws;  ws += (size_t)64 * BKP * 2;
  ws = (char*)(((size_t)ws + 255) & ~(size_t)255);
  float* vbuf  = (float*)ws;  // NE * DIM * 4 = 42 MB

  hipMemsetAsync(z, 0, (size_t)NN * 4, stream);
  hipMemsetAsync(cnt, 0, (size_t)NN * 4, stream);

  prep_B_kernel<<<32 * BKP / 256, 256, 0, stream>>>(fcv_w2, Bt);
  node_qd_kernel<<<NN / 256, 256, 0, stream>>>(f, Wq0, Wq1, Wd00, Wd11, qd);
  qq_kernel<<<1024, 256, 0, stream>>>(f, qd, fck_w2, qq);
  hist_kernel<<<NE / 256, 256, 0, stream>>>(ei, cnt);
  scan_kernel<<<1, 1024, 0, stream>>>(cnt, startb, off);
  scatter_kernel<<<NE / 256, 256, 0, stream>>>(ei, off, eperm);
  k_pass_kernel<<<NE / 256, 256, 0, stream>>>(ei, elen, esh, emb, fck_w1, qq, expv, z);
  v_mfma_kernel<<<NE / 64, 256, 0, stream>>>(ei, esh, emb, fcv_w1, f, expv, z,
                                             eperm, Bt, vbuf);
  gather_kernel<<<NN / 4, 256, 0, stream>>>(vbuf, startb, cnt, out);
}

// Round 9
// 202.485 us; speedup vs baseline: 1.8392x; 1.0658x over previous
//
#include <hip/hip_runtime.h>
#include <hip/hip_bf16.h>
#include <math.h>

namespace {
constexpr int NN  = 16384;
constexpr int NE  = 262144;
constexpr int DIM = 40;

constexpr float INV_SQRT3   = 0.5773502691896258f;
constexpr float A_PATH      = 0.2041241452319315f;      // 1/sqrt(24)
constexpr float INV_SQRT_NB = 0.31622776601683794f;     // 1/sqrt(10)
constexpr float H_SCALE     = 0.25f;                    // 1/sqrt(16)
constexpr float QSC_S       = 0.25f;
constexpr float QV_S        = 0.35355339059327373f;
constexpr float D00_S       = 1.0f / (16.0f * 1.4142135623730951f);
constexpr float D11_S       = 1.0f / (8.0f * 1.7320508075688772f * 1.4142135623730951f);

constexpr int BKP = 392;  // padded k-stride for Bt (bf16); 64*392*2 = 50176 B = 3136*16
}

typedef __attribute__((ext_vector_type(8))) short bf16x8;
typedef __attribute__((ext_vector_type(4))) float f32x4;

static __device__ inline short f2bf(float x) {
  __hip_bfloat16 h = __float2bfloat16(x);
  return __builtin_bit_cast(short, h);
}
static __device__ inline float bf2f(short b) {
  unsigned u = ((unsigned)(unsigned short)b) << 16;
  return __builtin_bit_cast(float, u);
}

static __device__ __forceinline__ void gload_lds16(const void* g, void* l) {
  __builtin_amdgcn_global_load_lds(
      (const __attribute__((address_space(1))) unsigned*)g,
      (__attribute__((address_space(3))) unsigned*)l, 16, 0, 0);
}

// ---------------------------------------------------------------------------
// node_qd (round-7 verified)
// ---------------------------------------------------------------------------
__global__ __launch_bounds__(256) void node_qd_kernel(
    const float* __restrict__ f,
    const float* __restrict__ Wq0, const float* __restrict__ Wq1,
    const float* __restrict__ Wd00, const float* __restrict__ Wd11,
    float* __restrict__ qd)
{
  const int n = blockIdx.x * 256 + threadIdx.x;

  float fs[16], fv[8][3];
  {
    const float4* fn4 = reinterpret_cast<const float4*>(f + (size_t)n * DIM);
#pragma unroll
    for (int i = 0; i < 10; i++) {
      float4 t = fn4[i];
      int base = i * 4;
#pragma unroll
      for (int k = 0; k < 4; k++) {
        float v = (k == 0) ? t.x : (k == 1) ? t.y : (k == 2) ? t.z : t.w;
        int idx = base + k;
        if (idx < 16) fs[idx] = v;
        else { int r = idx - 16; fv[r / 3][r % 3] = v; }
      }
    }
  }

  float out[40];
  {
    float qsc[16];
#pragma unroll
    for (int o = 0; o < 16; o++) {
      float a = 0.f;
#pragma unroll
      for (int i = 0; i < 16; i++) a += fs[i] * Wq0[i * 16 + o];
      qsc[o] = a * QSC_S;
    }
#pragma unroll
    for (int j = 0; j < 16; j++) {
      float a = 0.f;
#pragma unroll
      for (int i = 0; i < 16; i++) a += qsc[i] * Wd00[i * 16 + j];
      out[j] = a * D00_S;
    }
  }
  {
    float qv[8][3];
#pragma unroll
    for (int o = 0; o < 8; o++)
#pragma unroll
      for (int c = 0; c < 3; c++) {
        float a = 0.f;
#pragma unroll
        for (int i = 0; i < 8; i++) a += fv[i][c] * Wq1[i * 8 + o];
        qv[o][c] = a * QV_S;
      }
#pragma unroll
    for (int j = 0; j < 8; j++)
#pragma unroll
      for (int c = 0; c < 3; c++) {
        float a = 0.f;
#pragma unroll
        for (int i = 0; i < 8; i++) a += qv[i][c] * Wd11[i * 8 + j];
        out[16 + j * 3 + c] = a * D11_S;
      }
  }

  float4* op = reinterpret_cast<float4*>(qd + (size_t)n * DIM);
#pragma unroll
  for (int i = 0; i < 10; i++)
    op[i] = make_float4(out[4 * i], out[4 * i + 1], out[4 * i + 2], out[4 * i + 3]);
}

// ---------------------------------------------------------------------------
// qq_kernel (round-8 verified: r block-uniform -> scalar w2k reads)
// ---------------------------------------------------------------------------
__global__ __launch_bounds__(256) void qq_kernel(
    const float* __restrict__ f,
    const float* __restrict__ qd,
    const float* __restrict__ w2k,
    float* __restrict__ qq)
{
  const int r = blockIdx.x >> 6;                       // wave-uniform
  const int n = (blockIdx.x & 63) * 256 + threadIdx.x;

  float fs[16], fv[8][3];
  {
    const float4* fn4 = reinterpret_cast<const float4*>(f + (size_t)n * DIM);
#pragma unroll
    for (int i = 0; i < 10; i++) {
      float4 t = fn4[i];
      int base = i * 4;
#pragma unroll
      for (int k = 0; k < 4; k++) {
        float v = (k == 0) ? t.x : (k == 1) ? t.y : (k == 2) ? t.z : t.w;
        int idx = base + k;
        if (idx < 16) fs[idx] = v;
        else { int rr = idx - 16; fv[rr / 3][rr % 3] = v; }
      }
    }
  }
  float qd0[16], qdv[8][3];
  {
    const float4* qp = reinterpret_cast<const float4*>(qd + (size_t)n * DIM);
#pragma unroll
    for (int i = 0; i < 10; i++) {
      float4 t = qp[i];
      int base = i * 4;
#pragma unroll
      for (int k = 0; k < 4; k++) {
        float v = (k == 0) ? t.x : (k == 1) ? t.y : (k == 2) ? t.z : t.w;
        int idx = base + k;
        if (idx < 16) qd0[idx] = v;
        else { int rr = idx - 16; qdv[rr / 3][rr % 3] = v; }
      }
    }
  }

  const float* __restrict__ wr = w2k + (size_t)r * 576;  // scalar base
  float q0 = 0.f, qc0 = 0.f, qc1 = 0.f, qc2 = 0.f;

#pragma unroll
  for (int i = 0; i < 16; i++) {
    float t = 0.f;
#pragma unroll
    for (int o = 0; o < 16; o++) t += qd0[o] * wr[i * 16 + o];
    q0 += fs[i] * t;
  }
#pragma unroll
  for (int i = 0; i < 8; i++) {
    float t = 0.f;
#pragma unroll
    for (int o = 0; o < 16; o++) t += qd0[o] * wr[256 + i * 16 + o];
    t *= INV_SQRT3;
    qc0 += fv[i][0] * t; qc1 += fv[i][1] * t; qc2 += fv[i][2] * t;
  }
#pragma unroll
  for (int i = 0; i < 16; i++) {
    float t0 = 0.f, t1 = 0.f, t2 = 0.f;
#pragma unroll
    for (int o = 0; o < 8; o++) {
      float wk = wr[384 + i * 8 + o];
      t0 += qdv[o][0] * wk; t1 += qdv[o][1] * wk; t2 += qdv[o][2] * wk;
    }
    qc0 += fs[i] * t0; qc1 += fs[i] * t1; qc2 += fs[i] * t2;
  }
#pragma unroll
  for (int i = 0; i < 8; i++) {
    float t0 = 0.f, t1 = 0.f, t2 = 0.f;
#pragma unroll
    for (int o = 0; o < 8; o++) {
      float wk = wr[512 + i * 8 + o];
      t0 += qdv[o][0] * wk; t1 += qdv[o][1] * wk; t2 += qdv[o][2] * wk;
    }
    q0 += fv[i][0] * t0 + fv[i][1] * t1 + fv[i][2] * t2;
  }

  reinterpret_cast<float4*>(qq)[n * 16 + r] =
      make_float4(A_PATH * q0, A_PATH * qc0, A_PATH * qc1, A_PATH * qc2);
}

// ---------------------------------------------------------------------------
// Counting sort by dst; scatter emits eperm AND dst_sorted
// ---------------------------------------------------------------------------
__global__ __launch_bounds__(256) void hist_kernel(const int* __restrict__ ei,
                                                   int* __restrict__ cnt)
{
  const int e = blockIdx.x * 256 + threadIdx.x;
  atomicAdd(&cnt[ei[NE + e]], 1);
}

__global__ __launch_bounds__(1024) void scan_kernel(const int* __restrict__ cnt,
                                                    int* __restrict__ off)
{
  __shared__ int part[1024];
  const int t = threadIdx.x;
  const int base = t * 16;
  int loc[16];
  int s = 0;
#pragma unroll
  for (int k = 0; k < 16; k++) { loc[k] = s; s += cnt[base + k]; }
  part[t] = s;
  __syncthreads();
  for (int d = 1; d < 1024; d <<= 1) {
    int v = (t >= d) ? part[t - d] : 0;
    __syncthreads();
    part[t] += v;
    __syncthreads();
  }
  int excl = (t == 0) ? 0 : part[t - 1];
#pragma unroll
  for (int k = 0; k < 16; k++) off[base + k] = excl + loc[k];
}

__global__ __launch_bounds__(256) void scatter_kernel(const int* __restrict__ ei,
                                                      int* __restrict__ off,
                                                      int* __restrict__ eperm,
                                                      int* __restrict__ dst_sorted)
{
  const int e = blockIdx.x * 256 + threadIdx.x;
  const int dst = ei[NE + e];
  int rk = atomicAdd(&off[dst], 1);
  eperm[rk] = e;
  dst_sorted[rk] = dst;
}

// ---------------------------------------------------------------------------
// K-pass over SORTED ranks: qq[dst] reads become sequential/broadcast;
// expv written by rank (linear read in v_mfma).
// ---------------------------------------------------------------------------
__global__ __launch_bounds__(256) void k_pass_kernel(
    const int*   __restrict__ eperm,
    const int*   __restrict__ dst_sorted,
    const float* __restrict__ elen,
    const float* __restrict__ esh,
    const float* __restrict__ emb,
    const float* __restrict__ w1,
    const float* __restrict__ qq,
    float* __restrict__ expv,
    float* __restrict__ z)
{
  const int rk = blockIdx.x * 256 + threadIdx.x;
  const int e = eperm[rk];
  const int dst = dst_sorted[rk];

  float el[10];
  const float2* e2 = reinterpret_cast<const float2*>(emb + (size_t)e * 10);
#pragma unroll
  for (int b = 0; b < 5; b++) { float2 t = e2[b]; el[2 * b] = t.x; el[2 * b + 1] = t.y; }

  float h[16];
#pragma unroll
  for (int j = 0; j < 16; j++) {
    float a = 0.f;
#pragma unroll
    for (int b = 0; b < 10; b++) a += el[b] * w1[b * 16 + j];
    a *= INV_SQRT_NB;
    float sig = 1.0f / (1.0f + __expf(-a));
    h[j] = a * sig * H_SCALE;
  }

  float4 sh4 = reinterpret_cast<const float4*>(esh)[e];
  const float4* q4 = reinterpret_cast<const float4*>(qq + (size_t)dst * 64);
  float s = 0.f;
#pragma unroll
  for (int r = 0; r < 16; r++) {
    float4 qv = q4[r];
    s += h[r] * (sh4.x * qv.x + sh4.y * qv.y + sh4.z * qv.z + sh4.w * qv.w);
  }

  float len = elen[e];
  float x = 10.0f * (1.0f - len * (1.0f / 1.3f));
  float cut = (x > 0.f) ? __expf(-1.0f / x) : 0.f;
  float ev = cut * __expf(s);
  expv[rk] = ev;
  atomicAdd(&z[dst], ev);
}

// ---------------------------------------------------------------------------
// prep_B: hi/lo bf16 split planes (round-5 verified)
// ---------------------------------------------------------------------------
__global__ __launch_bounds__(256) void prep_B_kernel(const float* __restrict__ w2v,
                                                     unsigned short* __restrict__ Bt)
{
  int t = blockIdx.x * 256 + threadIdx.x;   // 32*BKP threads
  int col = t / BKP, kp = t % BKP;
  float val = 0.f;
  if (kp < 384 && col < 24) {
    if (kp < 256) {
      int r = kp >> 4, i = kp & 15;
      if (col < 16) val = A_PATH * w2v[r * 576 + i * 16 + col];
      else          val = A_PATH * w2v[r * 576 + 384 + i * 8 + (col - 16)];
    } else {
      int k2 = kp - 256; int r = k2 >> 3, i = k2 & 7;
      if (col < 16) val = A_PATH * INV_SQRT3 * w2v[r * 576 + 256 + i * 16 + col];
      else          val = A_PATH * w2v[r * 576 + 512 + i * 8 + (col - 16)];
    }
  }
  short hi = f2bf(val);
  short lo = f2bf(val - bf2f(hi));
  Bt[t] = (unsigned short)hi;
  Bt[32 * BKP + t] = (unsigned short)lo;
}

// ---------------------------------------------------------------------------
// V-pass via MFMA (round-5 verified compute) + global_load_lds staging +
// in-block segmented reduction over sorted dst (direct f_out write).
// ---------------------------------------------------------------------------
__global__ __launch_bounds__(256) void v_mfma_kernel(
    const int*   __restrict__ ei,
    const float* __restrict__ esh,
    const float* __restrict__ emb,
    const float* __restrict__ w1,      // fcv_w1
    const float* __restrict__ f,
    const float* __restrict__ expv,    // by rank
    const float* __restrict__ z,
    const int*   __restrict__ eperm,
    const int*   __restrict__ dst_sorted,
    const unsigned short* __restrict__ Bt,
    float* __restrict__ fout)
{
  __shared__ float h_s[64][17];
  __shared__ float fsT[16][65];
  __shared__ float fvT[24][65];
  __shared__ float scal[64][5];
  __shared__ int   nid[64];
  __shared__ __attribute__((aligned(16))) unsigned short BtL[64][BKP];
  __shared__ float rows[64][41];
  __shared__ int seg_start[64], seg_len[64], seg_nid[64];
  __shared__ int nseg_s;

  const int tid  = threadIdx.x;
  const int base = blockIdx.x * 64;

  // stage Bt (hi+lo planes) -> LDS via async global_load_lds (50176 B)
  {
    const char* src = (const char*)Bt;
    char* dst = (char*)&BtL[0][0];
    const int wid = tid >> 6, lid = tid & 63;
#pragma unroll
    for (int i = 0; i < 12; i++) {
      int off = i * 4096 + wid * 1024 + lid * 16;
      gload_lds16(src + off, dst + off);
    }
    if (wid == 0) {
      int off = 49152 + lid * 16;
      gload_lds16(src + off, dst + off);
    }
  }

  const int m = tid & 63;
  const int q = tid >> 6;
  const int e = eperm[base + m];

  if (q == 0) {
    int dn = dst_sorted[base + m];
    float4 sh4 = reinterpret_cast<const float4*>(esh)[e];
    float zz = z[dn]; zz = (zz == 0.f) ? 1.f : zz;
    float ev = expv[base + m];
    float wgt = sqrtf(fmaxf(ev / zz, 0.f));
    scal[m][0] = sh4.x; scal[m][1] = sh4.y; scal[m][2] = sh4.z; scal[m][3] = sh4.w;
    scal[m][4] = wgt;
    nid[m] = dn;
  } else if (q == 3) {
    int sn = ei[e];
    const float4* f4 = reinterpret_cast<const float4*>(f + (size_t)sn * DIM);
    float v[40];
#pragma unroll
    for (int i = 0; i < 10; i++) {
      float4 t = f4[i];
      v[4 * i] = t.x; v[4 * i + 1] = t.y; v[4 * i + 2] = t.z; v[4 * i + 3] = t.w;
    }
#pragma unroll
    for (int i = 0; i < 16; i++) fsT[i][m] = v[i];
#pragma unroll
    for (int k = 0; k < 24; k++) fvT[(k % 3) * 8 + (k / 3)][m] = v[16 + k];  // fvT[c*8+i]
  } else {
    // q=1: h[0..7], q=2: h[8..15]
    float el[10];
    const float2* e2 = reinterpret_cast<const float2*>(emb + (size_t)e * 10);
#pragma unroll
    for (int b = 0; b < 5; b++) { float2 t = e2[b]; el[2 * b] = t.x; el[2 * b + 1] = t.y; }
    const int j0 = (q == 1) ? 0 : 8;
#pragma unroll
    for (int jj = 0; jj < 8; jj++) {
      int j = j0 + jj;
      float a = 0.f;
#pragma unroll
      for (int b = 0; b < 10; b++) a += el[b] * w1[b * 16 + j];
      a *= INV_SQRT_NB;
      float sig = 1.0f / (1.0f + __expf(-a));
      h_s[m][j] = a * sig * H_SCALE;
    }
  }
  __syncthreads();

  // ---- MFMA phase (round-5 verified, byte-identical) ----
  const int w    = tid >> 6;
  const int l    = tid & 63;
  const int row  = l & 15;
  const int kb   = l >> 4;
  const int mrow = w * 16 + row;
  const int col  = l & 15;

  f32x4 pfs0 = {0.f, 0.f, 0.f, 0.f}, pfs1 = {0.f, 0.f, 0.f, 0.f};
  f32x4 pc0_0 = {0.f, 0.f, 0.f, 0.f}, pc0_1 = {0.f, 0.f, 0.f, 0.f}, pc0_2 = {0.f, 0.f, 0.f, 0.f};
  f32x4 pc1_0 = {0.f, 0.f, 0.f, 0.f}, pc1_1 = {0.f, 0.f, 0.f, 0.f}, pc1_2 = {0.f, 0.f, 0.f, 0.f};

  // fs path: K=256, 8 K-steps. k = s*32 + kb*8 + j; r = k>>4, i = k&15.
#pragma unroll
  for (int s = 0; s < 8; s++) {
    const int r  = 2 * s + (kb >> 1);
    const int i0 = (kb & 1) * 8;
    const float hr = h_s[mrow][r];
    bf16x8 ah, al;
#pragma unroll
    for (int j = 0; j < 8; j++) {
      float v = hr * fsT[i0 + j][mrow];
      short hi = f2bf(v);
      ah[j] = hi;
      al[j] = f2bf(v - bf2f(hi));
    }
    const int k0 = s * 32 + kb * 8;
    bf16x8 bh0 = *reinterpret_cast<const bf16x8*>(&BtL[col][k0]);
    bf16x8 bh1 = *reinterpret_cast<const bf16x8*>(&BtL[16 + col][k0]);
    bf16x8 bl0 = *reinterpret_cast<const bf16x8*>(&BtL[32 + col][k0]);
    bf16x8 bl1 = *reinterpret_cast<const bf16x8*>(&BtL[48 + col][k0]);
    pfs0 = __builtin_amdgcn_mfma_f32_16x16x32_bf16(ah, bh0, pfs0, 0, 0, 0);
    pfs0 = __builtin_amdgcn_mfma_f32_16x16x32_bf16(al, bh0, pfs0, 0, 0, 0);
    pfs0 = __builtin_amdgcn_mfma_f32_16x16x32_bf16(ah, bl0, pfs0, 0, 0, 0);
    pfs1 = __builtin_amdgcn_mfma_f32_16x16x32_bf16(ah, bh1, pfs1, 0, 0, 0);
    pfs1 = __builtin_amdgcn_mfma_f32_16x16x32_bf16(al, bh1, pfs1, 0, 0, 0);
    pfs1 = __builtin_amdgcn_mfma_f32_16x16x32_bf16(ah, bl1, pfs1, 0, 0, 0);
  }

  // fv path: K=128 per c, 4 K-steps; r = 4s+kb, i = j.
#pragma unroll
  for (int s = 0; s < 4; s++) {
    const int r = 4 * s + kb;
    const float hr = h_s[mrow][r];
    const int k0 = 256 + s * 32 + kb * 8;
    bf16x8 bh0 = *reinterpret_cast<const bf16x8*>(&BtL[col][k0]);
    bf16x8 bh1 = *reinterpret_cast<const bf16x8*>(&BtL[16 + col][k0]);
    bf16x8 bl0 = *reinterpret_cast<const bf16x8*>(&BtL[32 + col][k0]);
    bf16x8 bl1 = *reinterpret_cast<const bf16x8*>(&BtL[48 + col][k0]);
#pragma unroll
    for (int c = 0; c < 3; c++) {
      bf16x8 ah, al;
#pragma unroll
      for (int j = 0; j < 8; j++) {
        float v = hr * fvT[c * 8 + j][mrow];
        short hi = f2bf(v);
        ah[j] = hi;
        al[j] = f2bf(v - bf2f(hi));
      }
      f32x4* p0 = (c == 0) ? &pc0_0 : (c == 1) ? &pc0_1 : &pc0_2;
      f32x4* p1 = (c == 0) ? &pc1_0 : (c == 1) ? &pc1_1 : &pc1_2;
      *p0 = __builtin_amdgcn_mfma_f32_16x16x32_bf16(ah, bh0, *p0, 0, 0, 0);
      *p0 = __builtin_amdgcn_mfma_f32_16x16x32_bf16(al, bh0, *p0, 0, 0, 0);
      *p0 = __builtin_amdgcn_mfma_f32_16x16x32_bf16(ah, bl0, *p0, 0, 0, 0);
      *p1 = __builtin_amdgcn_mfma_f32_16x16x32_bf16(ah, bh1, *p1, 0, 0, 0);
      *p1 = __builtin_amdgcn_mfma_f32_16x16x32_bf16(al, bh1, *p1, 0, 0, 0);
      *p1 = __builtin_amdgcn_mfma_f32_16x16x32_bf16(ah, bl1, *p1, 0, 0, 0);
    }
  }

  // ---- epilogue: combine with per-edge sh scalars, weighted rows -> LDS ----
#pragma unroll
  for (int j = 0; j < 4; j++) {
    const int me = w * 16 + kb * 4 + j;          // D row = (l>>4)*4 + reg
    const float sh0 = scal[me][0], sh1 = scal[me][1], sh2 = scal[me][2], sh3 = scal[me][3];
    const float wg = scal[me][4];
    float vsc = sh0 * pfs0[j] + sh1 * pc0_0[j] + sh2 * pc0_1[j] + sh3 * pc0_2[j];
    rows[me][col] = wg * vsc;
    if (col < 8) {
      rows[me][16 + col * 3 + 0] = wg * (sh1 * pfs1[j] + sh0 * pc1_0[j]);
      rows[me][16 + col * 3 + 1] = wg * (sh2 * pfs1[j] + sh0 * pc1_1[j]);
      rows[me][16 + col * 3 + 2] = wg * (sh3 * pfs1[j] + sh0 * pc1_2[j]);
    }
  }
  __syncthreads();

  // ---- segmented reduction over sorted dst (direct f_out write) ----
  if (tid < 64) {
    bool head = (m == 0) || (nid[m] != nid[m - 1]);
    unsigned long long mask = __ballot(head);
    if (tid == 0) nseg_s = __popcll(mask);
    if (head) {
      int idx = __popcll(mask & ((1ull << m) - 1ull));
      unsigned long long higher = (m == 63) ? 0ull : (mask >> (m + 1));
      int len = higher ? __ffsll((long long)higher) : (64 - m);
      seg_start[idx] = m; seg_len[idx] = len; seg_nid[idx] = nid[m];
    }
  }
  __syncthreads();

  const int nseg = nseg_s;
  const int d = tid & 63;
  const int g = tid >> 6;
  if (d < DIM) {
    for (int s = g; s < nseg; s += 4) {
      const int st = seg_start[s], ln = seg_len[s];
      float acc = 0.f;
      for (int k2 = 0; k2 < ln; k2++) acc += rows[st + k2][d];
      float* fo = &fout[(size_t)seg_nid[s] * DIM + d];
      if (s > 0 && s < nseg - 1) *fo = acc;   // node fully inside this block
      else atomicAdd(fo, acc);                // may span block boundary
    }
  }
}

extern "C" void kernel_launch(void* const* d_in, const int* in_sizes, int n_in,
                              void* d_out, int out_size, void* d_ws, size_t ws_size,
                              hipStream_t stream) {
  const float* f      = (const float*)d_in[0];
  const int*   ei     = (const int*)d_in[1];
  const float* elen   = (const float*)d_in[2];
  const float* esh    = (const float*)d_in[3];
  const float* emb    = (const float*)d_in[4];
  const float* Wq0    = (const float*)d_in[5];
  const float* Wq1    = (const float*)d_in[6];
  const float* fck_w1 = (const float*)d_in[7];
  const float* fck_w2 = (const float*)d_in[8];
  const float* fcv_w1 = (const float*)d_in[9];
  const float* fcv_w2 = (const float*)d_in[10];
  const float* Wd00   = (const float*)d_in[11];
  const float* Wd11   = (const float*)d_in[12];

  float* out = (float*)d_out;

  char* ws = (char*)d_ws;
  float* qq     = (float*)ws;  ws += (size_t)NN * 64 * 4;
  float* qd     = (float*)ws;  ws += (size_t)NN * DIM * 4;
  float* z      = (float*)ws;  ws += (size_t)NN * 4;
  float* expv   = (float*)ws;  ws += (size_t)NE * 4;
  int*   cnt    = (int*)ws;    ws += (size_t)NN * 4;
  int*   off    = (int*)ws;    ws += (size_t)NN * 4;
  int*   eperm  = (int*)ws;    ws += (size_t)NE * 4;
  int*   dsts   = (int*)ws;    ws += (size_t)NE * 4;
  unsigned short* Bt = (unsigned short*)ws;  ws += (size_t)64 * BKP * 2;

  hipMemsetAsync(z, 0, (size_t)NN * 4, stream);
  hipMemsetAsync(cnt, 0, (size_t)NN * 4, stream);
  hipMemsetAsync(out, 0, (size_t)NN * DIM * 4, stream);

  prep_B_kernel<<<32 * BKP / 256, 256, 0, stream>>>(fcv_w2, Bt);
  node_qd_kernel<<<NN / 256, 256, 0, stream>>>(f, Wq0, Wq1, Wd00, Wd11, qd);
  qq_kernel<<<1024, 256, 0, stream>>>(f, qd, fck_w2, qq);
  hist_kernel<<<NE / 256, 256, 0, stream>>>(ei, cnt);
  scan_kernel<<<1, 1024, 0, stream>>>(cnt, off);
  scatter_kernel<<<NE / 256, 256, 0, stream>>>(ei, off, eperm, dsts);
  k_pass_kernel<<<NE / 256, 256, 0, stream>>>(eperm, dsts, elen, esh, emb,
                                              fck_w1, qq, expv, z);
  v_mfma_kernel<<<NE / 64, 256, 0, stream>>>(ei, esh, emb, fcv_w1, f, expv, z,
                                             eperm, dsts, Bt, out);
}

// Round 10
// 181.271 us; speedup vs baseline: 2.0544x; 1.1170x over previous
//
#include <hip/hip_runtime.h>
#include <hip/hip_bf16.h>
#include <math.h>

namespace {
constexpr int NN  = 16384;
constexpr int NE  = 262144;
constexpr int DIM = 40;

constexpr float INV_SQRT3   = 0.5773502691896258f;
constexpr float A_PATH      = 0.2041241452319315f;      // 1/sqrt(24)
constexpr float INV_SQRT_NB = 0.31622776601683794f;     // 1/sqrt(10)
constexpr float H_SCALE     = 0.25f;                    // 1/sqrt(16)
constexpr float QSC_S       = 0.25f;
constexpr float QV_S        = 0.35355339059327373f;
constexpr float D00_S       = 1.0f / (16.0f * 1.4142135623730951f);
constexpr float D11_S       = 1.0f / (8.0f * 1.7320508075688772f * 1.4142135623730951f);

constexpr int BKP = 392;  // padded k-stride for Bt (fp16); 32*392*2 = 25088 B = 1568*16
}

typedef __attribute__((ext_vector_type(8))) _Float16 f16x8;
typedef __attribute__((ext_vector_type(4))) float f32x4;

static __device__ __forceinline__ void gload_lds16(const void* g, void* l) {
  __builtin_amdgcn_global_load_lds(
      (const __attribute__((address_space(1))) unsigned*)g,
      (__attribute__((address_space(3))) unsigned*)l, 16, 0, 0);
}

// ---------------------------------------------------------------------------
// node_qd (round-7 verified)
// ---------------------------------------------------------------------------
__global__ __launch_bounds__(256) void node_qd_kernel(
    const float* __restrict__ f,
    const float* __restrict__ Wq0, const float* __restrict__ Wq1,
    const float* __restrict__ Wd00, const float* __restrict__ Wd11,
    float* __restrict__ qd)
{
  const int n = blockIdx.x * 256 + threadIdx.x;

  float fs[16], fv[8][3];
  {
    const float4* fn4 = reinterpret_cast<const float4*>(f + (size_t)n * DIM);
#pragma unroll
    for (int i = 0; i < 10; i++) {
      float4 t = fn4[i];
      int base = i * 4;
#pragma unroll
      for (int k = 0; k < 4; k++) {
        float v = (k == 0) ? t.x : (k == 1) ? t.y : (k == 2) ? t.z : t.w;
        int idx = base + k;
        if (idx < 16) fs[idx] = v;
        else { int r = idx - 16; fv[r / 3][r % 3] = v; }
      }
    }
  }

  float out[40];
  {
    float qsc[16];
#pragma unroll
    for (int o = 0; o < 16; o++) {
      float a = 0.f;
#pragma unroll
      for (int i = 0; i < 16; i++) a += fs[i] * Wq0[i * 16 + o];
      qsc[o] = a * QSC_S;
    }
#pragma unroll
    for (int j = 0; j < 16; j++) {
      float a = 0.f;
#pragma unroll
      for (int i = 0; i < 16; i++) a += qsc[i] * Wd00[i * 16 + j];
      out[j] = a * D00_S;
    }
  }
  {
    float qv[8][3];
#pragma unroll
    for (int o = 0; o < 8; o++)
#pragma unroll
      for (int c = 0; c < 3; c++) {
        float a = 0.f;
#pragma unroll
        for (int i = 0; i < 8; i++) a += fv[i][c] * Wq1[i * 8 + o];
        qv[o][c] = a * QV_S;
      }
#pragma unroll
    for (int j = 0; j < 8; j++)
#pragma unroll
      for (int c = 0; c < 3; c++) {
        float a = 0.f;
#pragma unroll
        for (int i = 0; i < 8; i++) a += qv[i][c] * Wd11[i * 8 + j];
        out[16 + j * 3 + c] = a * D11_S;
      }
  }

  float4* op = reinterpret_cast<float4*>(qd + (size_t)n * DIM);
#pragma unroll
  for (int i = 0; i < 10; i++)
    op[i] = make_float4(out[4 * i], out[4 * i + 1], out[4 * i + 2], out[4 * i + 3]);
}

// ---------------------------------------------------------------------------
// qq_kernel (round-8 verified: r block-uniform -> scalar w2k reads)
// ---------------------------------------------------------------------------
__global__ __launch_bounds__(256) void qq_kernel(
    const float* __restrict__ f,
    const float* __restrict__ qd,
    const float* __restrict__ w2k,
    float* __restrict__ qq)
{
  const int r = blockIdx.x >> 6;                       // wave-uniform
  const int n = (blockIdx.x & 63) * 256 + threadIdx.x;

  float fs[16], fv[8][3];
  {
    const float4* fn4 = reinterpret_cast<const float4*>(f + (size_t)n * DIM);
#pragma unroll
    for (int i = 0; i < 10; i++) {
      float4 t = fn4[i];
      int base = i * 4;
#pragma unroll
      for (int k = 0; k < 4; k++) {
        float v = (k == 0) ? t.x : (k == 1) ? t.y : (k == 2) ? t.z : t.w;
        int idx = base + k;
        if (idx < 16) fs[idx] = v;
        else { int rr = idx - 16; fv[rr / 3][rr % 3] = v; }
      }
    }
  }
  float qd0[16], qdv[8][3];
  {
    const float4* qp = reinterpret_cast<const float4*>(qd + (size_t)n * DIM);
#pragma unroll
    for (int i = 0; i < 10; i++) {
      float4 t = qp[i];
      int base = i * 4;
#pragma unroll
      for (int k = 0; k < 4; k++) {
        float v = (k == 0) ? t.x : (k == 1) ? t.y : (k == 2) ? t.z : t.w;
        int idx = base + k;
        if (idx < 16) qd0[idx] = v;
        else { int rr = idx - 16; qdv[rr / 3][rr % 3] = v; }
      }
    }
  }

  const float* __restrict__ wr = w2k + (size_t)r * 576;  // scalar base
  float q0 = 0.f, qc0 = 0.f, qc1 = 0.f, qc2 = 0.f;

#pragma unroll
  for (int i = 0; i < 16; i++) {
    float t = 0.f;
#pragma unroll
    for (int o = 0; o < 16; o++) t += qd0[o] * wr[i * 16 + o];
    q0 += fs[i] * t;
  }
#pragma unroll
  for (int i = 0; i < 8; i++) {
    float t = 0.f;
#pragma unroll
    for (int o = 0; o < 16; o++) t += qd0[o] * wr[256 + i * 16 + o];
    t *= INV_SQRT3;
    qc0 += fv[i][0] * t; qc1 += fv[i][1] * t; qc2 += fv[i][2] * t;
  }
#pragma unroll
  for (int i = 0; i < 16; i++) {
    float t0 = 0.f, t1 = 0.f, t2 = 0.f;
#pragma unroll
    for (int o = 0; o < 8; o++) {
      float wk = wr[384 + i * 8 + o];
      t0 += qdv[o][0] * wk; t1 += qdv[o][1] * wk; t2 += qdv[o][2] * wk;
    }
    qc0 += fs[i] * t0; qc1 += fs[i] * t1; qc2 += fs[i] * t2;
  }
#pragma unroll
  for (int i = 0; i < 8; i++) {
    float t0 = 0.f, t1 = 0.f, t2 = 0.f;
#pragma unroll
    for (int o = 0; o < 8; o++) {
      float wk = wr[512 + i * 8 + o];
      t0 += qdv[o][0] * wk; t1 += qdv[o][1] * wk; t2 += qdv[o][2] * wk;
    }
    q0 += fv[i][0] * t0 + fv[i][1] * t1 + fv[i][2] * t2;
  }

  reinterpret_cast<float4*>(qq)[n * 16 + r] =
      make_float4(A_PATH * q0, A_PATH * qc0, A_PATH * qc1, A_PATH * qc2);
}

// ---------------------------------------------------------------------------
// Counting sort by dst; scatter emits eperm AND dst_sorted
// ---------------------------------------------------------------------------
__global__ __launch_bounds__(256) void hist_kernel(const int* __restrict__ ei,
                                                   int* __restrict__ cnt)
{
  const int e = blockIdx.x * 256 + threadIdx.x;
  atomicAdd(&cnt[ei[NE + e]], 1);
}

__global__ __launch_bounds__(1024) void scan_kernel(const int* __restrict__ cnt,
                                                    int* __restrict__ off)
{
  __shared__ int part[1024];
  const int t = threadIdx.x;
  const int base = t * 16;
  int loc[16];
  int s = 0;
#pragma unroll
  for (int k = 0; k < 16; k++) { loc[k] = s; s += cnt[base + k]; }
  part[t] = s;
  __syncthreads();
  for (int d = 1; d < 1024; d <<= 1) {
    int v = (t >= d) ? part[t - d] : 0;
    __syncthreads();
    part[t] += v;
    __syncthreads();
  }
  int excl = (t == 0) ? 0 : part[t - 1];
#pragma unroll
  for (int k = 0; k < 16; k++) off[base + k] = excl + loc[k];
}

__global__ __launch_bounds__(256) void scatter_kernel(const int* __restrict__ ei,
                                                      int* __restrict__ off,
                                                      int* __restrict__ eperm,
                                                      int* __restrict__ dst_sorted)
{
  const int e = blockIdx.x * 256 + threadIdx.x;
  const int dst = ei[NE + e];
  int rk = atomicAdd(&off[dst], 1);
  eperm[rk] = e;
  dst_sorted[rk] = dst;
}

// ---------------------------------------------------------------------------
// K-pass over SORTED ranks (round-9 verified)
// ---------------------------------------------------------------------------
__global__ __launch_bounds__(256) void k_pass_kernel(
    const int*   __restrict__ eperm,
    const int*   __restrict__ dst_sorted,
    const float* __restrict__ elen,
    const float* __restrict__ esh,
    const float* __restrict__ emb,
    const float* __restrict__ w1,
    const float* __restrict__ qq,
    float* __restrict__ expv,
    float* __restrict__ z)
{
  const int rk = blockIdx.x * 256 + threadIdx.x;
  const int e = eperm[rk];
  const int dst = dst_sorted[rk];

  float el[10];
  const float2* e2 = reinterpret_cast<const float2*>(emb + (size_t)e * 10);
#pragma unroll
  for (int b = 0; b < 5; b++) { float2 t = e2[b]; el[2 * b] = t.x; el[2 * b + 1] = t.y; }

  float h[16];
#pragma unroll
  for (int j = 0; j < 16; j++) {
    float a = 0.f;
#pragma unroll
    for (int b = 0; b < 10; b++) a += el[b] * w1[b * 16 + j];
    a *= INV_SQRT_NB;
    float sig = 1.0f / (1.0f + __expf(-a));
    h[j] = a * sig * H_SCALE;
  }

  float4 sh4 = reinterpret_cast<const float4*>(esh)[e];
  const float4* q4 = reinterpret_cast<const float4*>(qq + (size_t)dst * 64);
  float s = 0.f;
#pragma unroll
  for (int r = 0; r < 16; r++) {
    float4 qv = q4[r];
    s += h[r] * (sh4.x * qv.x + sh4.y * qv.y + sh4.z * qv.z + sh4.w * qv.w);
  }

  float len = elen[e];
  float x = 10.0f * (1.0f - len * (1.0f / 1.3f));
  float cut = (x > 0.f) ? __expf(-1.0f / x) : 0.f;
  float ev = cut * __expf(s);
  expv[rk] = ev;
  atomicAdd(&z[dst], ev);
}

// ---------------------------------------------------------------------------
// prep_B: single fp16 plane (11 mantissa bits; error 8x below bf16 single)
// ---------------------------------------------------------------------------
__global__ __launch_bounds__(256) void prep_B_kernel(const float* __restrict__ w2v,
                                                     unsigned short* __restrict__ Bt)
{
  int t = blockIdx.x * 256 + threadIdx.x;   // 32*BKP threads
  int col = t / BKP, kp = t % BKP;
  float val = 0.f;
  if (kp < 384 && col < 24) {
    if (kp < 256) {
      int r = kp >> 4, i = kp & 15;
      if (col < 16) val = A_PATH * w2v[r * 576 + i * 16 + col];
      else          val = A_PATH * w2v[r * 576 + 384 + i * 8 + (col - 16)];
    } else {
      int k2 = kp - 256; int r = k2 >> 3, i = k2 & 7;
      if (col < 16) val = A_PATH * INV_SQRT3 * w2v[r * 576 + 256 + i * 16 + col];
      else          val = A_PATH * w2v[r * 576 + 512 + i * 8 + (col - 16)];
    }
  }
  _Float16 hv = (_Float16)val;
  Bt[t] = __builtin_bit_cast(unsigned short, hv);
}

// ---------------------------------------------------------------------------
// V-pass via fp16 MFMA (single plane) + global_load_lds staging +
// in-block segmented reduction over sorted dst (round-9 verified tail).
// LDS ~52.6 KB -> 3 blocks/CU.
// ---------------------------------------------------------------------------
__global__ __launch_bounds__(256) void v_mfma_kernel(
    const int*   __restrict__ ei,
    const float* __restrict__ esh,
    const float* __restrict__ emb,
    const float* __restrict__ w1,      // fcv_w1
    const float* __restrict__ f,
    const float* __restrict__ expv,    // by rank
    const float* __restrict__ z,
    const int*   __restrict__ eperm,
    const int*   __restrict__ dst_sorted,
    const unsigned short* __restrict__ Bt,
    float* __restrict__ fout)
{
  __shared__ float h_s[64][17];
  __shared__ float fsT[16][65];
  __shared__ float fvT[24][65];
  __shared__ float scal[64][5];
  __shared__ int   nid[64];
  __shared__ __attribute__((aligned(16))) unsigned short BtL[32][BKP];
  __shared__ float rows[64][41];
  __shared__ int seg_start[64], seg_len[64], seg_nid[64];
  __shared__ int nseg_s;

  const int tid  = threadIdx.x;
  const int base = blockIdx.x * 64;

  // stage Bt (single fp16 plane) -> LDS via async global_load_lds (25088 B)
  {
    const char* src = (const char*)Bt;
    char* dst = (char*)&BtL[0][0];
#pragma unroll
    for (int k = 0; k < 6; k++) {
      int off = (k * 256 + tid) * 16;
      gload_lds16(src + off, dst + off);
    }
    if (tid < 32) {
      int off = (1536 + tid) * 16;
      gload_lds16(src + off, dst + off);
    }
  }

  const int m = tid & 63;
  const int q = tid >> 6;
  const int e = eperm[base + m];

  if (q == 0) {
    int dn = dst_sorted[base + m];
    float4 sh4 = reinterpret_cast<const float4*>(esh)[e];
    float zz = z[dn]; zz = (zz == 0.f) ? 1.f : zz;
    float ev = expv[base + m];
    float wgt = sqrtf(fmaxf(ev / zz, 0.f));
    scal[m][0] = sh4.x; scal[m][1] = sh4.y; scal[m][2] = sh4.z; scal[m][3] = sh4.w;
    scal[m][4] = wgt;
    nid[m] = dn;
  } else if (q == 3) {
    int sn = ei[e];
    const float4* f4 = reinterpret_cast<const float4*>(f + (size_t)sn * DIM);
    float v[40];
#pragma unroll
    for (int i = 0; i < 10; i++) {
      float4 t = f4[i];
      v[4 * i] = t.x; v[4 * i + 1] = t.y; v[4 * i + 2] = t.z; v[4 * i + 3] = t.w;
    }
#pragma unroll
    for (int i = 0; i < 16; i++) fsT[i][m] = v[i];
#pragma unroll
    for (int k = 0; k < 24; k++) fvT[(k % 3) * 8 + (k / 3)][m] = v[16 + k];  // fvT[c*8+i]
  } else {
    // q=1: h[0..7], q=2: h[8..15]
    float el[10];
    const float2* e2 = reinterpret_cast<const float2*>(emb + (size_t)e * 10);
#pragma unroll
    for (int b = 0; b < 5; b++) { float2 t = e2[b]; el[2 * b] = t.x; el[2 * b + 1] = t.y; }
    const int j0 = (q == 1) ? 0 : 8;
#pragma unroll
    for (int jj = 0; jj < 8; jj++) {
      int j = j0 + jj;
      float a = 0.f;
#pragma unroll
      for (int b = 0; b < 10; b++) a += el[b] * w1[b * 16 + j];
      a *= INV_SQRT_NB;
      float sig = 1.0f / (1.0f + __expf(-a));
      h_s[m][j] = a * sig * H_SCALE;
    }
  }
  __syncthreads();

  // ---- MFMA phase: fp16 single plane, same k-mappings as rounds 5-9 ----
  const int w    = tid >> 6;
  const int l    = tid & 63;
  const int row  = l & 15;
  const int kb   = l >> 4;
  const int mrow = w * 16 + row;
  const int col  = l & 15;

  f32x4 pfs0 = {0.f, 0.f, 0.f, 0.f}, pfs1 = {0.f, 0.f, 0.f, 0.f};
  f32x4 pc0_0 = {0.f, 0.f, 0.f, 0.f}, pc0_1 = {0.f, 0.f, 0.f, 0.f}, pc0_2 = {0.f, 0.f, 0.f, 0.f};
  f32x4 pc1_0 = {0.f, 0.f, 0.f, 0.f}, pc1_1 = {0.f, 0.f, 0.f, 0.f}, pc1_2 = {0.f, 0.f, 0.f, 0.f};

  // fs path: K=256, 8 K-steps. k = s*32 + kb*8 + j; r = k>>4, i = k&15.
#pragma unroll
  for (int s = 0; s < 8; s++) {
    const int r  = 2 * s + (kb >> 1);
    const int i0 = (kb & 1) * 8;
    const float hr = h_s[mrow][r];
    f16x8 a;
#pragma unroll
    for (int j = 0; j < 8; j++) a[j] = (_Float16)(hr * fsT[i0 + j][mrow]);
    const int k0 = s * 32 + kb * 8;
    f16x8 b0 = *reinterpret_cast<const f16x8*>(&BtL[col][k0]);
    f16x8 b1 = *reinterpret_cast<const f16x8*>(&BtL[16 + col][k0]);
    pfs0 = __builtin_amdgcn_mfma_f32_16x16x32_f16(a, b0, pfs0, 0, 0, 0);
    pfs1 = __builtin_amdgcn_mfma_f32_16x16x32_f16(a, b1, pfs1, 0, 0, 0);
  }

  // fv path: K=128 per c, 4 K-steps; r = 4s+kb, i = j.
#pragma unroll
  for (int s = 0; s < 4; s++) {
    const int r = 4 * s + kb;
    const float hr = h_s[mrow][r];
    const int k0 = 256 + s * 32 + kb * 8;
    f16x8 b0 = *reinterpret_cast<const f16x8*>(&BtL[col][k0]);
    f16x8 b1 = *reinterpret_cast<const f16x8*>(&BtL[16 + col][k0]);
#pragma unroll
    for (int c = 0; c < 3; c++) {
      f16x8 a;
#pragma unroll
      for (int j = 0; j < 8; j++) a[j] = (_Float16)(hr * fvT[c * 8 + j][mrow]);
      f32x4* p0 = (c == 0) ? &pc0_0 : (c == 1) ? &pc0_1 : &pc0_2;
      f32x4* p1 = (c == 0) ? &pc1_0 : (c == 1) ? &pc1_1 : &pc1_2;
      *p0 = __builtin_amdgcn_mfma_f32_16x16x32_f16(a, b0, *p0, 0, 0, 0);
      *p1 = __builtin_amdgcn_mfma_f32_16x16x32_f16(a, b1, *p1, 0, 0, 0);
    }
  }

  // ---- epilogue: combine with per-edge sh scalars, weighted rows -> LDS ----
#pragma unroll
  for (int j = 0; j < 4; j++) {
    const int me = w * 16 + kb * 4 + j;          // D row = (l>>4)*4 + reg
    const float sh0 = scal[me][0], sh1 = scal[me][1], sh2 = scal[me][2], sh3 = scal[me][3];
    const float wg = scal[me][4];
    float vsc = sh0 * pfs0[j] + sh1 * pc0_0[j] + sh2 * pc0_1[j] + sh3 * pc0_2[j];
    rows[me][col] = wg * vsc;
    if (col < 8) {
      rows[me][16 + col * 3 + 0] = wg * (sh1 * pfs1[j] + sh0 * pc1_0[j]);
      rows[me][16 + col * 3 + 1] = wg * (sh2 * pfs1[j] + sh0 * pc1_1[j]);
      rows[me][16 + col * 3 + 2] = wg * (sh3 * pfs1[j] + sh0 * pc1_2[j]);
    }
  }
  __syncthreads();

  // ---- segmented reduction over sorted dst (direct f_out write) ----
  if (tid < 64) {
    bool head = (m == 0) || (nid[m] != nid[m - 1]);
    unsigned long long mask = __ballot(head);
    if (tid == 0) nseg_s = __popcll(mask);
    if (head) {
      int idx = __popcll(mask & ((1ull << m) - 1ull));
      unsigned long long higher = (m == 63) ? 0ull : (mask >> (m + 1));
      int len = higher ? __ffsll((long long)higher) : (64 - m);
      seg_start[idx] = m; seg_len[idx] = len; seg_nid[idx] = nid[m];
    }
  }
  __syncthreads();

  const int nseg = nseg_s;
  const int d = tid & 63;
  const int g = tid >> 6;
  if (d < DIM) {
    for (int s = g; s < nseg; s += 4) {
      const int st = seg_start[s], ln = seg_len[s];
      float acc = 0.f;
      for (int k2 = 0; k2 < ln; k2++) acc += rows[st + k2][d];
      float* fo = &fout[(size_t)seg_nid[s] * DIM + d];
      if (s > 0 && s < nseg - 1) *fo = acc;   // node fully inside this block
      else atomicAdd(fo, acc);                // may span block boundary
    }
  }
}

extern "C" void kernel_launch(void* const* d_in, const int* in_sizes, int n_in,
                              void* d_out, int out_size, void* d_ws, size_t ws_size,
                              hipStream_t stream) {
  const float* f      = (const float*)d_in[0];
  const int*   ei     = (const int*)d_in[1];
  const float* elen   = (const float*)d_in[2];
  const float* esh    = (const float*)d_in[3];
  const float* emb    = (const float*)d_in[4];
  const float* Wq0    = (const float*)d_in[5];
  const float* Wq1    = (const float*)d_in[6];
  const float* fck_w1 = (const float*)d_in[7];
  const float* fck_w2 = (const float*)d_in[8];
  const float* fcv_w1 = (const float*)d_in[9];
  const float* fcv_w2 = (const float*)d_in[10];
  const float* Wd00   = (const float*)d_in[11];
  const float* Wd11   = (const float*)d_in[12];

  float* out = (float*)d_out;

  char* ws = (char*)d_ws;
  float* qq     = (float*)ws;  ws += (size_t)NN * 64 * 4;
  float* qd     = (float*)ws;  ws += (size_t)NN * DIM * 4;
  float* z      = (float*)ws;  ws += (size_t)NN * 4;
  float* expv   = (float*)ws;  ws += (size_t)NE * 4;
  int*   cnt    = (int*)ws;    ws += (size_t)NN * 4;
  int*   off    = (int*)ws;    ws += (size_t)NN * 4;
  int*   eperm  = (int*)ws;    ws += (size_t)NE * 4;
  int*   dsts   = (int*)ws;    ws += (size_t)NE * 4;
  unsigned short* Bt = (unsigned short*)ws;  ws += (size_t)32 * BKP * 2;

  hipMemsetAsync(z, 0, (size_t)NN * 4, stream);
  hipMemsetAsync(cnt, 0, (size_t)NN * 4, stream);
  hipMemsetAsync(out, 0, (size_t)NN * DIM * 4, stream);

  prep_B_kernel<<<32 * BKP / 256, 256, 0, stream>>>(fcv_w2, Bt);
  node_qd_kernel<<<NN / 256, 256, 0, stream>>>(f, Wq0, Wq1, Wd00, Wd11, qd);
  qq_kernel<<<1024, 256, 0, stream>>>(f, qd, fck_w2, qq);
  hist_kernel<<<NE / 256, 256, 0, stream>>>(ei, cnt);
  scan_kernel<<<1, 1024, 0, stream>>>(cnt, off);
  scatter_kernel<<<NE / 256, 256, 0, stream>>>(ei, off, eperm, dsts);
  k_pass_kernel<<<NE / 256, 256, 0, stream>>>(eperm, dsts, elen, esh, emb,
                                              fck_w1, qq, expv, z);
  v_mfma_kernel<<<NE / 64, 256, 0, stream>>>(ei, esh, emb, fcv_w1, f, expv, z,
                                             eperm, dsts, Bt, out);
}

// Round 11
// 138.329 us; speedup vs baseline: 2.6922x; 1.3104x over previous
//
#include <hip/hip_runtime.h>
#include <hip/hip_bf16.h>
#include <math.h>

namespace {
constexpr int NN  = 16384;
constexpr int NE  = 262144;
constexpr int DIM = 40;

constexpr float INV_SQRT3   = 0.5773502691896258f;
constexpr float A_PATH      = 0.2041241452319315f;      // 1/sqrt(24)
constexpr float INV_SQRT_NB = 0.31622776601683794f;     // 1/sqrt(10)
constexpr float H_SCALE     = 0.25f;                    // 1/sqrt(16)
constexpr float QSC_S       = 0.25f;
constexpr float QV_S        = 0.35355339059327373f;
constexpr float D00_S       = 1.0f / (16.0f * 1.4142135623730951f);
constexpr float D11_S       = 1.0f / (8.0f * 1.7320508075688772f * 1.4142135623730951f);

constexpr int BKP = 392;   // v_mfma B k-stride (fp16)
constexpr int K0P = 328;   // qq-GEMM path0 k-stride (320 used; 656B stride -> 2-way-free)
constexpr int KCP = 264;   // qq-GEMM pathC k-stride (256 used; 528B stride -> 2-way-free)
constexpr int BKTOT = 16 * K0P + 16 * KCP;   // 9472 shorts = 18944 B = 1184*16
}

typedef __attribute__((ext_vector_type(8))) _Float16 f16x8;
typedef __attribute__((ext_vector_type(4))) float f32x4;

static __device__ __forceinline__ void gload_lds16(const void* g, void* l) {
  __builtin_amdgcn_global_load_lds(
      (const __attribute__((address_space(1))) unsigned*)g,
      (__attribute__((address_space(3))) unsigned*)l, 16, 0, 0);
}

// ---------------------------------------------------------------------------
// node_qd (round-7 verified)
// ---------------------------------------------------------------------------
__global__ __launch_bounds__(256) void node_qd_kernel(
    const float* __restrict__ f,
    const float* __restrict__ Wq0, const float* __restrict__ Wq1,
    const float* __restrict__ Wd00, const float* __restrict__ Wd11,
    float* __restrict__ qd)
{
  const int n = blockIdx.x * 256 + threadIdx.x;

  float fs[16], fv[8][3];
  {
    const float4* fn4 = reinterpret_cast<const float4*>(f + (size_t)n * DIM);
#pragma unroll
    for (int i = 0; i < 10; i++) {
      float4 t = fn4[i];
      int base = i * 4;
#pragma unroll
      for (int k = 0; k < 4; k++) {
        float v = (k == 0) ? t.x : (k == 1) ? t.y : (k == 2) ? t.z : t.w;
        int idx = base + k;
        if (idx < 16) fs[idx] = v;
        else { int r = idx - 16; fv[r / 3][r % 3] = v; }
      }
    }
  }

  float out[40];
  {
    float qsc[16];
#pragma unroll
    for (int o = 0; o < 16; o++) {
      float a = 0.f;
#pragma unroll
      for (int i = 0; i < 16; i++) a += fs[i] * Wq0[i * 16 + o];
      qsc[o] = a * QSC_S;
    }
#pragma unroll
    for (int j = 0; j < 16; j++) {
      float a = 0.f;
#pragma unroll
      for (int i = 0; i < 16; i++) a += qsc[i] * Wd00[i * 16 + j];
      out[j] = a * D00_S;
    }
  }
  {
    float qv[8][3];
#pragma unroll
    for (int o = 0; o < 8; o++)
#pragma unroll
      for (int c = 0; c < 3; c++) {
        float a = 0.f;
#pragma unroll
        for (int i = 0; i < 8; i++) a += fv[i][c] * Wq1[i * 8 + o];
        qv[o][c] = a * QV_S;
      }
#pragma unroll
    for (int j = 0; j < 8; j++)
#pragma unroll
      for (int c = 0; c < 3; c++) {
        float a = 0.f;
#pragma unroll
        for (int i = 0; i < 8; i++) a += qv[i][c] * Wd11[i * 8 + j];
        out[16 + j * 3 + c] = a * D11_S;
      }
  }

  float4* op = reinterpret_cast<float4*>(qd + (size_t)n * DIM);
#pragma unroll
  for (int i = 0; i < 10; i++)
    op[i] = make_float4(out[4 * i], out[4 * i + 1], out[4 * i + 2], out[4 * i + 3]);
}

// ---------------------------------------------------------------------------
// prep_Bk: qq-GEMM B matrix from fck_w2, fp16, col(r)-major with padded k.
// Layout: [r*K0P + k] path0 (k<256: w00[i=k>>4][o=k&15]; k in [256,320):
// w10[i][o], kk=k-256, i=kk>>3, o=kk&7); offset 16*K0P: [r*KCP + k] pathC
// (k<128: INV_SQRT3*w11; k in [128,256): w01).
// ---------------------------------------------------------------------------
__global__ __launch_bounds__(256) void prep_Bk_kernel(const float* __restrict__ w2k,
                                                      unsigned short* __restrict__ Btk)
{
  int t = blockIdx.x * 256 + threadIdx.x;   // BKTOT threads
  float val = 0.f;
  if (t < 16 * K0P) {
    int r = t / K0P, k = t % K0P;
    if (k < 256)      { int i = k >> 4, o = k & 15; val = w2k[r * 576 + i * 16 + o]; }
    else if (k < 320) { int kk = k - 256; int i = kk >> 3, o = kk & 7;
                        val = w2k[r * 576 + 512 + i * 8 + o]; }
  } else {
    int t2 = t - 16 * K0P;
    int r = t2 / KCP, k = t2 % KCP;
    if (k < 128)      { int i = k >> 4, o = k & 15;
                        val = INV_SQRT3 * w2k[r * 576 + 256 + i * 16 + o]; }
    else if (k < 256) { int kk = k - 128; int i = kk >> 3, o = kk & 7;
                        val = w2k[r * 576 + 384 + i * 8 + o]; }
  }
  _Float16 hv = (_Float16)val;
  Btk[t] = __builtin_bit_cast(unsigned short, hv);
}

// ---------------------------------------------------------------------------
// qq via MFMA: per 64-node block, A = outer products of (fs,fv)x(qd0,qdv),
// B = Btk in LDS. Same fragment conventions as v_mfma (verified r5-r10).
// ---------------------------------------------------------------------------
__global__ __launch_bounds__(256) void qq_mfma_kernel(
    const float* __restrict__ f,
    const float* __restrict__ qd,
    const unsigned short* __restrict__ Btk,
    float* __restrict__ qq)
{
  __shared__ __attribute__((aligned(16))) unsigned short BL[BKTOT];
  __shared__ float fsT[16][65];
  __shared__ float fvT[24][65];    // fvT[c*8+i][m]
  __shared__ float qd0T[16][65];
  __shared__ float qdvT[24][65];   // qdvT[c*8+o][m]

  const int tid  = threadIdx.x;
  const int base = blockIdx.x * 64;

  // stage Btk -> LDS (18944 B = 1184 x16B)
  {
    const char* src = (const char*)Btk;
    char* dst = (char*)BL;
#pragma unroll
    for (int k2 = 0; k2 < 4; k2++) {
      int off = (k2 * 256 + tid) * 16;
      gload_lds16(src + off, dst + off);
    }
    if (tid < 160) {
      int off = (1024 + tid) * 16;
      gload_lds16(src + off, dst + off);
    }
  }

  const int m = tid & 63;
  const int q = tid >> 6;
  const int n = base + m;

  if (q == 0) {
    const float4* f4 = reinterpret_cast<const float4*>(f + (size_t)n * DIM);
    float v[40];
#pragma unroll
    for (int i = 0; i < 10; i++) {
      float4 t = f4[i];
      v[4 * i] = t.x; v[4 * i + 1] = t.y; v[4 * i + 2] = t.z; v[4 * i + 3] = t.w;
    }
#pragma unroll
    for (int i = 0; i < 16; i++) fsT[i][m] = v[i];
#pragma unroll
    for (int k = 0; k < 24; k++) fvT[(k % 3) * 8 + (k / 3)][m] = v[16 + k];
  } else if (q == 1) {
    const float4* q4 = reinterpret_cast<const float4*>(qd + (size_t)n * DIM);
    float v[40];
#pragma unroll
    for (int i = 0; i < 10; i++) {
      float4 t = q4[i];
      v[4 * i] = t.x; v[4 * i + 1] = t.y; v[4 * i + 2] = t.z; v[4 * i + 3] = t.w;
    }
#pragma unroll
    for (int i = 0; i < 16; i++) qd0T[i][m] = v[i];
#pragma unroll
    for (int k = 0; k < 24; k++) qdvT[(k % 3) * 8 + (k / 3)][m] = v[16 + k];
  }
  __syncthreads();

  const int w    = tid >> 6;
  const int l    = tid & 63;
  const int row  = l & 15;
  const int kb   = l >> 4;
  const int mrow = w * 16 + row;
  const int col  = l & 15;          // r

  f32x4 p0  = {0.f, 0.f, 0.f, 0.f};
  f32x4 pcA = {0.f, 0.f, 0.f, 0.f}, pcB = {0.f, 0.f, 0.f, 0.f}, pcC = {0.f, 0.f, 0.f, 0.f};

  // path0: K=320, 10 K-steps. k = s*32 + kb*8 + j.
#pragma unroll
  for (int s = 0; s < 10; s++) {
    f16x8 a;
    if (s < 8) {
      const int i  = 2 * s + (kb >> 1);
      const int o0 = (kb & 1) * 8;
      const float fsv = fsT[i][mrow];
#pragma unroll
      for (int j = 0; j < 8; j++) a[j] = (_Float16)(fsv * qd0T[o0 + j][mrow]);
    } else {
      const int i = (s - 8) * 4 + kb;   // i in [0,8)
      const float fv0 = fvT[i][mrow], fv1 = fvT[8 + i][mrow], fv2 = fvT[16 + i][mrow];
#pragma unroll
      for (int j = 0; j < 8; j++)
        a[j] = (_Float16)(fv0 * qdvT[j][mrow] + fv1 * qdvT[8 + j][mrow]
                          + fv2 * qdvT[16 + j][mrow]);
    }
    const int k0 = s * 32 + kb * 8;
    f16x8 b = *reinterpret_cast<const f16x8*>(&BL[col * K0P + k0]);
    p0 = __builtin_amdgcn_mfma_f32_16x16x32_f16(a, b, p0, 0, 0, 0);
  }

  // paths c=0..2: K=256, 8 K-steps each; B shared across c.
#pragma unroll
  for (int c = 0; c < 3; c++) {
    f32x4* pc = (c == 0) ? &pcA : (c == 1) ? &pcB : &pcC;
#pragma unroll
    for (int s = 0; s < 8; s++) {
      f16x8 a;
      if (s < 4) {
        const int i  = 2 * s + (kb >> 1);   // i in [0,8)
        const int o0 = (kb & 1) * 8;
        const float fvv = fvT[c * 8 + i][mrow];
#pragma unroll
        for (int j = 0; j < 8; j++) a[j] = (_Float16)(fvv * qd0T[o0 + j][mrow]);
      } else {
        const int i = (s - 4) * 4 + kb;     // i in [0,16)
        const float fsv = fsT[i][mrow];
#pragma unroll
        for (int j = 0; j < 8; j++) a[j] = (_Float16)(fsv * qdvT[c * 8 + j][mrow]);
      }
      const int k0 = s * 32 + kb * 8;
      f16x8 b = *reinterpret_cast<const f16x8*>(&BL[16 * K0P + col * KCP + k0]);
      *pc = __builtin_amdgcn_mfma_f32_16x16x32_f16(a, b, *pc, 0, 0, 0);
    }
  }

  // write: D row = (l>>4)*4+j = node-in-tile, col = r
#pragma unroll
  for (int j = 0; j < 4; j++) {
    const int me = w * 16 + kb * 4 + j;
    float4 outv = make_float4(A_PATH * p0[j], A_PATH * pcA[j],
                              A_PATH * pcB[j], A_PATH * pcC[j]);
    reinterpret_cast<float4*>(qq)[(size_t)(base + me) * 16 + col] = outv;
  }
}

// ---------------------------------------------------------------------------
// Counting sort by dst; scatter emits eperm AND dst_sorted
// ---------------------------------------------------------------------------
__global__ __launch_bounds__(256) void hist_kernel(const int* __restrict__ ei,
                                                   int* __restrict__ cnt)
{
  const int e = blockIdx.x * 256 + threadIdx.x;
  atomicAdd(&cnt[ei[NE + e]], 1);
}

__global__ __launch_bounds__(1024) void scan_kernel(const int* __restrict__ cnt,
                                                    int* __restrict__ off)
{
  __shared__ int part[1024];
  const int t = threadIdx.x;
  const int base = t * 16;
  int loc[16];
  int s = 0;
#pragma unroll
  for (int k = 0; k < 16; k++) { loc[k] = s; s += cnt[base + k]; }
  part[t] = s;
  __syncthreads();
  for (int d = 1; d < 1024; d <<= 1) {
    int v = (t >= d) ? part[t - d] : 0;
    __syncthreads();
    part[t] += v;
    __syncthreads();
  }
  int excl = (t == 0) ? 0 : part[t - 1];
#pragma unroll
  for (int k = 0; k < 16; k++) off[base + k] = excl + loc[k];
}

__global__ __launch_bounds__(256) void scatter_kernel(const int* __restrict__ ei,
                                                      int* __restrict__ off,
                                                      int* __restrict__ eperm,
                                                      int* __restrict__ dst_sorted)
{
  const int e = blockIdx.x * 256 + threadIdx.x;
  const int dst = ei[NE + e];
  int rk = atomicAdd(&off[dst], 1);
  eperm[rk] = e;
  dst_sorted[rk] = dst;
}

// ---------------------------------------------------------------------------
// K-pass over SORTED ranks (round-9 verified)
// ---------------------------------------------------------------------------
__global__ __launch_bounds__(256) void k_pass_kernel(
    const int*   __restrict__ eperm,
    const int*   __restrict__ dst_sorted,
    const float* __restrict__ elen,
    const float* __restrict__ esh,
    const float* __restrict__ emb,
    const float* __restrict__ w1,
    const float* __restrict__ qq,
    float* __restrict__ expv,
    float* __restrict__ z)
{
  const int rk = blockIdx.x * 256 + threadIdx.x;
  const int e = eperm[rk];
  const int dst = dst_sorted[rk];

  float el[10];
  const float2* e2 = reinterpret_cast<const float2*>(emb + (size_t)e * 10);
#pragma unroll
  for (int b = 0; b < 5; b++) { float2 t = e2[b]; el[2 * b] = t.x; el[2 * b + 1] = t.y; }

  float h[16];
#pragma unroll
  for (int j = 0; j < 16; j++) {
    float a = 0.f;
#pragma unroll
    for (int b = 0; b < 10; b++) a += el[b] * w1[b * 16 + j];
    a *= INV_SQRT_NB;
    float sig = 1.0f / (1.0f + __expf(-a));
    h[j] = a * sig * H_SCALE;
  }

  float4 sh4 = reinterpret_cast<const float4*>(esh)[e];
  const float4* q4 = reinterpret_cast<const float4*>(qq + (size_t)dst * 64);
  float s = 0.f;
#pragma unroll
  for (int r = 0; r < 16; r++) {
    float4 qv = q4[r];
    s += h[r] * (sh4.x * qv.x + sh4.y * qv.y + sh4.z * qv.z + sh4.w * qv.w);
  }

  float len = elen[e];
  float x = 10.0f * (1.0f - len * (1.0f / 1.3f));
  float cut = (x > 0.f) ? __expf(-1.0f / x) : 0.f;
  float ev = cut * __expf(s);
  expv[rk] = ev;
  atomicAdd(&z[dst], ev);
}

// ---------------------------------------------------------------------------
// prep_B for v_mfma: single fp16 plane (round-10 verified)
// ---------------------------------------------------------------------------
__global__ __launch_bounds__(256) void prep_B_kernel(const float* __restrict__ w2v,
                                                     unsigned short* __restrict__ Bt)
{
  int t = blockIdx.x * 256 + threadIdx.x;   // 32*BKP threads
  int col = t / BKP, kp = t % BKP;
  float val = 0.f;
  if (kp < 384 && col < 24) {
    if (kp < 256) {
      int r = kp >> 4, i = kp & 15;
      if (col < 16) val = A_PATH * w2v[r * 576 + i * 16 + col];
      else          val = A_PATH * w2v[r * 576 + 384 + i * 8 + (col - 16)];
    } else {
      int k2 = kp - 256; int r = k2 >> 3, i = k2 & 7;
      if (col < 16) val = A_PATH * INV_SQRT3 * w2v[r * 576 + 256 + i * 16 + col];
      else          val = A_PATH * w2v[r * 576 + 512 + i * 8 + (col - 16)];
    }
  }
  _Float16 hv = (_Float16)val;
  Bt[t] = __builtin_bit_cast(unsigned short, hv);
}

// ---------------------------------------------------------------------------
// V-pass via fp16 MFMA (round-10 verified, unchanged)
// ---------------------------------------------------------------------------
__global__ __launch_bounds__(256) void v_mfma_kernel(
    const int*   __restrict__ ei,
    const float* __restrict__ esh,
    const float* __restrict__ emb,
    const float* __restrict__ w1,      // fcv_w1
    const float* __restrict__ f,
    const float* __restrict__ expv,    // by rank
    const float* __restrict__ z,
    const int*   __restrict__ eperm,
    const int*   __restrict__ dst_sorted,
    const unsigned short* __restrict__ Bt,
    float* __restrict__ fout)
{
  __shared__ float h_s[64][17];
  __shared__ float fsT[16][65];
  __shared__ float fvT[24][65];
  __shared__ float scal[64][5];
  __shared__ int   nid[64];
  __shared__ __attribute__((aligned(16))) unsigned short BtL[32][BKP];
  __shared__ float rows[64][41];
  __shared__ int seg_start[64], seg_len[64], seg_nid[64];
  __shared__ int nseg_s;

  const int tid  = threadIdx.x;
  const int base = blockIdx.x * 64;

  // stage Bt (single fp16 plane) -> LDS via async global_load_lds (25088 B)
  {
    const char* src = (const char*)Bt;
    char* dst = (char*)&BtL[0][0];
#pragma unroll
    for (int k = 0; k < 6; k++) {
      int off = (k * 256 + tid) * 16;
      gload_lds16(src + off, dst + off);
    }
    if (tid < 32) {
      int off = (1536 + tid) * 16;
      gload_lds16(src + off, dst + off);
    }
  }

  const int m = tid & 63;
  const int q = tid >> 6;
  const int e = eperm[base + m];

  if (q == 0) {
    int dn = dst_sorted[base + m];
    float4 sh4 = reinterpret_cast<const float4*>(esh)[e];
    float zz = z[dn]; zz = (zz == 0.f) ? 1.f : zz;
    float ev = expv[base + m];
    float wgt = sqrtf(fmaxf(ev / zz, 0.f));
    scal[m][0] = sh4.x; scal[m][1] = sh4.y; scal[m][2] = sh4.z; scal[m][3] = sh4.w;
    scal[m][4] = wgt;
    nid[m] = dn;
  } else if (q == 3) {
    int sn = ei[e];
    const float4* f4 = reinterpret_cast<const float4*>(f + (size_t)sn * DIM);
    float v[40];
#pragma unroll
    for (int i = 0; i < 10; i++) {
      float4 t = f4[i];
      v[4 * i] = t.x; v[4 * i + 1] = t.y; v[4 * i + 2] = t.z; v[4 * i + 3] = t.w;
    }
#pragma unroll
    for (int i = 0; i < 16; i++) fsT[i][m] = v[i];
#pragma unroll
    for (int k = 0; k < 24; k++) fvT[(k % 3) * 8 + (k / 3)][m] = v[16 + k];  // fvT[c*8+i]
  } else {
    // q=1: h[0..7], q=2: h[8..15]
    float el[10];
    const float2* e2 = reinterpret_cast<const float2*>(emb + (size_t)e * 10);
#pragma unroll
    for (int b = 0; b < 5; b++) { float2 t = e2[b]; el[2 * b] = t.x; el[2 * b + 1] = t.y; }
    const int j0 = (q == 1) ? 0 : 8;
#pragma unroll
    for (int jj = 0; jj < 8; jj++) {
      int j = j0 + jj;
      float a = 0.f;
#pragma unroll
      for (int b = 0; b < 10; b++) a += el[b] * w1[b * 16 + j];
      a *= INV_SQRT_NB;
      float sig = 1.0f / (1.0f + __expf(-a));
      h_s[m][j] = a * sig * H_SCALE;
    }
  }
  __syncthreads();

  // ---- MFMA phase: fp16 single plane, same k-mappings as rounds 5-10 ----
  const int w    = tid >> 6;
  const int l    = tid & 63;
  const int row  = l & 15;
  const int kb   = l >> 4;
  const int mrow = w * 16 + row;
  const int col  = l & 15;

  f32x4 pfs0 = {0.f, 0.f, 0.f, 0.f}, pfs1 = {0.f, 0.f, 0.f, 0.f};
  f32x4 pc0_0 = {0.f, 0.f, 0.f, 0.f}, pc0_1 = {0.f, 0.f, 0.f, 0.f}, pc0_2 = {0.f, 0.f, 0.f, 0.f};
  f32x4 pc1_0 = {0.f, 0.f, 0.f, 0.f}, pc1_1 = {0.f, 0.f, 0.f, 0.f}, pc1_2 = {0.f, 0.f, 0.f, 0.f};

  // fs path: K=256, 8 K-steps. k = s*32 + kb*8 + j; r = k>>4, i = k&15.
#pragma unroll
  for (int s = 0; s < 8; s++) {
    const int r  = 2 * s + (kb >> 1);
    const int i0 = (kb & 1) * 8;
    const float hr = h_s[mrow][r];
    f16x8 a;
#pragma unroll
    for (int j = 0; j < 8; j++) a[j] = (_Float16)(hr * fsT[i0 + j][mrow]);
    const int k0 = s * 32 + kb * 8;
    f16x8 b0 = *reinterpret_cast<const f16x8*>(&BtL[col][k0]);
    f16x8 b1 = *reinterpret_cast<const f16x8*>(&BtL[16 + col][k0]);
    pfs0 = __builtin_amdgcn_mfma_f32_16x16x32_f16(a, b0, pfs0, 0, 0, 0);
    pfs1 = __builtin_amdgcn_mfma_f32_16x16x32_f16(a, b1, pfs1, 0, 0, 0);
  }

  // fv path: K=128 per c, 4 K-steps; r = 4s+kb, i = j.
#pragma unroll
  for (int s = 0; s < 4; s++) {
    const int r = 4 * s + kb;
    const float hr = h_s[mrow][r];
    const int k0 = 256 + s * 32 + kb * 8;
    f16x8 b0 = *reinterpret_cast<const f16x8*>(&BtL[col][k0]);
    f16x8 b1 = *reinterpret_cast<const f16x8*>(&BtL[16 + col][k0]);
#pragma unroll
    for (int c = 0; c < 3; c++) {
      f16x8 a;
#pragma unroll
      for (int j = 0; j < 8; j++) a[j] = (_Float16)(hr * fvT[c * 8 + j][mrow]);
      f32x4* p0 = (c == 0) ? &pc0_0 : (c == 1) ? &pc0_1 : &pc0_2;
      f32x4* p1 = (c == 0) ? &pc1_0 : (c == 1) ? &pc1_1 : &pc1_2;
      *p0 = __builtin_amdgcn_mfma_f32_16x16x32_f16(a, b0, *p0, 0, 0, 0);
      *p1 = __builtin_amdgcn_mfma_f32_16x16x32_f16(a, b1, *p1, 0, 0, 0);
    }
  }

  // ---- epilogue: combine with per-edge sh scalars, weighted rows -> LDS ----
#pragma unroll
  for (int j = 0; j < 4; j++) {
    const int me = w * 16 + kb * 4 + j;          // D row = (l>>4)*4 + reg
    const float sh0 = scal[me][0], sh1 = scal[me][1], sh2 = scal[me][2], sh3 = scal[me][3];
    const float wg = scal[me][4];
    float vsc = sh0 * pfs0[j] + sh1 * pc0_0[j] + sh2 * pc0_1[j] + sh3 * pc0_2[j];
    rows[me][col] = wg * vsc;
    if (col < 8) {
      rows[me][16 + col * 3 + 0] = wg * (sh1 * pfs1[j] + sh0 * pc1_0[j]);
      rows[me][16 + col * 3 + 1] = wg * (sh2 * pfs1[j] + sh0 * pc1_1[j]);
      rows[me][16 + col * 3 + 2] = wg * (sh3 * pfs1[j] + sh0 * pc1_2[j]);
    }
  }
  __syncthreads();

  // ---- segmented reduction over sorted dst (direct f_out write) ----
  if (tid < 64) {
    bool head = (m == 0) || (nid[m] != nid[m - 1]);
    unsigned long long mask = __ballot(head);
    if (tid == 0) nseg_s = __popcll(mask);
    if (head) {
      int idx = __popcll(mask & ((1ull << m) - 1ull));
      unsigned long long higher = (m == 63) ? 0ull : (mask >> (m + 1));
      int len = higher ? __ffsll((long long)higher) : (64 - m);
      seg_start[idx] = m; seg_len[idx] = len; seg_nid[idx] = nid[m];
    }
  }
  __syncthreads();

  const int nseg = nseg_s;
  const int d = tid & 63;
  const int g = tid >> 6;
  if (d < DIM) {
    for (int s = g; s < nseg; s += 4) {
      const int st = seg_start[s], ln = seg_len[s];
      float acc = 0.f;
      for (int k2 = 0; k2 < ln; k2++) acc += rows[st + k2][d];
      float* fo = &fout[(size_t)seg_nid[s] * DIM + d];
      if (s > 0 && s < nseg - 1) *fo = acc;   // node fully inside this block
      else atomicAdd(fo, acc);                // may span block boundary
    }
  }
}

extern "C" void kernel_launch(void* const* d_in, const int* in_sizes, int n_in,
                              void* d_out, int out_size, void* d_ws, size_t ws_size,
                              hipStream_t stream) {
  const float* f      = (const float*)d_in[0];
  const int*   ei     = (const int*)d_in[1];
  const float* elen   = (const float*)d_in[2];
  const float* esh    = (const float*)d_in[3];
  const float* emb    = (const float*)d_in[4];
  const float* Wq0    = (const float*)d_in[5];
  const float* Wq1    = (const float*)d_in[6];
  const float* fck_w1 = (const float*)d_in[7];
  const float* fck_w2 = (const float*)d_in[8];
  const float* fcv_w1 = (const float*)d_in[9];
  const float* fcv_w2 = (const float*)d_in[10];
  const float* Wd00   = (const float*)d_in[11];
  const float* Wd11   = (const float*)d_in[12];

  float* out = (float*)d_out;

  char* ws = (char*)d_ws;
  float* qq     = (float*)ws;  ws += (size_t)NN * 64 * 4;
  float* qd     = (float*)ws;  ws += (size_t)NN * DIM * 4;
  float* z      = (float*)ws;  ws += (size_t)NN * 4;
  float* expv   = (float*)ws;  ws += (size_t)NE * 4;
  int*   cnt    = (int*)ws;    ws += (size_t)NN * 4;
  int*   off    = (int*)ws;    ws += (size_t)NN * 4;
  int*   eperm  = (int*)ws;    ws += (size_t)NE * 4;
  int*   dsts   = (int*)ws;    ws += (size_t)NE * 4;
  unsigned short* Btv = (unsigned short*)ws;  ws += (size_t)32 * BKP * 2;
  unsigned short* Btk = (unsigned short*)ws;  ws += (size_t)BKTOT * 2;

  hipMemsetAsync(z, 0, (size_t)NN * 4, stream);
  hipMemsetAsync(cnt, 0, (size_t)NN * 4, stream);
  hipMemsetAsync(out, 0, (size_t)NN * DIM * 4, stream);

  prep_B_kernel<<<32 * BKP / 256, 256, 0, stream>>>(fcv_w2, Btv);
  prep_Bk_kernel<<<BKTOT / 256, 256, 0, stream>>>(fck_w2, Btk);
  node_qd_kernel<<<NN / 256, 256, 0, stream>>>(f, Wq0, Wq1, Wd00, Wd11, qd);
  qq_mfma_kernel<<<NN / 64, 256, 0, stream>>>(f, qd, Btk, qq);
  hist_kernel<<<NE / 256, 256, 0, stream>>>(ei, cnt);
  scan_kernel<<<1, 1024, 0, stream>>>(cnt, off);
  scatter_kernel<<<NE / 256, 256, 0, stream>>>(ei, off, eperm, dsts);
  k_pass_kernel<<<NE / 256, 256, 0, stream>>>(eperm, dsts, elen, esh, emb,
                                              fck_w1, qq, expv, z);
  v_mfma_kernel<<<NE / 64, 256, 0, stream>>>(ei, esh, emb, fcv_w1, f, expv, z,
                                             eperm, dsts, Btv, out);
}

// Round 12
// 134.565 us; speedup vs baseline: 2.7675x; 1.0280x over previous
//
#include <hip/hip_runtime.h>
#include <hip/hip_bf16.h>
#include <math.h>

namespace {
constexpr int NN  = 16384;
constexpr int NE  = 262144;
constexpr int DIM = 40;

constexpr float INV_SQRT3   = 0.5773502691896258f;
constexpr float A_PATH      = 0.2041241452319315f;      // 1/sqrt(24)
constexpr float INV_SQRT_NB = 0.31622776601683794f;     // 1/sqrt(10)
constexpr float H_SCALE     = 0.25f;                    // 1/sqrt(16)
constexpr float QSC_S       = 0.25f;
constexpr float QV_S        = 0.35355339059327373f;
constexpr float D00_S       = 1.0f / (16.0f * 1.4142135623730951f);
constexpr float D11_S       = 1.0f / (8.0f * 1.7320508075688772f * 1.4142135623730951f);

constexpr int BKP = 392;   // v_mfma B k-stride (fp16)
constexpr int K0P = 328;   // qq-GEMM path0 k-stride
constexpr int KCP = 264;   // qq-GEMM pathC k-stride
constexpr int BKTOT = 16 * K0P + 16 * KCP;   // 9472 shorts = 18944 B
constexpr int FEP = 40;    // feE padded row (fp16): 80 B = 16B-aligned, 20-bank stride
}

typedef __attribute__((ext_vector_type(8))) _Float16 f16x8;
typedef __attribute__((ext_vector_type(4))) float f32x4;

static __device__ __forceinline__ void gload_lds16(const void* g, void* l) {
  __builtin_amdgcn_global_load_lds(
      (const __attribute__((address_space(1))) unsigned*)g,
      (__attribute__((address_space(3))) unsigned*)l, 16, 0, 0);
}

// ---------------------------------------------------------------------------
// node_qd (round-7 verified)
// ---------------------------------------------------------------------------
__global__ __launch_bounds__(256) void node_qd_kernel(
    const float* __restrict__ f,
    const float* __restrict__ Wq0, const float* __restrict__ Wq1,
    const float* __restrict__ Wd00, const float* __restrict__ Wd11,
    float* __restrict__ qd)
{
  const int n = blockIdx.x * 256 + threadIdx.x;

  float fs[16], fv[8][3];
  {
    const float4* fn4 = reinterpret_cast<const float4*>(f + (size_t)n * DIM);
#pragma unroll
    for (int i = 0; i < 10; i++) {
      float4 t = fn4[i];
      int base = i * 4;
#pragma unroll
      for (int k = 0; k < 4; k++) {
        float v = (k == 0) ? t.x : (k == 1) ? t.y : (k == 2) ? t.z : t.w;
        int idx = base + k;
        if (idx < 16) fs[idx] = v;
        else { int r = idx - 16; fv[r / 3][r % 3] = v; }
      }
    }
  }

  float out[40];
  {
    float qsc[16];
#pragma unroll
    for (int o = 0; o < 16; o++) {
      float a = 0.f;
#pragma unroll
      for (int i = 0; i < 16; i++) a += fs[i] * Wq0[i * 16 + o];
      qsc[o] = a * QSC_S;
    }
#pragma unroll
    for (int j = 0; j < 16; j++) {
      float a = 0.f;
#pragma unroll
      for (int i = 0; i < 16; i++) a += qsc[i] * Wd00[i * 16 + j];
      out[j] = a * D00_S;
    }
  }
  {
    float qv[8][3];
#pragma unroll
    for (int o = 0; o < 8; o++)
#pragma unroll
      for (int c = 0; c < 3; c++) {
        float a = 0.f;
#pragma unroll
        for (int i = 0; i < 8; i++) a += fv[i][c] * Wq1[i * 8 + o];
        qv[o][c] = a * QV_S;
      }
#pragma unroll
    for (int j = 0; j < 8; j++)
#pragma unroll
      for (int c = 0; c < 3; c++) {
        float a = 0.f;
#pragma unroll
        for (int i = 0; i < 8; i++) a += qv[i][c] * Wd11[i * 8 + j];
        out[16 + j * 3 + c] = a * D11_S;
      }
  }

  float4* op = reinterpret_cast<float4*>(qd + (size_t)n * DIM);
#pragma unroll
  for (int i = 0; i < 10; i++)
    op[i] = make_float4(out[4 * i], out[4 * i + 1], out[4 * i + 2], out[4 * i + 3]);
}

// ---------------------------------------------------------------------------
// prep_Bk (round-11 verified)
// ---------------------------------------------------------------------------
__global__ __launch_bounds__(256) void prep_Bk_kernel(const float* __restrict__ w2k,
                                                      unsigned short* __restrict__ Btk)
{
  int t = blockIdx.x * 256 + threadIdx.x;
  float val = 0.f;
  if (t < 16 * K0P) {
    int r = t / K0P, k = t % K0P;
    if (k < 256)      { int i = k >> 4, o = k & 15; val = w2k[r * 576 + i * 16 + o]; }
    else if (k < 320) { int kk = k - 256; int i = kk >> 3, o = kk & 7;
                        val = w2k[r * 576 + 512 + i * 8 + o]; }
  } else {
    int t2 = t - 16 * K0P;
    int r = t2 / KCP, k = t2 % KCP;
    if (k < 128)      { int i = k >> 4, o = k & 15;
                        val = INV_SQRT3 * w2k[r * 576 + 256 + i * 16 + o]; }
    else if (k < 256) { int kk = k - 128; int i = kk >> 3, o = kk & 7;
                        val = w2k[r * 576 + 384 + i * 8 + o]; }
  }
  _Float16 hv = (_Float16)val;
  Btk[t] = __builtin_bit_cast(unsigned short, hv);
}

// ---------------------------------------------------------------------------
// qq via MFMA (round-11 verified, unchanged)
// ---------------------------------------------------------------------------
__global__ __launch_bounds__(256) void qq_mfma_kernel(
    const float* __restrict__ f,
    const float* __restrict__ qd,
    const unsigned short* __restrict__ Btk,
    float* __restrict__ qq)
{
  __shared__ __attribute__((aligned(16))) unsigned short BL[BKTOT];
  __shared__ float fsT[16][65];
  __shared__ float fvT[24][65];
  __shared__ float qd0T[16][65];
  __shared__ float qdvT[24][65];

  const int tid  = threadIdx.x;
  const int base = blockIdx.x * 64;

  {
    const char* src = (const char*)Btk;
    char* dst = (char*)BL;
#pragma unroll
    for (int k2 = 0; k2 < 4; k2++) {
      int off = (k2 * 256 + tid) * 16;
      gload_lds16(src + off, dst + off);
    }
    if (tid < 160) {
      int off = (1024 + tid) * 16;
      gload_lds16(src + off, dst + off);
    }
  }

  const int m = tid & 63;
  const int q = tid >> 6;
  const int n = base + m;

  if (q == 0) {
    const float4* f4 = reinterpret_cast<const float4*>(f + (size_t)n * DIM);
    float v[40];
#pragma unroll
    for (int i = 0; i < 10; i++) {
      float4 t = f4[i];
      v[4 * i] = t.x; v[4 * i + 1] = t.y; v[4 * i + 2] = t.z; v[4 * i + 3] = t.w;
    }
#pragma unroll
    for (int i = 0; i < 16; i++) fsT[i][m] = v[i];
#pragma unroll
    for (int k = 0; k < 24; k++) fvT[(k % 3) * 8 + (k / 3)][m] = v[16 + k];
  } else if (q == 1) {
    const float4* q4 = reinterpret_cast<const float4*>(qd + (size_t)n * DIM);
    float v[40];
#pragma unroll
    for (int i = 0; i < 10; i++) {
      float4 t = q4[i];
      v[4 * i] = t.x; v[4 * i + 1] = t.y; v[4 * i + 2] = t.z; v[4 * i + 3] = t.w;
    }
#pragma unroll
    for (int i = 0; i < 16; i++) qd0T[i][m] = v[i];
#pragma unroll
    for (int k = 0; k < 24; k++) qdvT[(k % 3) * 8 + (k / 3)][m] = v[16 + k];
  }
  __syncthreads();

  const int w    = tid >> 6;
  const int l    = tid & 63;
  const int row  = l & 15;
  const int kb   = l >> 4;
  const int mrow = w * 16 + row;
  const int col  = l & 15;

  f32x4 p0  = {0.f, 0.f, 0.f, 0.f};
  f32x4 pcA = {0.f, 0.f, 0.f, 0.f}, pcB = {0.f, 0.f, 0.f, 0.f}, pcC = {0.f, 0.f, 0.f, 0.f};

#pragma unroll
  for (int s = 0; s < 10; s++) {
    f16x8 a;
    if (s < 8) {
      const int i  = 2 * s + (kb >> 1);
      const int o0 = (kb & 1) * 8;
      const float fsv = fsT[i][mrow];
#pragma unroll
      for (int j = 0; j < 8; j++) a[j] = (_Float16)(fsv * qd0T[o0 + j][mrow]);
    } else {
      const int i = (s - 8) * 4 + kb;
      const float fv0 = fvT[i][mrow], fv1 = fvT[8 + i][mrow], fv2 = fvT[16 + i][mrow];
#pragma unroll
      for (int j = 0; j < 8; j++)
        a[j] = (_Float16)(fv0 * qdvT[j][mrow] + fv1 * qdvT[8 + j][mrow]
                          + fv2 * qdvT[16 + j][mrow]);
    }
    const int k0 = s * 32 + kb * 8;
    f16x8 b = *reinterpret_cast<const f16x8*>(&BL[col * K0P + k0]);
    p0 = __builtin_amdgcn_mfma_f32_16x16x32_f16(a, b, p0, 0, 0, 0);
  }

#pragma unroll
  for (int c = 0; c < 3; c++) {
    f32x4* pc = (c == 0) ? &pcA : (c == 1) ? &pcB : &pcC;
#pragma unroll
    for (int s = 0; s < 8; s++) {
      f16x8 a;
      if (s < 4) {
        const int i  = 2 * s + (kb >> 1);
        const int o0 = (kb & 1) * 8;
        const float fvv = fvT[c * 8 + i][mrow];
#pragma unroll
        for (int j = 0; j < 8; j++) a[j] = (_Float16)(fvv * qd0T[o0 + j][mrow]);
      } else {
        const int i = (s - 4) * 4 + kb;
        const float fsv = fsT[i][mrow];
#pragma unroll
        for (int j = 0; j < 8; j++) a[j] = (_Float16)(fsv * qdvT[c * 8 + j][mrow]);
      }
      const int k0 = s * 32 + kb * 8;
      f16x8 b = *reinterpret_cast<const f16x8*>(&BL[16 * K0P + col * KCP + k0]);
      *pc = __builtin_amdgcn_mfma_f32_16x16x32_f16(a, b, *pc, 0, 0, 0);
    }
  }

#pragma unroll
  for (int j = 0; j < 4; j++) {
    const int me = w * 16 + kb * 4 + j;
    float4 outv = make_float4(A_PATH * p0[j], A_PATH * pcA[j],
                              A_PATH * pcB[j], A_PATH * pcC[j]);
    reinterpret_cast<float4*>(qq)[(size_t)(base + me) * 16 + col] = outv;
  }
}

// ---------------------------------------------------------------------------
// Counting sort by dst
// ---------------------------------------------------------------------------
__global__ __launch_bounds__(256) void hist_kernel(const int* __restrict__ ei,
                                                   int* __restrict__ cnt)
{
  const int e = blockIdx.x * 256 + threadIdx.x;
  atomicAdd(&cnt[ei[NE + e]], 1);
}

__global__ __launch_bounds__(1024) void scan_kernel(const int* __restrict__ cnt,
                                                    int* __restrict__ off)
{
  __shared__ int part[1024];
  const int t = threadIdx.x;
  const int base = t * 16;
  int loc[16];
  int s = 0;
#pragma unroll
  for (int k = 0; k < 16; k++) { loc[k] = s; s += cnt[base + k]; }
  part[t] = s;
  __syncthreads();
  for (int d = 1; d < 1024; d <<= 1) {
    int v = (t >= d) ? part[t - d] : 0;
    __syncthreads();
    part[t] += v;
    __syncthreads();
  }
  int excl = (t == 0) ? 0 : part[t - 1];
#pragma unroll
  for (int k = 0; k < 16; k++) off[base + k] = excl + loc[k];
}

__global__ __launch_bounds__(256) void scatter_kernel(const int* __restrict__ ei,
                                                      int* __restrict__ off,
                                                      int* __restrict__ eperm,
                                                      int* __restrict__ dst_sorted)
{
  const int e = blockIdx.x * 256 + threadIdx.x;
  const int dst = ei[NE + e];
  int rk = atomicAdd(&off[dst], 1);
  eperm[rk] = e;
  dst_sorted[rk] = dst;
}

// ---------------------------------------------------------------------------
// K-pass over SORTED ranks (round-9 verified)
// ---------------------------------------------------------------------------
__global__ __launch_bounds__(256) void k_pass_kernel(
    const int*   __restrict__ eperm,
    const int*   __restrict__ dst_sorted,
    const float* __restrict__ elen,
    const float* __restrict__ esh,
    const float* __restrict__ emb,
    const float* __restrict__ w1,
    const float* __restrict__ qq,
    float* __restrict__ expv,
    float* __restrict__ z)
{
  const int rk = blockIdx.x * 256 + threadIdx.x;
  const int e = eperm[rk];
  const int dst = dst_sorted[rk];

  float el[10];
  const float2* e2 = reinterpret_cast<const float2*>(emb + (size_t)e * 10);
#pragma unroll
  for (int b = 0; b < 5; b++) { float2 t = e2[b]; el[2 * b] = t.x; el[2 * b + 1] = t.y; }

  float h[16];
#pragma unroll
  for (int j = 0; j < 16; j++) {
    float a = 0.f;
#pragma unroll
    for (int b = 0; b < 10; b++) a += el[b] * w1[b * 16 + j];
    a *= INV_SQRT_NB;
    float sig = 1.0f / (1.0f + __expf(-a));
    h[j] = a * sig * H_SCALE;
  }

  float4 sh4 = reinterpret_cast<const float4*>(esh)[e];
  const float4* q4 = reinterpret_cast<const float4*>(qq + (size_t)dst * 64);
  float s = 0.f;
#pragma unroll
  for (int r = 0; r < 16; r++) {
    float4 qv = q4[r];
    s += h[r] * (sh4.x * qv.x + sh4.y * qv.y + sh4.z * qv.z + sh4.w * qv.w);
  }

  float len = elen[e];
  float x = 10.0f * (1.0f - len * (1.0f / 1.3f));
  float cut = (x > 0.f) ? __expf(-1.0f / x) : 0.f;
  float ev = cut * __expf(s);
  expv[rk] = ev;
  atomicAdd(&z[dst], ev);
}

// ---------------------------------------------------------------------------
// prep_B for v_mfma (round-10 verified)
// ---------------------------------------------------------------------------
__global__ __launch_bounds__(256) void prep_B_kernel(const float* __restrict__ w2v,
                                                     unsigned short* __restrict__ Bt)
{
  int t = blockIdx.x * 256 + threadIdx.x;
  int col = t / BKP, kp = t % BKP;
  float val = 0.f;
  if (kp < 384 && col < 24) {
    if (kp < 256) {
      int r = kp >> 4, i = kp & 15;
      if (col < 16) val = A_PATH * w2v[r * 576 + i * 16 + col];
      else          val = A_PATH * w2v[r * 576 + 384 + i * 8 + (col - 16)];
    } else {
      int k2 = kp - 256; int r = k2 >> 3, i = k2 & 7;
      if (col < 16) val = A_PATH * INV_SQRT3 * w2v[r * 576 + 256 + i * 16 + col];
      else          val = A_PATH * w2v[r * 576 + 512 + i * 8 + (col - 16)];
    }
  }
  _Float16 hv = (_Float16)val;
  Bt[t] = __builtin_bit_cast(unsigned short, hv);
}

// ---------------------------------------------------------------------------
// V-pass via fp16 MFMA. Round-12 change: per-edge features stored fp16
// CONTIGUOUS per edge (feE[64][FEP]) -> A-operand is 4 ds_read_b128 total
// per thread (fs + 3 fv slices, all K-step-invariant) + packed fp16 muls.
// ---------------------------------------------------------------------------
__global__ __launch_bounds__(256) void v_mfma_kernel(
    const int*   __restrict__ ei,
    const float* __restrict__ esh,
    const float* __restrict__ emb,
    const float* __restrict__ w1,      // fcv_w1
    const float* __restrict__ f,
    const float* __restrict__ expv,    // by rank
    const float* __restrict__ z,
    const int*   __restrict__ eperm,
    const int*   __restrict__ dst_sorted,
    const unsigned short* __restrict__ Bt,
    float* __restrict__ fout)
{
  __shared__ float h_s[64][17];
  __shared__ __attribute__((aligned(16))) _Float16 feE[64][FEP];  // fs[0..16), fv at 16+c*8+i
  __shared__ float scal[64][5];
  __shared__ int   nid[64];
  __shared__ __attribute__((aligned(16))) unsigned short BtL[32][BKP];
  __shared__ float rows[64][41];
  __shared__ int seg_start[64], seg_len[64], seg_nid[64];
  __shared__ int nseg_s;

  const int tid  = threadIdx.x;
  const int base = blockIdx.x * 64;

  // stage Bt (single fp16 plane) -> LDS via async global_load_lds (25088 B)
  {
    const char* src = (const char*)Bt;
    char* dst = (char*)&BtL[0][0];
#pragma unroll
    for (int k = 0; k < 6; k++) {
      int off = (k * 256 + tid) * 16;
      gload_lds16(src + off, dst + off);
    }
    if (tid < 32) {
      int off = (1536 + tid) * 16;
      gload_lds16(src + off, dst + off);
    }
  }

  const int m = tid & 63;
  const int q = tid >> 6;
  const int e = eperm[base + m];

  if (q == 0) {
    int dn = dst_sorted[base + m];
    float4 sh4 = reinterpret_cast<const float4*>(esh)[e];
    float zz = z[dn]; zz = (zz == 0.f) ? 1.f : zz;
    float ev = expv[base + m];
    float wgt = sqrtf(fmaxf(ev / zz, 0.f));
    scal[m][0] = sh4.x; scal[m][1] = sh4.y; scal[m][2] = sh4.z; scal[m][3] = sh4.w;
    scal[m][4] = wgt;
    nid[m] = dn;
  } else if (q == 3) {
    int sn = ei[e];
    const float4* f4 = reinterpret_cast<const float4*>(f + (size_t)sn * DIM);
    float v[40];
#pragma unroll
    for (int i = 0; i < 10; i++) {
      float4 t = f4[i];
      v[4 * i] = t.x; v[4 * i + 1] = t.y; v[4 * i + 2] = t.z; v[4 * i + 3] = t.w;
    }
#pragma unroll
    for (int i = 0; i < 16; i++) feE[m][i] = (_Float16)v[i];
#pragma unroll
    for (int k = 0; k < 24; k++)
      feE[m][16 + (k % 3) * 8 + (k / 3)] = (_Float16)v[16 + k];  // [16+c*8+i]
  } else {
    // q=1: h[0..7], q=2: h[8..15]
    float el[10];
    const float2* e2 = reinterpret_cast<const float2*>(emb + (size_t)e * 10);
#pragma unroll
    for (int b = 0; b < 5; b++) { float2 t = e2[b]; el[2 * b] = t.x; el[2 * b + 1] = t.y; }
    const int j0 = (q == 1) ? 0 : 8;
#pragma unroll
    for (int jj = 0; jj < 8; jj++) {
      int j = j0 + jj;
      float a = 0.f;
#pragma unroll
      for (int b = 0; b < 10; b++) a += el[b] * w1[b * 16 + j];
      a *= INV_SQRT_NB;
      float sig = 1.0f / (1.0f + __expf(-a));
      h_s[m][j] = a * sig * H_SCALE;
    }
  }
  __syncthreads();

  // ---- MFMA phase: same k-mappings as rounds 5-11; A from 4 b128 reads ----
  const int w    = tid >> 6;
  const int l    = tid & 63;
  const int row  = l & 15;
  const int kb   = l >> 4;
  const int mrow = w * 16 + row;
  const int col  = l & 15;

  // K-step-invariant A data:
  const int i0 = (kb & 1) * 8;
  f16x8 afs = *reinterpret_cast<const f16x8*>(&feE[mrow][i0]);        // fs[i0..i0+8)
  f16x8 afv0 = *reinterpret_cast<const f16x8*>(&feE[mrow][16]);       // fv[c=0][0..8)
  f16x8 afv1 = *reinterpret_cast<const f16x8*>(&feE[mrow][24]);       // fv[c=1]
  f16x8 afv2 = *reinterpret_cast<const f16x8*>(&feE[mrow][32]);       // fv[c=2]

  f32x4 pfs0 = {0.f, 0.f, 0.f, 0.f}, pfs1 = {0.f, 0.f, 0.f, 0.f};
  f32x4 pc0_0 = {0.f, 0.f, 0.f, 0.f}, pc0_1 = {0.f, 0.f, 0.f, 0.f}, pc0_2 = {0.f, 0.f, 0.f, 0.f};
  f32x4 pc1_0 = {0.f, 0.f, 0.f, 0.f}, pc1_1 = {0.f, 0.f, 0.f, 0.f}, pc1_2 = {0.f, 0.f, 0.f, 0.f};

  // fs path: K=256, 8 K-steps. k = s*32 + kb*8 + j; r = k>>4, i = k&15.
#pragma unroll
  for (int s = 0; s < 8; s++) {
    const int r  = 2 * s + (kb >> 1);
    const _Float16 hr = (_Float16)h_s[mrow][r];
    f16x8 a;
#pragma unroll
    for (int j = 0; j < 8; j++) a[j] = hr * afs[j];
    const int k0 = s * 32 + kb * 8;
    f16x8 b0 = *reinterpret_cast<const f16x8*>(&BtL[col][k0]);
    f16x8 b1 = *reinterpret_cast<const f16x8*>(&BtL[16 + col][k0]);
    pfs0 = __builtin_amdgcn_mfma_f32_16x16x32_f16(a, b0, pfs0, 0, 0, 0);
    pfs1 = __builtin_amdgcn_mfma_f32_16x16x32_f16(a, b1, pfs1, 0, 0, 0);
  }

  // fv path: K=128 per c, 4 K-steps; r = 4s+kb, i = j.
#pragma unroll
  for (int s = 0; s < 4; s++) {
    const int r = 4 * s + kb;
    const _Float16 hr = (_Float16)h_s[mrow][r];
    const int k0 = 256 + s * 32 + kb * 8;
    f16x8 b0 = *reinterpret_cast<const f16x8*>(&BtL[col][k0]);
    f16x8 b1 = *reinterpret_cast<const f16x8*>(&BtL[16 + col][k0]);
#pragma unroll
    for (int c = 0; c < 3; c++) {
      const f16x8 av = (c == 0) ? afv0 : (c == 1) ? afv1 : afv2;
      f16x8 a;
#pragma unroll
      for (int j = 0; j < 8; j++) a[j] = hr * av[j];
      f32x4* p0 = (c == 0) ? &pc0_0 : (c == 1) ? &pc0_1 : &pc0_2;
      f32x4* p1 = (c == 0) ? &pc1_0 : (c == 1) ? &pc1_1 : &pc1_2;
      *p0 = __builtin_amdgcn_mfma_f32_16x16x32_f16(a, b0, *p0, 0, 0, 0);
      *p1 = __builtin_amdgcn_mfma_f32_16x16x32_f16(a, b1, *p1, 0, 0, 0);
    }
  }

  // ---- epilogue: combine with per-edge sh scalars, weighted rows -> LDS ----
#pragma unroll
  for (int j = 0; j < 4; j++) {
    const int me = w * 16 + kb * 4 + j;          // D row = (l>>4)*4 + reg
    const float sh0 = scal[me][0], sh1 = scal[me][1], sh2 = scal[me][2], sh3 = scal[me][3];
    const float wg = scal[me][4];
    float vsc = sh0 * pfs0[j] + sh1 * pc0_0[j] + sh2 * pc0_1[j] + sh3 * pc0_2[j];
    rows[me][col] = wg * vsc;
    if (col < 8) {
      rows[me][16 + col * 3 + 0] = wg * (sh1 * pfs1[j] + sh0 * pc1_0[j]);
      rows[me][16 + col * 3 + 1] = wg * (sh2 * pfs1[j] + sh0 * pc1_1[j]);
      rows[me][16 + col * 3 + 2] = wg * (sh3 * pfs1[j] + sh0 * pc1_2[j]);
    }
  }
  __syncthreads();

  // ---- segmented reduction over sorted dst (direct f_out write) ----
  if (tid < 64) {
    bool head = (m == 0) || (nid[m] != nid[m - 1]);
    unsigned long long mask = __ballot(head);
    if (tid == 0) nseg_s = __popcll(mask);
    if (head) {
      int idx = __popcll(mask & ((1ull << m) - 1ull));
      unsigned long long higher = (m == 63) ? 0ull : (mask >> (m + 1));
      int len = higher ? __ffsll((long long)higher) : (64 - m);
      seg_start[idx] = m; seg_len[idx] = len; seg_nid[idx] = nid[m];
    }
  }
  __syncthreads();

  const int nseg = nseg_s;
  const int d = tid & 63;
  const int g = tid >> 6;
  if (d < DIM) {
    for (int s = g; s < nseg; s += 4) {
      const int st = seg_start[s], ln = seg_len[s];
      float acc = 0.f;
      for (int k2 = 0; k2 < ln; k2++) acc += rows[st + k2][d];
      float* fo = &fout[(size_t)seg_nid[s] * DIM + d];
      if (s > 0 && s < nseg - 1) *fo = acc;   // node fully inside this block
      else atomicAdd(fo, acc);                // may span block boundary
    }
  }
}

extern "C" void kernel_launch(void* const* d_in, const int* in_sizes, int n_in,
                              void* d_out, int out_size, void* d_ws, size_t ws_size,
                              hipStream_t stream) {
  const float* f      = (const float*)d_in[0];
  const int*   ei     = (const int*)d_in[1];
  const float* elen   = (const float*)d_in[2];
  const float* esh    = (const float*)d_in[3];
  const float* emb    = (const float*)d_in[4];
  const float* Wq0    = (const float*)d_in[5];
  const float* Wq1    = (const float*)d_in[6];
  const float* fck_w1 = (const float*)d_in[7];
  const float* fck_w2 = (const float*)d_in[8];
  const float* fcv_w1 = (const float*)d_in[9];
  const float* fcv_w2 = (const float*)d_in[10];
  const float* Wd00   = (const float*)d_in[11];
  const float* Wd11   = (const float*)d_in[12];

  float* out = (float*)d_out;

  char* ws = (char*)d_ws;
  float* qq     = (float*)ws;  ws += (size_t)NN * 64 * 4;
  float* qd     = (float*)ws;  ws += (size_t)NN * DIM * 4;
  float* z      = (float*)ws;  ws += (size_t)NN * 4;
  float* expv   = (float*)ws;  ws += (size_t)NE * 4;
  int*   cnt    = (int*)ws;    ws += (size_t)NN * 4;
  int*   off    = (int*)ws;    ws += (size_t)NN * 4;
  int*   eperm  = (int*)ws;    ws += (size_t)NE * 4;
  int*   dsts   = (int*)ws;    ws += (size_t)NE * 4;
  unsigned short* Btv = (unsigned short*)ws;  ws += (size_t)32 * BKP * 2;
  unsigned short* Btk = (unsigned short*)ws;  ws += (size_t)BKTOT * 2;

  hipMemsetAsync(z, 0, (size_t)NN * 4, stream);
  hipMemsetAsync(cnt, 0, (size_t)NN * 4, stream);
  hipMemsetAsync(out, 0, (size_t)NN * DIM * 4, stream);

  prep_B_kernel<<<32 * BKP / 256, 256, 0, stream>>>(fcv_w2, Btv);
  prep_Bk_kernel<<<BKTOT / 256, 256, 0, stream>>>(fck_w2, Btk);
  node_qd_kernel<<<NN / 256, 256, 0, stream>>>(f, Wq0, Wq1, Wd00, Wd11, qd);
  qq_mfma_kernel<<<NN / 64, 256, 0, stream>>>(f, qd, Btk, qq);
  hist_kernel<<<NE / 256, 256, 0, stream>>>(ei, cnt);
  scan_kernel<<<1, 1024, 0, stream>>>(cnt, off);
  scatter_kernel<<<NE / 256, 256, 0, stream>>>(ei, off, eperm, dsts);
  k_pass_kernel<<<NE / 256, 256, 0, stream>>>(eperm, dsts, elen, esh, emb,
                                              fck_w1, qq, expv, z);
  v_mfma_kernel<<<NE / 64, 256, 0, stream>>>(ei, esh, emb, fcv_w1, f, expv, z,
                                             eperm, dsts, Btv, out);
}

// Round 13
// 122.913 us; speedup vs baseline: 3.0299x; 1.0948x over previous
//
#include <hip/hip_runtime.h>
#include <hip/hip_bf16.h>
#include <math.h>

namespace {
constexpr int NN  = 16384;
constexpr int NE  = 262144;
constexpr int DIM = 40;

constexpr float INV_SQRT3   = 0.5773502691896258f;
constexpr float A_PATH      = 0.2041241452319315f;      // 1/sqrt(24)
constexpr float INV_SQRT_NB = 0.31622776601683794f;     // 1/sqrt(10)
constexpr float H_SCALE     = 0.25f;                    // 1/sqrt(16)
constexpr float QSC_S       = 0.25f;
constexpr float QV_S        = 0.35355339059327373f;
constexpr float D00_S       = 1.0f / (16.0f * 1.4142135623730951f);
constexpr float D11_S       = 1.0f / (8.0f * 1.7320508075688772f * 1.4142135623730951f);

constexpr int BKP = 392;   // v_mfma B k-stride (fp16)
constexpr int K0P = 328;   // qq-GEMM path0 k-stride
constexpr int KCP = 264;   // qq-GEMM pathC k-stride
constexpr int BKTOT = 16 * K0P + 16 * KCP;   // 9472 shorts
constexpr int FEP = 40;    // feE padded row (fp16)

constexpr int PREP_NODE_BLKS = NN / 256;                 // 64
constexpr int PREP_BV_BLKS   = 32 * BKP / 256;           // 49
constexpr int PREP_BK_BLKS   = BKTOT / 256;              // 37
}

typedef __attribute__((ext_vector_type(8))) _Float16 f16x8;
typedef __attribute__((ext_vector_type(4))) float f32x4;

static __device__ __forceinline__ void gload_lds16(const void* g, void* l) {
  __builtin_amdgcn_global_load_lds(
      (const __attribute__((address_space(1))) unsigned*)g,
      (__attribute__((address_space(3))) unsigned*)l, 16, 0, 0);
}

// ---------------------------------------------------------------------------
// prep_kernel: merged node_qd (blocks [0,64), also zeroes cnt) +
// prep_B for v_mfma (blocks [64,113)) + prep_Bk for qq (blocks [113,150)).
// All three bodies byte-identical to their round-11/12 verified forms.
// ---------------------------------------------------------------------------
__global__ __launch_bounds__(256) void prep_kernel(
    const float* __restrict__ f,
    const float* __restrict__ Wq0, const float* __restrict__ Wq1,
    const float* __restrict__ Wd00, const float* __restrict__ Wd11,
    const float* __restrict__ w2v,   // fcv_w2
    const float* __restrict__ w2k,   // fck_w2
    float* __restrict__ qd,
    unsigned short* __restrict__ Btv,
    unsigned short* __restrict__ Btk,
    int* __restrict__ cnt)
{
  const int blk = blockIdx.x;
  if (blk < PREP_NODE_BLKS) {
    // ---- node_qd body (round-7 verified) + cnt zeroing ----
    const int n = blk * 256 + threadIdx.x;
    cnt[n] = 0;

    float fs[16], fv[8][3];
    {
      const float4* fn4 = reinterpret_cast<const float4*>(f + (size_t)n * DIM);
#pragma unroll
      for (int i = 0; i < 10; i++) {
        float4 t = fn4[i];
        int base = i * 4;
#pragma unroll
        for (int k = 0; k < 4; k++) {
          float v = (k == 0) ? t.x : (k == 1) ? t.y : (k == 2) ? t.z : t.w;
          int idx = base + k;
          if (idx < 16) fs[idx] = v;
          else { int r = idx - 16; fv[r / 3][r % 3] = v; }
        }
      }
    }

    float out[40];
    {
      float qsc[16];
#pragma unroll
      for (int o = 0; o < 16; o++) {
        float a = 0.f;
#pragma unroll
        for (int i = 0; i < 16; i++) a += fs[i] * Wq0[i * 16 + o];
        qsc[o] = a * QSC_S;
      }
#pragma unroll
      for (int j = 0; j < 16; j++) {
        float a = 0.f;
#pragma unroll
        for (int i = 0; i < 16; i++) a += qsc[i] * Wd00[i * 16 + j];
        out[j] = a * D00_S;
      }
    }
    {
      float qv[8][3];
#pragma unroll
      for (int o = 0; o < 8; o++)
#pragma unroll
        for (int c = 0; c < 3; c++) {
          float a = 0.f;
#pragma unroll
          for (int i = 0; i < 8; i++) a += fv[i][c] * Wq1[i * 8 + o];
          qv[o][c] = a * QV_S;
        }
#pragma unroll
      for (int j = 0; j < 8; j++)
#pragma unroll
        for (int c = 0; c < 3; c++) {
          float a = 0.f;
#pragma unroll
          for (int i = 0; i < 8; i++) a += qv[i][c] * Wd11[i * 8 + j];
          out[16 + j * 3 + c] = a * D11_S;
        }
    }

    float4* op = reinterpret_cast<float4*>(qd + (size_t)n * DIM);
#pragma unroll
    for (int i = 0; i < 10; i++)
      op[i] = make_float4(out[4 * i], out[4 * i + 1], out[4 * i + 2], out[4 * i + 3]);

  } else if (blk < PREP_NODE_BLKS + PREP_BV_BLKS) {
    // ---- prep_B body (round-10 verified) ----
    int t = (blk - PREP_NODE_BLKS) * 256 + threadIdx.x;
    int col = t / BKP, kp = t % BKP;
    float val = 0.f;
    if (kp < 384 && col < 24) {
      if (kp < 256) {
        int r = kp >> 4, i = kp & 15;
        if (col < 16) val = A_PATH * w2v[r * 576 + i * 16 + col];
        else          val = A_PATH * w2v[r * 576 + 384 + i * 8 + (col - 16)];
      } else {
        int k2 = kp - 256; int r = k2 >> 3, i = k2 & 7;
        if (col < 16) val = A_PATH * INV_SQRT3 * w2v[r * 576 + 256 + i * 16 + col];
        else          val = A_PATH * w2v[r * 576 + 512 + i * 8 + (col - 16)];
      }
    }
    _Float16 hv = (_Float16)val;
    Btv[t] = __builtin_bit_cast(unsigned short, hv);

  } else {
    // ---- prep_Bk body (round-11 verified) ----
    int t = (blk - PREP_NODE_BLKS - PREP_BV_BLKS) * 256 + threadIdx.x;
    float val = 0.f;
    if (t < 16 * K0P) {
      int r = t / K0P, k = t % K0P;
      if (k < 256)      { int i = k >> 4, o = k & 15; val = w2k[r * 576 + i * 16 + o]; }
      else if (k < 320) { int kk = k - 256; int i = kk >> 3, o = kk & 7;
                          val = w2k[r * 576 + 512 + i * 8 + o]; }
    } else {
      int t2 = t - 16 * K0P;
      int r = t2 / KCP, k = t2 % KCP;
      if (k < 128)      { int i = k >> 4, o = k & 15;
                          val = INV_SQRT3 * w2k[r * 576 + 256 + i * 16 + o]; }
      else if (k < 256) { int kk = k - 128; int i = kk >> 3, o = kk & 7;
                          val = w2k[r * 576 + 384 + i * 8 + o]; }
    }
    _Float16 hv = (_Float16)val;
    Btk[t] = __builtin_bit_cast(unsigned short, hv);
  }
}

// ---------------------------------------------------------------------------
// qq via MFMA (round-11 verified, unchanged)
// ---------------------------------------------------------------------------
__global__ __launch_bounds__(256) void qq_mfma_kernel(
    const float* __restrict__ f,
    const float* __restrict__ qd,
    const unsigned short* __restrict__ Btk,
    float* __restrict__ qq)
{
  __shared__ __attribute__((aligned(16))) unsigned short BL[BKTOT];
  __shared__ float fsT[16][65];
  __shared__ float fvT[24][65];
  __shared__ float qd0T[16][65];
  __shared__ float qdvT[24][65];

  const int tid  = threadIdx.x;
  const int base = blockIdx.x * 64;

  {
    const char* src = (const char*)Btk;
    char* dst = (char*)BL;
#pragma unroll
    for (int k2 = 0; k2 < 4; k2++) {
      int off = (k2 * 256 + tid) * 16;
      gload_lds16(src + off, dst + off);
    }
    if (tid < 160) {
      int off = (1024 + tid) * 16;
      gload_lds16(src + off, dst + off);
    }
  }

  const int m = tid & 63;
  const int q = tid >> 6;
  const int n = base + m;

  if (q == 0) {
    const float4* f4 = reinterpret_cast<const float4*>(f + (size_t)n * DIM);
    float v[40];
#pragma unroll
    for (int i = 0; i < 10; i++) {
      float4 t = f4[i];
      v[4 * i] = t.x; v[4 * i + 1] = t.y; v[4 * i + 2] = t.z; v[4 * i + 3] = t.w;
    }
#pragma unroll
    for (int i = 0; i < 16; i++) fsT[i][m] = v[i];
#pragma unroll
    for (int k = 0; k < 24; k++) fvT[(k % 3) * 8 + (k / 3)][m] = v[16 + k];
  } else if (q == 1) {
    const float4* q4 = reinterpret_cast<const float4*>(qd + (size_t)n * DIM);
    float v[40];
#pragma unroll
    for (int i = 0; i < 10; i++) {
      float4 t = q4[i];
      v[4 * i] = t.x; v[4 * i + 1] = t.y; v[4 * i + 2] = t.z; v[4 * i + 3] = t.w;
    }
#pragma unroll
    for (int i = 0; i < 16; i++) qd0T[i][m] = v[i];
#pragma unroll
    for (int k = 0; k < 24; k++) qdvT[(k % 3) * 8 + (k / 3)][m] = v[16 + k];
  }
  __syncthreads();

  const int w    = tid >> 6;
  const int l    = tid & 63;
  const int row  = l & 15;
  const int kb   = l >> 4;
  const int mrow = w * 16 + row;
  const int col  = l & 15;

  f32x4 p0  = {0.f, 0.f, 0.f, 0.f};
  f32x4 pcA = {0.f, 0.f, 0.f, 0.f}, pcB = {0.f, 0.f, 0.f, 0.f}, pcC = {0.f, 0.f, 0.f, 0.f};

#pragma unroll
  for (int s = 0; s < 10; s++) {
    f16x8 a;
    if (s < 8) {
      const int i  = 2 * s + (kb >> 1);
      const int o0 = (kb & 1) * 8;
      const float fsv = fsT[i][mrow];
#pragma unroll
      for (int j = 0; j < 8; j++) a[j] = (_Float16)(fsv * qd0T[o0 + j][mrow]);
    } else {
      const int i = (s - 8) * 4 + kb;
      const float fv0 = fvT[i][mrow], fv1 = fvT[8 + i][mrow], fv2 = fvT[16 + i][mrow];
#pragma unroll
      for (int j = 0; j < 8; j++)
        a[j] = (_Float16)(fv0 * qdvT[j][mrow] + fv1 * qdvT[8 + j][mrow]
                          + fv2 * qdvT[16 + j][mrow]);
    }
    const int k0 = s * 32 + kb * 8;
    f16x8 b = *reinterpret_cast<const f16x8*>(&BL[col * K0P + k0]);
    p0 = __builtin_amdgcn_mfma_f32_16x16x32_f16(a, b, p0, 0, 0, 0);
  }

#pragma unroll
  for (int c = 0; c < 3; c++) {
    f32x4* pc = (c == 0) ? &pcA : (c == 1) ? &pcB : &pcC;
#pragma unroll
    for (int s = 0; s < 8; s++) {
      f16x8 a;
      if (s < 4) {
        const int i  = 2 * s + (kb >> 1);
        const int o0 = (kb & 1) * 8;
        const float fvv = fvT[c * 8 + i][mrow];
#pragma unroll
        for (int j = 0; j < 8; j++) a[j] = (_Float16)(fvv * qd0T[o0 + j][mrow]);
      } else {
        const int i = (s - 4) * 4 + kb;
        const float fsv = fsT[i][mrow];
#pragma unroll
        for (int j = 0; j < 8; j++) a[j] = (_Float16)(fsv * qdvT[c * 8 + j][mrow]);
      }
      const int k0 = s * 32 + kb * 8;
      f16x8 b = *reinterpret_cast<const f16x8*>(&BL[16 * K0P + col * KCP + k0]);
      *pc = __builtin_amdgcn_mfma_f32_16x16x32_f16(a, b, *pc, 0, 0, 0);
    }
  }

#pragma unroll
  for (int j = 0; j < 4; j++) {
    const int me = w * 16 + kb * 4 + j;
    float4 outv = make_float4(A_PATH * p0[j], A_PATH * pcA[j],
                              A_PATH * pcB[j], A_PATH * pcC[j]);
    reinterpret_cast<float4*>(qq)[(size_t)(base + me) * 16 + col] = outv;
  }
}

// ---------------------------------------------------------------------------
// Counting sort by dst
// ---------------------------------------------------------------------------
__global__ __launch_bounds__(256) void hist_kernel(const int* __restrict__ ei,
                                                   int* __restrict__ cnt)
{
  const int e = blockIdx.x * 256 + threadIdx.x;
  atomicAdd(&cnt[ei[NE + e]], 1);
}

// scan also zeroes z (needed before k_pass atomics)
__global__ __launch_bounds__(1024) void scan_kernel(const int* __restrict__ cnt,
                                                    int* __restrict__ off,
                                                    float* __restrict__ z)
{
  __shared__ int part[1024];
  const int t = threadIdx.x;
  const int base = t * 16;
  int loc[16];
  int s = 0;
#pragma unroll
  for (int k = 0; k < 16; k++) { loc[k] = s; s += cnt[base + k]; }
  part[t] = s;
  __syncthreads();
  for (int d = 1; d < 1024; d <<= 1) {
    int v = (t >= d) ? part[t - d] : 0;
    __syncthreads();
    part[t] += v;
    __syncthreads();
  }
  int excl = (t == 0) ? 0 : part[t - 1];
#pragma unroll
  for (int k = 0; k < 16; k++) {
    off[base + k] = excl + loc[k];
    z[base + k] = 0.f;
  }
}

// scatter also zeroes out (needed before v_mfma atomics; runs before it)
__global__ __launch_bounds__(256) void scatter_kernel(const int* __restrict__ ei,
                                                      int* __restrict__ off,
                                                      int* __restrict__ eperm,
                                                      int* __restrict__ dst_sorted,
                                                      float* __restrict__ out)
{
  const int gid = blockIdx.x * 256 + threadIdx.x;
#pragma unroll
  for (int i = 0; i < 3; i++) {
    int idx = gid + i * NE;
    if (idx < NN * DIM) out[idx] = 0.f;
  }
  const int dst = ei[NE + gid];
  int rk = atomicAdd(&off[dst], 1);
  eperm[rk] = gid;
  dst_sorted[rk] = dst;
}

// ---------------------------------------------------------------------------
// K-pass over SORTED ranks (round-9 verified)
// ---------------------------------------------------------------------------
__global__ __launch_bounds__(256) void k_pass_kernel(
    const int*   __restrict__ eperm,
    const int*   __restrict__ dst_sorted,
    const float* __restrict__ elen,
    const float* __restrict__ esh,
    const float* __restrict__ emb,
    const float* __restrict__ w1,
    const float* __restrict__ qq,
    float* __restrict__ expv,
    float* __restrict__ z)
{
  const int rk = blockIdx.x * 256 + threadIdx.x;
  const int e = eperm[rk];
  const int dst = dst_sorted[rk];

  float el[10];
  const float2* e2 = reinterpret_cast<const float2*>(emb + (size_t)e * 10);
#pragma unroll
  for (int b = 0; b < 5; b++) { float2 t = e2[b]; el[2 * b] = t.x; el[2 * b + 1] = t.y; }

  float h[16];
#pragma unroll
  for (int j = 0; j < 16; j++) {
    float a = 0.f;
#pragma unroll
    for (int b = 0; b < 10; b++) a += el[b] * w1[b * 16 + j];
    a *= INV_SQRT_NB;
    float sig = 1.0f / (1.0f + __expf(-a));
    h[j] = a * sig * H_SCALE;
  }

  float4 sh4 = reinterpret_cast<const float4*>(esh)[e];
  const float4* q4 = reinterpret_cast<const float4*>(qq + (size_t)dst * 64);
  float s = 0.f;
#pragma unroll
  for (int r = 0; r < 16; r++) {
    float4 qv = q4[r];
    s += h[r] * (sh4.x * qv.x + sh4.y * qv.y + sh4.z * qv.z + sh4.w * qv.w);
  }

  float len = elen[e];
  float x = 10.0f * (1.0f - len * (1.0f / 1.3f));
  float cut = (x > 0.f) ? __expf(-1.0f / x) : 0.f;
  float ev = cut * __expf(s);
  expv[rk] = ev;
  atomicAdd(&z[dst], ev);
}

// ---------------------------------------------------------------------------
// V-pass via fp16 MFMA (round-12 verified, unchanged)
// ---------------------------------------------------------------------------
__global__ __launch_bounds__(256) void v_mfma_kernel(
    const int*   __restrict__ ei,
    const float* __restrict__ esh,
    const float* __restrict__ emb,
    const float* __restrict__ w1,      // fcv_w1
    const float* __restrict__ f,
    const float* __restrict__ expv,    // by rank
    const float* __restrict__ z,
    const int*   __restrict__ eperm,
    const int*   __restrict__ dst_sorted,
    const unsigned short* __restrict__ Bt,
    float* __restrict__ fout)
{
  __shared__ float h_s[64][17];
  __shared__ __attribute__((aligned(16))) _Float16 feE[64][FEP];
  __shared__ float scal[64][5];
  __shared__ int   nid[64];
  __shared__ __attribute__((aligned(16))) unsigned short BtL[32][BKP];
  __shared__ float rows[64][41];
  __shared__ int seg_start[64], seg_len[64], seg_nid[64];
  __shared__ int nseg_s;

  const int tid  = threadIdx.x;
  const int base = blockIdx.x * 64;

  {
    const char* src = (const char*)Bt;
    char* dst = (char*)&BtL[0][0];
#pragma unroll
    for (int k = 0; k < 6; k++) {
      int off = (k * 256 + tid) * 16;
      gload_lds16(src + off, dst + off);
    }
    if (tid < 32) {
      int off = (1536 + tid) * 16;
      gload_lds16(src + off, dst + off);
    }
  }

  const int m = tid & 63;
  const int q = tid >> 6;
  const int e = eperm[base + m];

  if (q == 0) {
    int dn = dst_sorted[base + m];
    float4 sh4 = reinterpret_cast<const float4*>(esh)[e];
    float zz = z[dn]; zz = (zz == 0.f) ? 1.f : zz;
    float ev = expv[base + m];
    float wgt = sqrtf(fmaxf(ev / zz, 0.f));
    scal[m][0] = sh4.x; scal[m][1] = sh4.y; scal[m][2] = sh4.z; scal[m][3] = sh4.w;
    scal[m][4] = wgt;
    nid[m] = dn;
  } else if (q == 3) {
    int sn = ei[e];
    const float4* f4 = reinterpret_cast<const float4*>(f + (size_t)sn * DIM);
    float v[40];
#pragma unroll
    for (int i = 0; i < 10; i++) {
      float4 t = f4[i];
      v[4 * i] = t.x; v[4 * i + 1] = t.y; v[4 * i + 2] = t.z; v[4 * i + 3] = t.w;
    }
#pragma unroll
    for (int i = 0; i < 16; i++) feE[m][i] = (_Float16)v[i];
#pragma unroll
    for (int k = 0; k < 24; k++)
      feE[m][16 + (k % 3) * 8 + (k / 3)] = (_Float16)v[16 + k];
  } else {
    float el[10];
    const float2* e2 = reinterpret_cast<const float2*>(emb + (size_t)e * 10);
#pragma unroll
    for (int b = 0; b < 5; b++) { float2 t = e2[b]; el[2 * b] = t.x; el[2 * b + 1] = t.y; }
    const int j0 = (q == 1) ? 0 : 8;
#pragma unroll
    for (int jj = 0; jj < 8; jj++) {
      int j = j0 + jj;
      float a = 0.f;
#pragma unroll
      for (int b = 0; b < 10; b++) a += el[b] * w1[b * 16 + j];
      a *= INV_SQRT_NB;
      float sig = 1.0f / (1.0f + __expf(-a));
      h_s[m][j] = a * sig * H_SCALE;
    }
  }
  __syncthreads();

  const int w    = tid >> 6;
  const int l    = tid & 63;
  const int row  = l & 15;
  const int kb   = l >> 4;
  const int mrow = w * 16 + row;
  const int col  = l & 15;

  const int i0 = (kb & 1) * 8;
  f16x8 afs = *reinterpret_cast<const f16x8*>(&feE[mrow][i0]);
  f16x8 afv0 = *reinterpret_cast<const f16x8*>(&feE[mrow][16]);
  f16x8 afv1 = *reinterpret_cast<const f16x8*>(&feE[mrow][24]);
  f16x8 afv2 = *reinterpret_cast<const f16x8*>(&feE[mrow][32]);

  f32x4 pfs0 = {0.f, 0.f, 0.f, 0.f}, pfs1 = {0.f, 0.f, 0.f, 0.f};
  f32x4 pc0_0 = {0.f, 0.f, 0.f, 0.f}, pc0_1 = {0.f, 0.f, 0.f, 0.f}, pc0_2 = {0.f, 0.f, 0.f, 0.f};
  f32x4 pc1_0 = {0.f, 0.f, 0.f, 0.f}, pc1_1 = {0.f, 0.f, 0.f, 0.f}, pc1_2 = {0.f, 0.f, 0.f, 0.f};

#pragma unroll
  for (int s = 0; s < 8; s++) {
    const int r  = 2 * s + (kb >> 1);
    const _Float16 hr = (_Float16)h_s[mrow][r];
    f16x8 a;
#pragma unroll
    for (int j = 0; j < 8; j++) a[j] = hr * afs[j];
    const int k0 = s * 32 + kb * 8;
    f16x8 b0 = *reinterpret_cast<const f16x8*>(&BtL[col][k0]);
    f16x8 b1 = *reinterpret_cast<const f16x8*>(&BtL[16 + col][k0]);
    pfs0 = __builtin_amdgcn_mfma_f32_16x16x32_f16(a, b0, pfs0, 0, 0, 0);
    pfs1 = __builtin_amdgcn_mfma_f32_16x16x32_f16(a, b1, pfs1, 0, 0, 0);
  }

#pragma unroll
  for (int s = 0; s < 4; s++) {
    const int r = 4 * s + kb;
    const _Float16 hr = (_Float16)h_s[mrow][r];
    const int k0 = 256 + s * 32 + kb * 8;
    f16x8 b0 = *reinterpret_cast<const f16x8*>(&BtL[col][k0]);
    f16x8 b1 = *reinterpret_cast<const f16x8*>(&BtL[16 + col][k0]);
#pragma unroll
    for (int c = 0; c < 3; c++) {
      const f16x8 av = (c == 0) ? afv0 : (c == 1) ? afv1 : afv2;
      f16x8 a;
#pragma unroll
      for (int j = 0; j < 8; j++) a[j] = hr * av[j];
      f32x4* p0 = (c == 0) ? &pc0_0 : (c == 1) ? &pc0_1 : &pc0_2;
      f32x4* p1 = (c == 0) ? &pc1_0 : (c == 1) ? &pc1_1 : &pc1_2;
      *p0 = __builtin_amdgcn_mfma_f32_16x16x32_f16(a, b0, *p0, 0, 0, 0);
      *p1 = __builtin_amdgcn_mfma_f32_16x16x32_f16(a, b1, *p1, 0, 0, 0);
    }
  }

#pragma unroll
  for (int j = 0; j < 4; j++) {
    const int me = w * 16 + kb * 4 + j;
    const float sh0 = scal[me][0], sh1 = scal[me][1], sh2 = scal[me][2], sh3 = scal[me][3];
    const float wg = scal[me][4];
    float vsc = sh0 * pfs0[j] + sh1 * pc0_0[j] + sh2 * pc0_1[j] + sh3 * pc0_2[j];
    rows[me][col] = wg * vsc;
    if (col < 8) {
      rows[me][16 + col * 3 + 0] = wg * (sh1 * pfs1[j] + sh0 * pc1_0[j]);
      rows[me][16 + col * 3 + 1] = wg * (sh2 * pfs1[j] + sh0 * pc1_1[j]);
      rows[me][16 + col * 3 + 2] = wg * (sh3 * pfs1[j] + sh0 * pc1_2[j]);
    }
  }
  __syncthreads();

  if (tid < 64) {
    bool head = (m == 0) || (nid[m] != nid[m - 1]);
    unsigned long long mask = __ballot(head);
    if (tid == 0) nseg_s = __popcll(mask);
    if (head) {
      int idx = __popcll(mask & ((1ull << m) - 1ull));
      unsigned long long higher = (m == 63) ? 0ull : (mask >> (m + 1));
      int len = higher ? __ffsll((long long)higher) : (64 - m);
      seg_start[idx] = m; seg_len[idx] = len; seg_nid[idx] = nid[m];
    }
  }
  __syncthreads();

  const int nseg = nseg_s;
  const int d = tid & 63;
  const int g = tid >> 6;
  if (d < DIM) {
    for (int s = g; s < nseg; s += 4) {
      const int st = seg_start[s], ln = seg_len[s];
      float acc = 0.f;
      for (int k2 = 0; k2 < ln; k2++) acc += rows[st + k2][d];
      float* fo = &fout[(size_t)seg_nid[s] * DIM + d];
      if (s > 0 && s < nseg - 1) *fo = acc;
      else atomicAdd(fo, acc);
    }
  }
}

extern "C" void kernel_launch(void* const* d_in, const int* in_sizes, int n_in,
                              void* d_out, int out_size, void* d_ws, size_t ws_size,
                              hipStream_t stream) {
  const float* f      = (const float*)d_in[0];
  const int*   ei     = (const int*)d_in[1];
  const float* elen   = (const float*)d_in[2];
  const float* esh    = (const float*)d_in[3];
  const float* emb    = (const float*)d_in[4];
  const float* Wq0    = (const float*)d_in[5];
  const float* Wq1    = (const float*)d_in[6];
  const float* fck_w1 = (const float*)d_in[7];
  const float* fck_w2 = (const float*)d_in[8];
  const float* fcv_w1 = (const float*)d_in[9];
  const float* fcv_w2 = (const float*)d_in[10];
  const float* Wd00   = (const float*)d_in[11];
  const float* Wd11   = (const float*)d_in[12];

  float* out = (float*)d_out;

  char* ws = (char*)d_ws;
  float* qq     = (float*)ws;  ws += (size_t)NN * 64 * 4;
  float* qd     = (float*)ws;  ws += (size_t)NN * DIM * 4;
  float* z      = (float*)ws;  ws += (size_t)NN * 4;
  float* expv   = (float*)ws;  ws += (size_t)NE * 4;
  int*   cnt    = (int*)ws;    ws += (size_t)NN * 4;
  int*   off    = (int*)ws;    ws += (size_t)NN * 4;
  int*   eperm  = (int*)ws;    ws += (size_t)NE * 4;
  int*   dsts   = (int*)ws;    ws += (size_t)NE * 4;
  unsigned short* Btv = (unsigned short*)ws;  ws += (size_t)32 * BKP * 2;
  unsigned short* Btk = (unsigned short*)ws;  ws += (size_t)BKTOT * 2;

  prep_kernel<<<PREP_NODE_BLKS + PREP_BV_BLKS + PREP_BK_BLKS, 256, 0, stream>>>(
      f, Wq0, Wq1, Wd00, Wd11, fcv_w2, fck_w2, qd, Btv, Btk, cnt);
  hist_kernel<<<NE / 256, 256, 0, stream>>>(ei, cnt);
  scan_kernel<<<1, 1024, 0, stream>>>(cnt, off, z);
  qq_mfma_kernel<<<NN / 64, 256, 0, stream>>>(f, qd, Btk, qq);
  scatter_kernel<<<NE / 256, 256, 0, stream>>>(ei, off, eperm, dsts, out);
  k_pass_kernel<<<NE / 256, 256, 0, stream>>>(eperm, dsts, elen, esh, emb,
                                              fck_w1, qq, expv, z);
  v_mfma_kernel<<<NE / 64, 256, 0, stream>>>(ei, esh, emb, fcv_w1, f, expv, z,
                                             eperm, dsts, Btv, out);
}

// Round 14
// 108.052 us; speedup vs baseline: 3.4466x; 1.1375x over previous
//
#include <hip/hip_runtime.h>
#include <hip/hip_bf16.h>
#include <math.h>

namespace {
constexpr int NN  = 16384;
constexpr int NE  = 262144;
constexpr int DIM = 40;

constexpr float INV_SQRT3   = 0.5773502691896258f;
constexpr float A_PATH      = 0.2041241452319315f;      // 1/sqrt(24)
constexpr float INV_SQRT_NB = 0.31622776601683794f;     // 1/sqrt(10)
constexpr float H_SCALE     = 0.25f;                    // 1/sqrt(16)
constexpr float QSC_S       = 0.25f;
constexpr float QV_S        = 0.35355339059327373f;
constexpr float D00_S       = 1.0f / (16.0f * 1.4142135623730951f);
constexpr float D11_S       = 1.0f / (8.0f * 1.7320508075688772f * 1.4142135623730951f);

constexpr int BKP = 392;   // v_mfma B k-stride (fp16)
constexpr int K0P = 328;   // qq-GEMM path0 k-stride
constexpr int KCP = 264;   // qq-GEMM pathC k-stride
constexpr int BKTOT = 16 * K0P + 16 * KCP;   // 9472 shorts
constexpr int FEP = 40;    // feE padded row (fp16)

constexpr int PREP_NODE_BLKS = NN / 256;                 // 64
constexpr int PREP_BV_BLKS   = 32 * BKP / 256;           // 49
constexpr int PREP_BK_BLKS   = BKTOT / 256;              // 37
}

typedef __attribute__((ext_vector_type(8))) _Float16 f16x8;
typedef __attribute__((ext_vector_type(4))) float f32x4;

static __device__ __forceinline__ void gload_lds16(const void* g, void* l) {
  __builtin_amdgcn_global_load_lds(
      (const __attribute__((address_space(1))) unsigned*)g,
      (__attribute__((address_space(3))) unsigned*)l, 16, 0, 0);
}

// ---------------------------------------------------------------------------
// prep_kernel (round-13 verified): node_qd + cnt zero | prep_Btv | prep_Btk
// ---------------------------------------------------------------------------
__global__ __launch_bounds__(256) void prep_kernel(
    const float* __restrict__ f,
    const float* __restrict__ Wq0, const float* __restrict__ Wq1,
    const float* __restrict__ Wd00, const float* __restrict__ Wd11,
    const float* __restrict__ w2v,   // fcv_w2
    const float* __restrict__ w2k,   // fck_w2
    float* __restrict__ qd,
    unsigned short* __restrict__ Btv,
    unsigned short* __restrict__ Btk,
    int* __restrict__ cnt)
{
  const int blk = blockIdx.x;
  if (blk < PREP_NODE_BLKS) {
    const int n = blk * 256 + threadIdx.x;
    cnt[n] = 0;

    float fs[16], fv[8][3];
    {
      const float4* fn4 = reinterpret_cast<const float4*>(f + (size_t)n * DIM);
#pragma unroll
      for (int i = 0; i < 10; i++) {
        float4 t = fn4[i];
        int base = i * 4;
#pragma unroll
        for (int k = 0; k < 4; k++) {
          float v = (k == 0) ? t.x : (k == 1) ? t.y : (k == 2) ? t.z : t.w;
          int idx = base + k;
          if (idx < 16) fs[idx] = v;
          else { int r = idx - 16; fv[r / 3][r % 3] = v; }
        }
      }
    }

    float out[40];
    {
      float qsc[16];
#pragma unroll
      for (int o = 0; o < 16; o++) {
        float a = 0.f;
#pragma unroll
        for (int i = 0; i < 16; i++) a += fs[i] * Wq0[i * 16 + o];
        qsc[o] = a * QSC_S;
      }
#pragma unroll
      for (int j = 0; j < 16; j++) {
        float a = 0.f;
#pragma unroll
        for (int i = 0; i < 16; i++) a += qsc[i] * Wd00[i * 16 + j];
        out[j] = a * D00_S;
      }
    }
    {
      float qv[8][3];
#pragma unroll
      for (int o = 0; o < 8; o++)
#pragma unroll
        for (int c = 0; c < 3; c++) {
          float a = 0.f;
#pragma unroll
          for (int i = 0; i < 8; i++) a += fv[i][c] * Wq1[i * 8 + o];
          qv[o][c] = a * QV_S;
        }
#pragma unroll
      for (int j = 0; j < 8; j++)
#pragma unroll
        for (int c = 0; c < 3; c++) {
          float a = 0.f;
#pragma unroll
          for (int i = 0; i < 8; i++) a += qv[i][c] * Wd11[i * 8 + j];
          out[16 + j * 3 + c] = a * D11_S;
        }
    }

    float4* op = reinterpret_cast<float4*>(qd + (size_t)n * DIM);
#pragma unroll
    for (int i = 0; i < 10; i++)
      op[i] = make_float4(out[4 * i], out[4 * i + 1], out[4 * i + 2], out[4 * i + 3]);

  } else if (blk < PREP_NODE_BLKS + PREP_BV_BLKS) {
    int t = (blk - PREP_NODE_BLKS) * 256 + threadIdx.x;
    int col = t / BKP, kp = t % BKP;
    float val = 0.f;
    if (kp < 384 && col < 24) {
      if (kp < 256) {
        int r = kp >> 4, i = kp & 15;
        if (col < 16) val = A_PATH * w2v[r * 576 + i * 16 + col];
        else          val = A_PATH * w2v[r * 576 + 384 + i * 8 + (col - 16)];
      } else {
        int k2 = kp - 256; int r = k2 >> 3, i = k2 & 7;
        if (col < 16) val = A_PATH * INV_SQRT3 * w2v[r * 576 + 256 + i * 16 + col];
        else          val = A_PATH * w2v[r * 576 + 512 + i * 8 + (col - 16)];
      }
    }
    _Float16 hv = (_Float16)val;
    Btv[t] = __builtin_bit_cast(unsigned short, hv);

  } else {
    int t = (blk - PREP_NODE_BLKS - PREP_BV_BLKS) * 256 + threadIdx.x;
    float val = 0.f;
    if (t < 16 * K0P) {
      int r = t / K0P, k = t % K0P;
      if (k < 256)      { int i = k >> 4, o = k & 15; val = w2k[r * 576 + i * 16 + o]; }
      else if (k < 320) { int kk = k - 256; int i = kk >> 3, o = kk & 7;
                          val = w2k[r * 576 + 512 + i * 8 + o]; }
    } else {
      int t2 = t - 16 * K0P;
      int r = t2 / KCP, k = t2 % KCP;
      if (k < 128)      { int i = k >> 4, o = k & 15;
                          val = INV_SQRT3 * w2k[r * 576 + 256 + i * 16 + o]; }
      else if (k < 256) { int kk = k - 128; int i = kk >> 3, o = kk & 7;
                          val = w2k[r * 576 + 384 + i * 8 + o]; }
    }
    _Float16 hv = (_Float16)val;
    Btk[t] = __builtin_bit_cast(unsigned short, hv);
  }
}

// ---------------------------------------------------------------------------
// qq via MFMA (round-11 verified, unchanged)
// ---------------------------------------------------------------------------
__global__ __launch_bounds__(256) void qq_mfma_kernel(
    const float* __restrict__ f,
    const float* __restrict__ qd,
    const unsigned short* __restrict__ Btk,
    float* __restrict__ qq)
{
  __shared__ __attribute__((aligned(16))) unsigned short BL[BKTOT];
  __shared__ float fsT[16][65];
  __shared__ float fvT[24][65];
  __shared__ float qd0T[16][65];
  __shared__ float qdvT[24][65];

  const int tid  = threadIdx.x;
  const int base = blockIdx.x * 64;

  {
    const char* src = (const char*)Btk;
    char* dst = (char*)BL;
#pragma unroll
    for (int k2 = 0; k2 < 4; k2++) {
      int off = (k2 * 256 + tid) * 16;
      gload_lds16(src + off, dst + off);
    }
    if (tid < 160) {
      int off = (1024 + tid) * 16;
      gload_lds16(src + off, dst + off);
    }
  }

  const int m = tid & 63;
  const int q = tid >> 6;
  const int n = base + m;

  if (q == 0) {
    const float4* f4 = reinterpret_cast<const float4*>(f + (size_t)n * DIM);
    float v[40];
#pragma unroll
    for (int i = 0; i < 10; i++) {
      float4 t = f4[i];
      v[4 * i] = t.x; v[4 * i + 1] = t.y; v[4 * i + 2] = t.z; v[4 * i + 3] = t.w;
    }
#pragma unroll
    for (int i = 0; i < 16; i++) fsT[i][m] = v[i];
#pragma unroll
    for (int k = 0; k < 24; k++) fvT[(k % 3) * 8 + (k / 3)][m] = v[16 + k];
  } else if (q == 1) {
    const float4* q4 = reinterpret_cast<const float4*>(qd + (size_t)n * DIM);
    float v[40];
#pragma unroll
    for (int i = 0; i < 10; i++) {
      float4 t = q4[i];
      v[4 * i] = t.x; v[4 * i + 1] = t.y; v[4 * i + 2] = t.z; v[4 * i + 3] = t.w;
    }
#pragma unroll
    for (int i = 0; i < 16; i++) qd0T[i][m] = v[i];
#pragma unroll
    for (int k = 0; k < 24; k++) qdvT[(k % 3) * 8 + (k / 3)][m] = v[16 + k];
  }
  __syncthreads();

  const int w    = tid >> 6;
  const int l    = tid & 63;
  const int row  = l & 15;
  const int kb   = l >> 4;
  const int mrow = w * 16 + row;
  const int col  = l & 15;

  f32x4 p0  = {0.f, 0.f, 0.f, 0.f};
  f32x4 pcA = {0.f, 0.f, 0.f, 0.f}, pcB = {0.f, 0.f, 0.f, 0.f}, pcC = {0.f, 0.f, 0.f, 0.f};

#pragma unroll
  for (int s = 0; s < 10; s++) {
    f16x8 a;
    if (s < 8) {
      const int i  = 2 * s + (kb >> 1);
      const int o0 = (kb & 1) * 8;
      const float fsv = fsT[i][mrow];
#pragma unroll
      for (int j = 0; j < 8; j++) a[j] = (_Float16)(fsv * qd0T[o0 + j][mrow]);
    } else {
      const int i = (s - 8) * 4 + kb;
      const float fv0 = fvT[i][mrow], fv1 = fvT[8 + i][mrow], fv2 = fvT[16 + i][mrow];
#pragma unroll
      for (int j = 0; j < 8; j++)
        a[j] = (_Float16)(fv0 * qdvT[j][mrow] + fv1 * qdvT[8 + j][mrow]
                          + fv2 * qdvT[16 + j][mrow]);
    }
    const int k0 = s * 32 + kb * 8;
    f16x8 b = *reinterpret_cast<const f16x8*>(&BL[col * K0P + k0]);
    p0 = __builtin_amdgcn_mfma_f32_16x16x32_f16(a, b, p0, 0, 0, 0);
  }

#pragma unroll
  for (int c = 0; c < 3; c++) {
    f32x4* pc = (c == 0) ? &pcA : (c == 1) ? &pcB : &pcC;
#pragma unroll
    for (int s = 0; s < 8; s++) {
      f16x8 a;
      if (s < 4) {
        const int i  = 2 * s + (kb >> 1);
        const int o0 = (kb & 1) * 8;
        const float fvv = fvT[c * 8 + i][mrow];
#pragma unroll
        for (int j = 0; j < 8; j++) a[j] = (_Float16)(fvv * qd0T[o0 + j][mrow]);
      } else {
        const int i = (s - 4) * 4 + kb;
        const float fsv = fsT[i][mrow];
#pragma unroll
        for (int j = 0; j < 8; j++) a[j] = (_Float16)(fsv * qdvT[c * 8 + j][mrow]);
      }
      const int k0 = s * 32 + kb * 8;
      f16x8 b = *reinterpret_cast<const f16x8*>(&BL[16 * K0P + col * KCP + k0]);
      *pc = __builtin_amdgcn_mfma_f32_16x16x32_f16(a, b, *pc, 0, 0, 0);
    }
  }

#pragma unroll
  for (int j = 0; j < 4; j++) {
    const int me = w * 16 + kb * 4 + j;
    float4 outv = make_float4(A_PATH * p0[j], A_PATH * pcA[j],
                              A_PATH * pcB[j], A_PATH * pcC[j]);
    reinterpret_cast<float4*>(qq)[(size_t)(base + me) * 16 + col] = outv;
  }
}

// ---------------------------------------------------------------------------
// Counting sort: hist + scan (scan zeroes z)
// ---------------------------------------------------------------------------
__global__ __launch_bounds__(256) void hist_kernel(const int* __restrict__ ei,
                                                   int* __restrict__ cnt)
{
  const int e = blockIdx.x * 256 + threadIdx.x;
  atomicAdd(&cnt[ei[NE + e]], 1);
}

__global__ __launch_bounds__(1024) void scan_kernel(const int* __restrict__ cnt,
                                                    int* __restrict__ off,
                                                    float* __restrict__ z)
{
  __shared__ int part[1024];
  const int t = threadIdx.x;
  const int base = t * 16;
  int loc[16];
  int s = 0;
#pragma unroll
  for (int k = 0; k < 16; k++) { loc[k] = s; s += cnt[base + k]; }
  part[t] = s;
  __syncthreads();
  for (int d = 1; d < 1024; d <<= 1) {
    int v = (t >= d) ? part[t - d] : 0;
    __syncthreads();
    part[t] += v;
    __syncthreads();
  }
  int excl = (t == 0) ? 0 : part[t - 1];
#pragma unroll
  for (int k = 0; k < 16; k++) {
    off[base + k] = excl + loc[k];
    z[base + k] = 0.f;
  }
}

// ---------------------------------------------------------------------------
// edge_kernel (fused scatter + k_pass + V-side radial precompute), e-ordered:
// coalesced ei/elen/esh/emb reads; computes rank, score, expv[rk], z-atomic;
// ALSO computes h_v (fcv_w1) once here, storing hv/esh/src/dst BY RANK so
// v_mfma reads them sequentially. Also zeroes out[].
// ---------------------------------------------------------------------------
__global__ __launch_bounds__(256) void edge_kernel(
    const int*   __restrict__ ei,
    const float* __restrict__ elen,
    const float* __restrict__ esh,
    const float* __restrict__ emb,
    const float* __restrict__ w1k,    // fck_w1
    const float* __restrict__ w1v,    // fcv_w1
    const float* __restrict__ qq,
    int*   __restrict__ off,
    int*   __restrict__ dsts,
    int*   __restrict__ srcs,
    float* __restrict__ esh_rank,
    _Float16* __restrict__ hv_rank,
    float* __restrict__ expv,
    float* __restrict__ z,
    float* __restrict__ out)
{
  const int gid = blockIdx.x * 256 + threadIdx.x;
#pragma unroll
  for (int i = 0; i < 3; i++) {
    int idx = gid + i * NE;
    if (idx < NN * DIM) out[idx] = 0.f;
  }

  const int src = ei[gid];
  const int dst = ei[NE + gid];
  const int rk = atomicAdd(&off[dst], 1);

  float el[10];
  const float2* e2 = reinterpret_cast<const float2*>(emb + (size_t)gid * 10);
#pragma unroll
  for (int b = 0; b < 5; b++) { float2 t = e2[b]; el[2 * b] = t.x; el[2 * b + 1] = t.y; }

  // K-side radial h (round-9 verified math)
  float h[16];
#pragma unroll
  for (int j = 0; j < 16; j++) {
    float a = 0.f;
#pragma unroll
    for (int b = 0; b < 10; b++) a += el[b] * w1k[b * 16 + j];
    a *= INV_SQRT_NB;
    float sig = 1.0f / (1.0f + __expf(-a));
    h[j] = a * sig * H_SCALE;
  }

  float4 sh4 = reinterpret_cast<const float4*>(esh)[gid];
  const float4* q4 = reinterpret_cast<const float4*>(qq + (size_t)dst * 64);
  float s = 0.f;
#pragma unroll
  for (int r = 0; r < 16; r++) {
    float4 qv = q4[r];
    s += h[r] * (sh4.x * qv.x + sh4.y * qv.y + sh4.z * qv.z + sh4.w * qv.w);
  }

  float len = elen[gid];
  float x = 10.0f * (1.0f - len * (1.0f / 1.3f));
  float cut = (x > 0.f) ? __expf(-1.0f / x) : 0.f;
  float ev = cut * __expf(s);
  expv[rk] = ev;
  atomicAdd(&z[dst], ev);

  // V-side radial h (identical formula, fcv_w1), stored fp16 by rank
  f16x8 hv0, hv1;
#pragma unroll
  for (int j = 0; j < 16; j++) {
    float a = 0.f;
#pragma unroll
    for (int b = 0; b < 10; b++) a += el[b] * w1v[b * 16 + j];
    a *= INV_SQRT_NB;
    float sig = 1.0f / (1.0f + __expf(-a));
    _Float16 hh = (_Float16)(a * sig * H_SCALE);
    if (j < 8) hv0[j] = hh; else hv1[j - 8] = hh;
  }
  f16x8* hvp = reinterpret_cast<f16x8*>(hv_rank + (size_t)rk * 16);
  hvp[0] = hv0;
  hvp[1] = hv1;

  dsts[rk] = dst;
  srcs[rk] = src;
  reinterpret_cast<float4*>(esh_rank)[rk] = sh4;
}

// ---------------------------------------------------------------------------
// V-pass via fp16 MFMA (round-12 verified MFMA/epilogue/tail); staging now
// reads rank-ordered hv/esh/src/dst sequentially — no emb gather, no radial
// recompute, no eperm indirection. Only f[src] remains a gather.
// ---------------------------------------------------------------------------
__global__ __launch_bounds__(256) void v_mfma_kernel(
    const float* __restrict__ f,
    const float* __restrict__ expv,      // by rank
    const float* __restrict__ z,
    const int*   __restrict__ dsts,      // by rank
    const int*   __restrict__ srcs,      // by rank
    const float* __restrict__ esh_rank,  // by rank
    const _Float16* __restrict__ hv_rank,// by rank
    const unsigned short* __restrict__ Bt,
    float* __restrict__ fout)
{
  __shared__ float h_s[64][17];
  __shared__ __attribute__((aligned(16))) _Float16 feE[64][FEP];
  __shared__ float scal[64][5];
  __shared__ int   nid[64];
  __shared__ __attribute__((aligned(16))) unsigned short BtL[32][BKP];
  __shared__ float rows[64][41];
  __shared__ int seg_start[64], seg_len[64], seg_nid[64];
  __shared__ int nseg_s;

  const int tid  = threadIdx.x;
  const int base = blockIdx.x * 64;

  {
    const char* src = (const char*)Bt;
    char* dst = (char*)&BtL[0][0];
#pragma unroll
    for (int k = 0; k < 6; k++) {
      int off = (k * 256 + tid) * 16;
      gload_lds16(src + off, dst + off);
    }
    if (tid < 32) {
      int off = (1536 + tid) * 16;
      gload_lds16(src + off, dst + off);
    }
  }

  const int m = tid & 63;
  const int q = tid >> 6;

  if (q == 0) {
    int dn = dsts[base + m];
    float4 sh4 = reinterpret_cast<const float4*>(esh_rank)[base + m];
    float zz = z[dn]; zz = (zz == 0.f) ? 1.f : zz;
    float ev = expv[base + m];
    float wgt = sqrtf(fmaxf(ev / zz, 0.f));
    scal[m][0] = sh4.x; scal[m][1] = sh4.y; scal[m][2] = sh4.z; scal[m][3] = sh4.w;
    scal[m][4] = wgt;
    nid[m] = dn;
  } else if (q == 3) {
    int sn = srcs[base + m];
    const float4* f4 = reinterpret_cast<const float4*>(f + (size_t)sn * DIM);
    float v[40];
#pragma unroll
    for (int i = 0; i < 10; i++) {
      float4 t = f4[i];
      v[4 * i] = t.x; v[4 * i + 1] = t.y; v[4 * i + 2] = t.z; v[4 * i + 3] = t.w;
    }
#pragma unroll
    for (int i = 0; i < 16; i++) feE[m][i] = (_Float16)v[i];
#pragma unroll
    for (int k = 0; k < 24; k++)
      feE[m][16 + (k % 3) * 8 + (k / 3)] = (_Float16)v[16 + k];
  } else if (q == 1) {
    // sequential fp16 load of hv -> h_s (fp32; fp16->fp32->fp16 is exact)
    const f16x8* hp = reinterpret_cast<const f16x8*>(hv_rank + (size_t)(base + m) * 16);
    f16x8 h0 = hp[0], h1 = hp[1];
#pragma unroll
    for (int j = 0; j < 8; j++) {
      h_s[m][j]     = (float)h0[j];
      h_s[m][8 + j] = (float)h1[j];
    }
  }
  __syncthreads();

  const int w    = tid >> 6;
  const int l    = tid & 63;
  const int row  = l & 15;
  const int kb   = l >> 4;
  const int mrow = w * 16 + row;
  const int col  = l & 15;

  const int i0 = (kb & 1) * 8;
  f16x8 afs = *reinterpret_cast<const f16x8*>(&feE[mrow][i0]);
  f16x8 afv0 = *reinterpret_cast<const f16x8*>(&feE[mrow][16]);
  f16x8 afv1 = *reinterpret_cast<const f16x8*>(&feE[mrow][24]);
  f16x8 afv2 = *reinterpret_cast<const f16x8*>(&feE[mrow][32]);

  f32x4 pfs0 = {0.f, 0.f, 0.f, 0.f}, pfs1 = {0.f, 0.f, 0.f, 0.f};
  f32x4 pc0_0 = {0.f, 0.f, 0.f, 0.f}, pc0_1 = {0.f, 0.f, 0.f, 0.f}, pc0_2 = {0.f, 0.f, 0.f, 0.f};
  f32x4 pc1_0 = {0.f, 0.f, 0.f, 0.f}, pc1_1 = {0.f, 0.f, 0.f, 0.f}, pc1_2 = {0.f, 0.f, 0.f, 0.f};

#pragma unroll
  for (int s = 0; s < 8; s++) {
    const int r  = 2 * s + (kb >> 1);
    const _Float16 hr = (_Float16)h_s[mrow][r];
    f16x8 a;
#pragma unroll
    for (int j = 0; j < 8; j++) a[j] = hr * afs[j];
    const int k0 = s * 32 + kb * 8;
    f16x8 b0 = *reinterpret_cast<const f16x8*>(&BtL[col][k0]);
    f16x8 b1 = *reinterpret_cast<const f16x8*>(&BtL[16 + col][k0]);
    pfs0 = __builtin_amdgcn_mfma_f32_16x16x32_f16(a, b0, pfs0, 0, 0, 0);
    pfs1 = __builtin_amdgcn_mfma_f32_16x16x32_f16(a, b1, pfs1, 0, 0, 0);
  }

#pragma unroll
  for (int s = 0; s < 4; s++) {
    const int r = 4 * s + kb;
    const _Float16 hr = (_Float16)h_s[mrow][r];
    const int k0 = 256 + s * 32 + kb * 8;
    f16x8 b0 = *reinterpret_cast<const f16x8*>(&BtL[col][k0]);
    f16x8 b1 = *reinterpret_cast<const f16x8*>(&BtL[16 + col][k0]);
#pragma unroll
    for (int c = 0; c < 3; c++) {
      const f16x8 av = (c == 0) ? afv0 : (c == 1) ? afv1 : afv2;
      f16x8 a;
#pragma unroll
      for (int j = 0; j < 8; j++) a[j] = hr * av[j];
      f32x4* p0 = (c == 0) ? &pc0_0 : (c == 1) ? &pc0_1 : &pc0_2;
      f32x4* p1 = (c == 0) ? &pc1_0 : (c == 1) ? &pc1_1 : &pc1_2;
      *p0 = __builtin_amdgcn_mfma_f32_16x16x32_f16(a, b0, *p0, 0, 0, 0);
      *p1 = __builtin_amdgcn_mfma_f32_16x16x32_f16(a, b1, *p1, 0, 0, 0);
    }
  }

#pragma unroll
  for (int j = 0; j < 4; j++) {
    const int me = w * 16 + kb * 4 + j;
    const float sh0 = scal[me][0], sh1 = scal[me][1], sh2 = scal[me][2], sh3 = scal[me][3];
    const float wg = scal[me][4];
    float vsc = sh0 * pfs0[j] + sh1 * pc0_0[j] + sh2 * pc0_1[j] + sh3 * pc0_2[j];
    rows[me][col] = wg * vsc;
    if (col < 8) {
      rows[me][16 + col * 3 + 0] = wg * (sh1 * pfs1[j] + sh0 * pc1_0[j]);
      rows[me][16 + col * 3 + 1] = wg * (sh2 * pfs1[j] + sh0 * pc1_1[j]);
      rows[me][16 + col * 3 + 2] = wg * (sh3 * pfs1[j] + sh0 * pc1_2[j]);
    }
  }
  __syncthreads();

  if (tid < 64) {
    bool head = (m == 0) || (nid[m] != nid[m - 1]);
    unsigned long long mask = __ballot(head);
    if (tid == 0) nseg_s = __popcll(mask);
    if (head) {
      int idx = __popcll(mask & ((1ull << m) - 1ull));
      unsigned long long higher = (m == 63) ? 0ull : (mask >> (m + 1));
      int len = higher ? __ffsll((long long)higher) : (64 - m);
      seg_start[idx] = m; seg_len[idx] = len; seg_nid[idx] = nid[m];
    }
  }
  __syncthreads();

  const int nseg = nseg_s;
  const int d = tid & 63;
  const int g = tid >> 6;
  if (d < DIM) {
    for (int s = g; s < nseg; s += 4) {
      const int st = seg_start[s], ln = seg_len[s];
      float acc = 0.f;
      for (int k2 = 0; k2 < ln; k2++) acc += rows[st + k2][d];
      float* fo = &fout[(size_t)seg_nid[s] * DIM + d];
      if (s > 0 && s < nseg - 1) *fo = acc;
      else atomicAdd(fo, acc);
    }
  }
}

extern "C" void kernel_launch(void* const* d_in, const int* in_sizes, int n_in,
                              void* d_out, int out_size, void* d_ws, size_t ws_size,
                              hipStream_t stream) {
  const float* f      = (const float*)d_in[0];
  const int*   ei     = (const int*)d_in[1];
  const float* elen   = (const float*)d_in[2];
  const float* esh    = (const float*)d_in[3];
  const float* emb    = (const float*)d_in[4];
  const float* Wq0    = (const float*)d_in[5];
  const float* Wq1    = (const float*)d_in[6];
  const float* fck_w1 = (const float*)d_in[7];
  const float* fck_w2 = (const float*)d_in[8];
  const float* fcv_w1 = (const float*)d_in[9];
  const float* fcv_w2 = (const float*)d_in[10];
  const float* Wd00   = (const float*)d_in[11];
  const float* Wd11   = (const float*)d_in[12];

  float* out = (float*)d_out;

  char* ws = (char*)d_ws;
  float* qq       = (float*)ws;  ws += (size_t)NN * 64 * 4;
  float* qd       = (float*)ws;  ws += (size_t)NN * DIM * 4;
  float* z        = (float*)ws;  ws += (size_t)NN * 4;
  float* expv     = (float*)ws;  ws += (size_t)NE * 4;
  int*   cnt      = (int*)ws;    ws += (size_t)NN * 4;
  int*   off      = (int*)ws;    ws += (size_t)NN * 4;
  int*   dsts     = (int*)ws;    ws += (size_t)NE * 4;
  int*   srcs     = (int*)ws;    ws += (size_t)NE * 4;
  float* esh_rank = (float*)ws;  ws += (size_t)NE * 4 * 4;
  _Float16* hv_rank = (_Float16*)ws;  ws += (size_t)NE * 16 * 2;
  unsigned short* Btv = (unsigned short*)ws;  ws += (size_t)32 * BKP * 2;
  unsigned short* Btk = (unsigned short*)ws;  ws += (size_t)BKTOT * 2;

  prep_kernel<<<PREP_NODE_BLKS + PREP_BV_BLKS + PREP_BK_BLKS, 256, 0, stream>>>(
      f, Wq0, Wq1, Wd00, Wd11, fcv_w2, fck_w2, qd, Btv, Btk, cnt);
  hist_kernel<<<NE / 256, 256, 0, stream>>>(ei, cnt);
  scan_kernel<<<1, 1024, 0, stream>>>(cnt, off, z);
  qq_mfma_kernel<<<NN / 64, 256, 0, stream>>>(f, qd, Btk, qq);
  edge_kernel<<<NE / 256, 256, 0, stream>>>(ei, elen, esh, emb, fck_w1, fcv_w1,
                                            qq, off, dsts, srcs, esh_rank,
                                            hv_rank, expv, z, out);
  v_mfma_kernel<<<NE / 64, 256, 0, stream>>>(f, expv, z, dsts, srcs, esh_rank,
                                             hv_rank, Btv, out);
}

// Round 15
// 101.366 us; speedup vs baseline: 3.6739x; 1.0660x over previous
//
#include <hip/hip_runtime.h>
#include <hip/hip_bf16.h>
#include <math.h>

namespace {
constexpr int NN  = 16384;
constexpr int NE  = 262144;
constexpr int DIM = 40;

constexpr float INV_SQRT3   = 0.5773502691896258f;
constexpr float A_PATH      = 0.2041241452319315f;      // 1/sqrt(24)
constexpr float INV_SQRT_NB = 0.31622776601683794f;     // 1/sqrt(10)
constexpr float H_SCALE     = 0.25f;                    // 1/sqrt(16)
constexpr float QSC_S       = 0.25f;
constexpr float QV_S        = 0.35355339059327373f;
constexpr float D00_S       = 1.0f / (16.0f * 1.4142135623730951f);
constexpr float D11_S       = 1.0f / (8.0f * 1.7320508075688772f * 1.4142135623730951f);

constexpr int BKP = 392;   // v_mfma B k-stride (fp16)
constexpr int K0P = 328;   // qq-GEMM path0 k-stride
constexpr int KCP = 264;   // qq-GEMM pathC k-stride
constexpr int BKTOT = 16 * K0P + 16 * KCP;   // 9472 shorts
constexpr int FEP = 40;    // feE padded row (fp16)

constexpr int PREP_NODE_BLKS = NN / 256;                 // 64
constexpr int PREP_BV_BLKS   = 32 * BKP / 256;           // 49
constexpr int PREP_BK_BLKS   = BKTOT / 256;              // 37
}

typedef __attribute__((ext_vector_type(8))) _Float16 f16x8;
typedef __attribute__((ext_vector_type(4))) float f32x4;

static __device__ __forceinline__ void gload_lds16(const void* g, void* l) {
  __builtin_amdgcn_global_load_lds(
      (const __attribute__((address_space(1))) unsigned*)g,
      (__attribute__((address_space(3))) unsigned*)l, 16, 0, 0);
}

// ---------------------------------------------------------------------------
// prep_kernel (round-13 verified): node_qd + cnt zero | prep_Btv | prep_Btk
// ---------------------------------------------------------------------------
__global__ __launch_bounds__(256) void prep_kernel(
    const float* __restrict__ f,
    const float* __restrict__ Wq0, const float* __restrict__ Wq1,
    const float* __restrict__ Wd00, const float* __restrict__ Wd11,
    const float* __restrict__ w2v,   // fcv_w2
    const float* __restrict__ w2k,   // fck_w2
    float* __restrict__ qd,
    unsigned short* __restrict__ Btv,
    unsigned short* __restrict__ Btk,
    int* __restrict__ cnt)
{
  const int blk = blockIdx.x;
  if (blk < PREP_NODE_BLKS) {
    const int n = blk * 256 + threadIdx.x;
    cnt[n] = 0;

    float fs[16], fv[8][3];
    {
      const float4* fn4 = reinterpret_cast<const float4*>(f + (size_t)n * DIM);
#pragma unroll
      for (int i = 0; i < 10; i++) {
        float4 t = fn4[i];
        int base = i * 4;
#pragma unroll
        for (int k = 0; k < 4; k++) {
          float v = (k == 0) ? t.x : (k == 1) ? t.y : (k == 2) ? t.z : t.w;
          int idx = base + k;
          if (idx < 16) fs[idx] = v;
          else { int r = idx - 16; fv[r / 3][r % 3] = v; }
        }
      }
    }

    float out[40];
    {
      float qsc[16];
#pragma unroll
      for (int o = 0; o < 16; o++) {
        float a = 0.f;
#pragma unroll
        for (int i = 0; i < 16; i++) a += fs[i] * Wq0[i * 16 + o];
        qsc[o] = a * QSC_S;
      }
#pragma unroll
      for (int j = 0; j < 16; j++) {
        float a = 0.f;
#pragma unroll
        for (int i = 0; i < 16; i++) a += qsc[i] * Wd00[i * 16 + j];
        out[j] = a * D00_S;
      }
    }
    {
      float qv[8][3];
#pragma unroll
      for (int o = 0; o < 8; o++)
#pragma unroll
        for (int c = 0; c < 3; c++) {
          float a = 0.f;
#pragma unroll
          for (int i = 0; i < 8; i++) a += fv[i][c] * Wq1[i * 8 + o];
          qv[o][c] = a * QV_S;
        }
#pragma unroll
      for (int j = 0; j < 8; j++)
#pragma unroll
        for (int c = 0; c < 3; c++) {
          float a = 0.f;
#pragma unroll
          for (int i = 0; i < 8; i++) a += qv[i][c] * Wd11[i * 8 + j];
          out[16 + j * 3 + c] = a * D11_S;
        }
    }

    float4* op = reinterpret_cast<float4*>(qd + (size_t)n * DIM);
#pragma unroll
    for (int i = 0; i < 10; i++)
      op[i] = make_float4(out[4 * i], out[4 * i + 1], out[4 * i + 2], out[4 * i + 3]);

  } else if (blk < PREP_NODE_BLKS + PREP_BV_BLKS) {
    int t = (blk - PREP_NODE_BLKS) * 256 + threadIdx.x;
    int col = t / BKP, kp = t % BKP;
    float val = 0.f;
    if (kp < 384 && col < 24) {
      if (kp < 256) {
        int r = kp >> 4, i = kp & 15;
        if (col < 16) val = A_PATH * w2v[r * 576 + i * 16 + col];
        else          val = A_PATH * w2v[r * 576 + 384 + i * 8 + (col - 16)];
      } else {
        int k2 = kp - 256; int r = k2 >> 3, i = k2 & 7;
        if (col < 16) val = A_PATH * INV_SQRT3 * w2v[r * 576 + 256 + i * 16 + col];
        else          val = A_PATH * w2v[r * 576 + 512 + i * 8 + (col - 16)];
      }
    }
    _Float16 hv = (_Float16)val;
    Btv[t] = __builtin_bit_cast(unsigned short, hv);

  } else {
    int t = (blk - PREP_NODE_BLKS - PREP_BV_BLKS) * 256 + threadIdx.x;
    float val = 0.f;
    if (t < 16 * K0P) {
      int r = t / K0P, k = t % K0P;
      if (k < 256)      { int i = k >> 4, o = k & 15; val = w2k[r * 576 + i * 16 + o]; }
      else if (k < 320) { int kk = k - 256; int i = kk >> 3, o = kk & 7;
                          val = w2k[r * 576 + 512 + i * 8 + o]; }
    } else {
      int t2 = t - 16 * K0P;
      int r = t2 / KCP, k = t2 % KCP;
      if (k < 128)      { int i = k >> 4, o = k & 15;
                          val = INV_SQRT3 * w2k[r * 576 + 256 + i * 16 + o]; }
      else if (k < 256) { int kk = k - 128; int i = kk >> 3, o = kk & 7;
                          val = w2k[r * 576 + 384 + i * 8 + o]; }
    }
    _Float16 hv = (_Float16)val;
    Btk[t] = __builtin_bit_cast(unsigned short, hv);
  }
}

// ---------------------------------------------------------------------------
// qq via MFMA (round-11 verified, unchanged)
// ---------------------------------------------------------------------------
__global__ __launch_bounds__(256) void qq_mfma_kernel(
    const float* __restrict__ f,
    const float* __restrict__ qd,
    const unsigned short* __restrict__ Btk,
    float* __restrict__ qq)
{
  __shared__ __attribute__((aligned(16))) unsigned short BL[BKTOT];
  __shared__ float fsT[16][65];
  __shared__ float fvT[24][65];
  __shared__ float qd0T[16][65];
  __shared__ float qdvT[24][65];

  const int tid  = threadIdx.x;
  const int base = blockIdx.x * 64;

  {
    const char* src = (const char*)Btk;
    char* dst = (char*)BL;
#pragma unroll
    for (int k2 = 0; k2 < 4; k2++) {
      int off = (k2 * 256 + tid) * 16;
      gload_lds16(src + off, dst + off);
    }
    if (tid < 160) {
      int off = (1024 + tid) * 16;
      gload_lds16(src + off, dst + off);
    }
  }

  const int m = tid & 63;
  const int q = tid >> 6;
  const int n = base + m;

  if (q == 0) {
    const float4* f4 = reinterpret_cast<const float4*>(f + (size_t)n * DIM);
    float v[40];
#pragma unroll
    for (int i = 0; i < 10; i++) {
      float4 t = f4[i];
      v[4 * i] = t.x; v[4 * i + 1] = t.y; v[4 * i + 2] = t.z; v[4 * i + 3] = t.w;
    }
#pragma unroll
    for (int i = 0; i < 16; i++) fsT[i][m] = v[i];
#pragma unroll
    for (int k = 0; k < 24; k++) fvT[(k % 3) * 8 + (k / 3)][m] = v[16 + k];
  } else if (q == 1) {
    const float4* q4 = reinterpret_cast<const float4*>(qd + (size_t)n * DIM);
    float v[40];
#pragma unroll
    for (int i = 0; i < 10; i++) {
      float4 t = q4[i];
      v[4 * i] = t.x; v[4 * i + 1] = t.y; v[4 * i + 2] = t.z; v[4 * i + 3] = t.w;
    }
#pragma unroll
    for (int i = 0; i < 16; i++) qd0T[i][m] = v[i];
#pragma unroll
    for (int k = 0; k < 24; k++) qdvT[(k % 3) * 8 + (k / 3)][m] = v[16 + k];
  }
  __syncthreads();

  const int w    = tid >> 6;
  const int l    = tid & 63;
  const int row  = l & 15;
  const int kb   = l >> 4;
  const int mrow = w * 16 + row;
  const int col  = l & 15;

  f32x4 p0  = {0.f, 0.f, 0.f, 0.f};
  f32x4 pcA = {0.f, 0.f, 0.f, 0.f}, pcB = {0.f, 0.f, 0.f, 0.f}, pcC = {0.f, 0.f, 0.f, 0.f};

#pragma unroll
  for (int s = 0; s < 10; s++) {
    f16x8 a;
    if (s < 8) {
      const int i  = 2 * s + (kb >> 1);
      const int o0 = (kb & 1) * 8;
      const float fsv = fsT[i][mrow];
#pragma unroll
      for (int j = 0; j < 8; j++) a[j] = (_Float16)(fsv * qd0T[o0 + j][mrow]);
    } else {
      const int i = (s - 8) * 4 + kb;
      const float fv0 = fvT[i][mrow], fv1 = fvT[8 + i][mrow], fv2 = fvT[16 + i][mrow];
#pragma unroll
      for (int j = 0; j < 8; j++)
        a[j] = (_Float16)(fv0 * qdvT[j][mrow] + fv1 * qdvT[8 + j][mrow]
                          + fv2 * qdvT[16 + j][mrow]);
    }
    const int k0 = s * 32 + kb * 8;
    f16x8 b = *reinterpret_cast<const f16x8*>(&BL[col * K0P + k0]);
    p0 = __builtin_amdgcn_mfma_f32_16x16x32_f16(a, b, p0, 0, 0, 0);
  }

#pragma unroll
  for (int c = 0; c < 3; c++) {
    f32x4* pc = (c == 0) ? &pcA : (c == 1) ? &pcB : &pcC;
#pragma unroll
    for (int s = 0; s < 8; s++) {
      f16x8 a;
      if (s < 4) {
        const int i  = 2 * s + (kb >> 1);
        const int o0 = (kb & 1) * 8;
        const float fvv = fvT[c * 8 + i][mrow];
#pragma unroll
        for (int j = 0; j < 8; j++) a[j] = (_Float16)(fvv * qd0T[o0 + j][mrow]);
      } else {
        const int i = (s - 4) * 4 + kb;
        const float fsv = fsT[i][mrow];
#pragma unroll
        for (int j = 0; j < 8; j++) a[j] = (_Float16)(fsv * qdvT[c * 8 + j][mrow]);
      }
      const int k0 = s * 32 + kb * 8;
      f16x8 b = *reinterpret_cast<const f16x8*>(&BL[16 * K0P + col * KCP + k0]);
      *pc = __builtin_amdgcn_mfma_f32_16x16x32_f16(a, b, *pc, 0, 0, 0);
    }
  }

#pragma unroll
  for (int j = 0; j < 4; j++) {
    const int me = w * 16 + kb * 4 + j;
    float4 outv = make_float4(A_PATH * p0[j], A_PATH * pcA[j],
                              A_PATH * pcB[j], A_PATH * pcC[j]);
    reinterpret_cast<float4*>(qq)[(size_t)(base + me) * 16 + col] = outv;
  }
}

// ---------------------------------------------------------------------------
// Counting sort: hist + scan (scan zeroes z)
// ---------------------------------------------------------------------------
__global__ __launch_bounds__(256) void hist_kernel(const int* __restrict__ ei,
                                                   int* __restrict__ cnt)
{
  const int e = blockIdx.x * 256 + threadIdx.x;
  atomicAdd(&cnt[ei[NE + e]], 1);
}

__global__ __launch_bounds__(1024) void scan_kernel(const int* __restrict__ cnt,
                                                    int* __restrict__ off,
                                                    float* __restrict__ z)
{
  __shared__ int part[1024];
  const int t = threadIdx.x;
  const int base = t * 16;
  int loc[16];
  int s = 0;
#pragma unroll
  for (int k = 0; k < 16; k++) { loc[k] = s; s += cnt[base + k]; }
  part[t] = s;
  __syncthreads();
  for (int d = 1; d < 1024; d <<= 1) {
    int v = (t >= d) ? part[t - d] : 0;
    __syncthreads();
    part[t] += v;
    __syncthreads();
  }
  int excl = (t == 0) ? 0 : part[t - 1];
#pragma unroll
  for (int k = 0; k < 16; k++) {
    off[base + k] = excl + loc[k];
    z[base + k] = 0.f;
  }
}

// ---------------------------------------------------------------------------
// edge_kernel (round-14 verified math): fused scatter + k_pass + V-radial.
// Round-15 change: rank-ordered payload packed into ONE 64B struct per edge
// (v0,v1 = hv fp16x16; v2 = sh float4; v3 = {src, dst, expv, pad}) so the
// random scatter costs exactly one 64B sector instead of five.
// ---------------------------------------------------------------------------
__global__ __launch_bounds__(256) void edge_kernel(
    const int*   __restrict__ ei,
    const float* __restrict__ elen,
    const float* __restrict__ esh,
    const float* __restrict__ emb,
    const float* __restrict__ w1k,    // fck_w1
    const float* __restrict__ w1v,    // fcv_w1
    const float* __restrict__ qq,
    int*   __restrict__ off,
    float4* __restrict__ edata,       // [NE][4] float4 (64B per edge, by rank)
    float* __restrict__ z,
    float* __restrict__ out)
{
  const int gid = blockIdx.x * 256 + threadIdx.x;
#pragma unroll
  for (int i = 0; i < 3; i++) {
    int idx = gid + i * NE;
    if (idx < NN * DIM) out[idx] = 0.f;
  }

  const int src = ei[gid];
  const int dst = ei[NE + gid];
  const int rk = atomicAdd(&off[dst], 1);

  float el[10];
  const float2* e2 = reinterpret_cast<const float2*>(emb + (size_t)gid * 10);
#pragma unroll
  for (int b = 0; b < 5; b++) { float2 t = e2[b]; el[2 * b] = t.x; el[2 * b + 1] = t.y; }

  // K-side radial h (round-9 verified math)
  float h[16];
#pragma unroll
  for (int j = 0; j < 16; j++) {
    float a = 0.f;
#pragma unroll
    for (int b = 0; b < 10; b++) a += el[b] * w1k[b * 16 + j];
    a *= INV_SQRT_NB;
    float sig = 1.0f / (1.0f + __expf(-a));
    h[j] = a * sig * H_SCALE;
  }

  float4 sh4 = reinterpret_cast<const float4*>(esh)[gid];
  const float4* q4 = reinterpret_cast<const float4*>(qq + (size_t)dst * 64);
  float s = 0.f;
#pragma unroll
  for (int r = 0; r < 16; r++) {
    float4 qv = q4[r];
    s += h[r] * (sh4.x * qv.x + sh4.y * qv.y + sh4.z * qv.z + sh4.w * qv.w);
  }

  float len = elen[gid];
  float x = 10.0f * (1.0f - len * (1.0f / 1.3f));
  float cut = (x > 0.f) ? __expf(-1.0f / x) : 0.f;
  float ev = cut * __expf(s);
  atomicAdd(&z[dst], ev);

  // V-side radial h (identical formula, fcv_w1), fp16
  f16x8 hv0, hv1;
#pragma unroll
  for (int j = 0; j < 16; j++) {
    float a = 0.f;
#pragma unroll
    for (int b = 0; b < 10; b++) a += el[b] * w1v[b * 16 + j];
    a *= INV_SQRT_NB;
    float sig = 1.0f / (1.0f + __expf(-a));
    _Float16 hh = (_Float16)(a * sig * H_SCALE);
    if (j < 8) hv0[j] = hh; else hv1[j - 8] = hh;
  }

  float4* ep = edata + (size_t)rk * 4;
  ep[0] = __builtin_bit_cast(float4, hv0);
  ep[1] = __builtin_bit_cast(float4, hv1);
  ep[2] = sh4;
  ep[3] = make_float4(__int_as_float(src), __int_as_float(dst), ev, 0.f);
}

// ---------------------------------------------------------------------------
// V-pass via fp16 MFMA (round-12 verified MFMA/epilogue/tail); staging reads
// the rank-ordered 64B edata struct sequentially. Only f[src] is a gather.
// ---------------------------------------------------------------------------
__global__ __launch_bounds__(256) void v_mfma_kernel(
    const float* __restrict__ f,
    const float4* __restrict__ edata,   // by rank, 4 float4 per edge
    const float* __restrict__ z,
    const unsigned short* __restrict__ Bt,
    float* __restrict__ fout)
{
  __shared__ float h_s[64][17];
  __shared__ __attribute__((aligned(16))) _Float16 feE[64][FEP];
  __shared__ float scal[64][5];
  __shared__ int   nid[64];
  __shared__ __attribute__((aligned(16))) unsigned short BtL[32][BKP];
  __shared__ float rows[64][41];
  __shared__ int seg_start[64], seg_len[64], seg_nid[64];
  __shared__ int nseg_s;

  const int tid  = threadIdx.x;
  const int base = blockIdx.x * 64;

  {
    const char* src = (const char*)Bt;
    char* dst = (char*)&BtL[0][0];
#pragma unroll
    for (int k = 0; k < 6; k++) {
      int off = (k * 256 + tid) * 16;
      gload_lds16(src + off, dst + off);
    }
    if (tid < 32) {
      int off = (1536 + tid) * 16;
      gload_lds16(src + off, dst + off);
    }
  }

  const int m = tid & 63;
  const int q = tid >> 6;
  const float4* ed = edata + (size_t)(base + m) * 4;

  if (q == 0) {
    float4 v3 = ed[3];
    float4 sh4 = ed[2];
    int dn = __float_as_int(v3.y);
    float zz = z[dn]; zz = (zz == 0.f) ? 1.f : zz;
    float ev = v3.z;
    float wgt = sqrtf(fmaxf(ev / zz, 0.f));
    scal[m][0] = sh4.x; scal[m][1] = sh4.y; scal[m][2] = sh4.z; scal[m][3] = sh4.w;
    scal[m][4] = wgt;
    nid[m] = dn;
  } else if (q == 3) {
    int sn = __float_as_int(ed[3].x);
    const float4* f4 = reinterpret_cast<const float4*>(f + (size_t)sn * DIM);
    float v[40];
#pragma unroll
    for (int i = 0; i < 10; i++) {
      float4 t = f4[i];
      v[4 * i] = t.x; v[4 * i + 1] = t.y; v[4 * i + 2] = t.z; v[4 * i + 3] = t.w;
    }
#pragma unroll
    for (int i = 0; i < 16; i++) feE[m][i] = (_Float16)v[i];
#pragma unroll
    for (int k = 0; k < 24; k++)
      feE[m][16 + (k % 3) * 8 + (k / 3)] = (_Float16)v[16 + k];
  } else if (q == 1) {
    f16x8 h0 = __builtin_bit_cast(f16x8, ed[0]);
    f16x8 h1 = __builtin_bit_cast(f16x8, ed[1]);
#pragma unroll
    for (int j = 0; j < 8; j++) {
      h_s[m][j]     = (float)h0[j];
      h_s[m][8 + j] = (float)h1[j];
    }
  }
  __syncthreads();

  const int w    = tid >> 6;
  const int l    = tid & 63;
  const int row  = l & 15;
  const int kb   = l >> 4;
  const int mrow = w * 16 + row;
  const int col  = l & 15;

  const int i0 = (kb & 1) * 8;
  f16x8 afs = *reinterpret_cast<const f16x8*>(&feE[mrow][i0]);
  f16x8 afv0 = *reinterpret_cast<const f16x8*>(&feE[mrow][16]);
  f16x8 afv1 = *reinterpret_cast<const f16x8*>(&feE[mrow][24]);
  f16x8 afv2 = *reinterpret_cast<const f16x8*>(&feE[mrow][32]);

  f32x4 pfs0 = {0.f, 0.f, 0.f, 0.f}, pfs1 = {0.f, 0.f, 0.f, 0.f};
  f32x4 pc0_0 = {0.f, 0.f, 0.f, 0.f}, pc0_1 = {0.f, 0.f, 0.f, 0.f}, pc0_2 = {0.f, 0.f, 0.f, 0.f};
  f32x4 pc1_0 = {0.f, 0.f, 0.f, 0.f}, pc1_1 = {0.f, 0.f, 0.f, 0.f}, pc1_2 = {0.f, 0.f, 0.f, 0.f};

#pragma unroll
  for (int s = 0; s < 8; s++) {
    const int r  = 2 * s + (kb >> 1);
    const _Float16 hr = (_Float16)h_s[mrow][r];
    f16x8 a;
#pragma unroll
    for (int j = 0; j < 8; j++) a[j] = hr * afs[j];
    const int k0 = s * 32 + kb * 8;
    f16x8 b0 = *reinterpret_cast<const f16x8*>(&BtL[col][k0]);
    f16x8 b1 = *reinterpret_cast<const f16x8*>(&BtL[16 + col][k0]);
    pfs0 = __builtin_amdgcn_mfma_f32_16x16x32_f16(a, b0, pfs0, 0, 0, 0);
    pfs1 = __builtin_amdgcn_mfma_f32_16x16x32_f16(a, b1, pfs1, 0, 0, 0);
  }

#pragma unroll
  for (int s = 0; s < 4; s++) {
    const int r = 4 * s + kb;
    const _Float16 hr = (_Float16)h_s[mrow][r];
    const int k0 = 256 + s * 32 + kb * 8;
    f16x8 b0 = *reinterpret_cast<const f16x8*>(&BtL[col][k0]);
    f16x8 b1 = *reinterpret_cast<const f16x8*>(&BtL[16 + col][k0]);
#pragma unroll
    for (int c = 0; c < 3; c++) {
      const f16x8 av = (c == 0) ? afv0 : (c == 1) ? afv1 : afv2;
      f16x8 a;
#pragma unroll
      for (int j = 0; j < 8; j++) a[j] = hr * av[j];
      f32x4* p0 = (c == 0) ? &pc0_0 : (c == 1) ? &pc0_1 : &pc0_2;
      f32x4* p1 = (c == 0) ? &pc1_0 : (c == 1) ? &pc1_1 : &pc1_2;
      *p0 = __builtin_amdgcn_mfma_f32_16x16x32_f16(a, b0, *p0, 0, 0, 0);
      *p1 = __builtin_amdgcn_mfma_f32_16x16x32_f16(a, b1, *p1, 0, 0, 0);
    }
  }

#pragma unroll
  for (int j = 0; j < 4; j++) {
    const int me = w * 16 + kb * 4 + j;
    const float sh0 = scal[me][0], sh1 = scal[me][1], sh2 = scal[me][2], sh3 = scal[me][3];
    const float wg = scal[me][4];
    float vsc = sh0 * pfs0[j] + sh1 * pc0_0[j] + sh2 * pc0_1[j] + sh3 * pc0_2[j];
    rows[me][col] = wg * vsc;
    if (col < 8) {
      rows[me][16 + col * 3 + 0] = wg * (sh1 * pfs1[j] + sh0 * pc1_0[j]);
      rows[me][16 + col * 3 + 1] = wg * (sh2 * pfs1[j] + sh0 * pc1_1[j]);
      rows[me][16 + col * 3 + 2] = wg * (sh3 * pfs1[j] + sh0 * pc1_2[j]);
    }
  }
  __syncthreads();

  if (tid < 64) {
    bool head = (m == 0) || (nid[m] != nid[m - 1]);
    unsigned long long mask = __ballot(head);
    if (tid == 0) nseg_s = __popcll(mask);
    if (head) {
      int idx = __popcll(mask & ((1ull << m) - 1ull));
      unsigned long long higher = (m == 63) ? 0ull : (mask >> (m + 1));
      int len = higher ? __ffsll((long long)higher) : (64 - m);
      seg_start[idx] = m; seg_len[idx] = len; seg_nid[idx] = nid[m];
    }
  }
  __syncthreads();

  const int nseg = nseg_s;
  const int d = tid & 63;
  const int g = tid >> 6;
  if (d < DIM) {
    for (int s = g; s < nseg; s += 4) {
      const int st = seg_start[s], ln = seg_len[s];
      float acc = 0.f;
      for (int k2 = 0; k2 < ln; k2++) acc += rows[st + k2][d];
      float* fo = &fout[(size_t)seg_nid[s] * DIM + d];
      if (s > 0 && s < nseg - 1) *fo = acc;
      else atomicAdd(fo, acc);
    }
  }
}

extern "C" void kernel_launch(void* const* d_in, const int* in_sizes, int n_in,
                              void* d_out, int out_size, void* d_ws, size_t ws_size,
                              hipStream_t stream) {
  const float* f      = (const float*)d_in[0];
  const int*   ei     = (const int*)d_in[1];
  const float* elen   = (const float*)d_in[2];
  const float* esh    = (const float*)d_in[3];
  const float* emb    = (const float*)d_in[4];
  const float* Wq0    = (const float*)d_in[5];
  const float* Wq1    = (const float*)d_in[6];
  const float* fck_w1 = (const float*)d_in[7];
  const float* fck_w2 = (const float*)d_in[8];
  const float* fcv_w1 = (const float*)d_in[9];
  const float* fcv_w2 = (const float*)d_in[10];
  const float* Wd00   = (const float*)d_in[11];
  const float* Wd11   = (const float*)d_in[12];

  float* out = (float*)d_out;

  char* ws = (char*)d_ws;
  float* qq       = (float*)ws;  ws += (size_t)NN * 64 * 4;
  float* qd       = (float*)ws;  ws += (size_t)NN * DIM * 4;
  float* z        = (float*)ws;  ws += (size_t)NN * 4;
  int*   cnt      = (int*)ws;    ws += (size_t)NN * 4;
  int*   off      = (int*)ws;    ws += (size_t)NN * 4;
  ws = (char*)(((size_t)ws + 63) & ~(size_t)63);
  float4* edata   = (float4*)ws; ws += (size_t)NE * 64;      // 16.8 MB
  unsigned short* Btv = (unsigned short*)ws;  ws += (size_t)32 * BKP * 2;
  unsigned short* Btk = (unsigned short*)ws;  ws += (size_t)BKTOT * 2;

  prep_kernel<<<PREP_NODE_BLKS + PREP_BV_BLKS + PREP_BK_BLKS, 256, 0, stream>>>(
      f, Wq0, Wq1, Wd00, Wd11, fcv_w2, fck_w2, qd, Btv, Btk, cnt);
  hist_kernel<<<NE / 256, 256, 0, stream>>>(ei, cnt);
  scan_kernel<<<1, 1024, 0, stream>>>(cnt, off, z);
  qq_mfma_kernel<<<NN / 64, 256, 0, stream>>>(f, qd, Btk, qq);
  edge_kernel<<<NE / 256, 256, 0, stream>>>(ei, elen, esh, emb, fck_w1, fcv_w1,
                                            qq, off, edata, z, out);
  v_mfma_kernel<<<NE / 64, 256, 0, stream>>>(f, edata, z, Btv, out);
}

// Round 16
// 100.343 us; speedup vs baseline: 3.7114x; 1.0102x over previous
//
#include <hip/hip_runtime.h>
#include <hip/hip_bf16.h>
#include <math.h>

namespace {
constexpr int NN  = 16384;
constexpr int NE  = 262144;
constexpr int DIM = 40;

constexpr float INV_SQRT3   = 0.5773502691896258f;
constexpr float A_PATH      = 0.2041241452319315f;      // 1/sqrt(24)
constexpr float INV_SQRT_NB = 0.31622776601683794f;     // 1/sqrt(10)
constexpr float H_SCALE     = 0.25f;                    // 1/sqrt(16)
constexpr float QSC_S       = 0.25f;
constexpr float QV_S        = 0.35355339059327373f;
constexpr float D00_S       = 1.0f / (16.0f * 1.4142135623730951f);
constexpr float D11_S       = 1.0f / (8.0f * 1.7320508075688772f * 1.4142135623730951f);

constexpr int BKP = 392;   // v_mfma B k-stride (fp16)
constexpr int K0P = 328;   // qq-GEMM path0 k-stride
constexpr int KCP = 264;   // qq-GEMM pathC k-stride
constexpr int BKTOT = 16 * K0P + 16 * KCP;   // 9472 shorts
constexpr int FEP = 40;    // feE padded row (fp16)

constexpr int PREP_NODE_BLKS = NN / 256;                 // 64
constexpr int PREP_BV_BLKS   = 32 * BKP / 256;           // 49
constexpr int PREP_BK_BLKS   = BKTOT / 256;              // 37
}

typedef __attribute__((ext_vector_type(8))) _Float16 f16x8;
typedef __attribute__((ext_vector_type(4))) float f32x4;

static __device__ __forceinline__ void gload_lds16(const void* g, void* l) {
  __builtin_amdgcn_global_load_lds(
      (const __attribute__((address_space(1))) unsigned*)g,
      (__attribute__((address_space(3))) unsigned*)l, 16, 0, 0);
}

// ---------------------------------------------------------------------------
// prep_kernel (round-13 verified): node_qd + cnt zero | prep_Btv | prep_Btk
// ---------------------------------------------------------------------------
__global__ __launch_bounds__(256) void prep_kernel(
    const float* __restrict__ f,
    const float* __restrict__ Wq0, const float* __restrict__ Wq1,
    const float* __restrict__ Wd00, const float* __restrict__ Wd11,
    const float* __restrict__ w2v,   // fcv_w2
    const float* __restrict__ w2k,   // fck_w2
    float* __restrict__ qd,
    unsigned short* __restrict__ Btv,
    unsigned short* __restrict__ Btk,
    int* __restrict__ cnt)
{
  const int blk = blockIdx.x;
  if (blk < PREP_NODE_BLKS) {
    const int n = blk * 256 + threadIdx.x;
    cnt[n] = 0;

    float fs[16], fv[8][3];
    {
      const float4* fn4 = reinterpret_cast<const float4*>(f + (size_t)n * DIM);
#pragma unroll
      for (int i = 0; i < 10; i++) {
        float4 t = fn4[i];
        int base = i * 4;
#pragma unroll
        for (int k = 0; k < 4; k++) {
          float v = (k == 0) ? t.x : (k == 1) ? t.y : (k == 2) ? t.z : t.w;
          int idx = base + k;
          if (idx < 16) fs[idx] = v;
          else { int r = idx - 16; fv[r / 3][r % 3] = v; }
        }
      }
    }

    float out[40];
    {
      float qsc[16];
#pragma unroll
      for (int o = 0; o < 16; o++) {
        float a = 0.f;
#pragma unroll
        for (int i = 0; i < 16; i++) a += fs[i] * Wq0[i * 16 + o];
        qsc[o] = a * QSC_S;
      }
#pragma unroll
      for (int j = 0; j < 16; j++) {
        float a = 0.f;
#pragma unroll
        for (int i = 0; i < 16; i++) a += qsc[i] * Wd00[i * 16 + j];
        out[j] = a * D00_S;
      }
    }
    {
      float qv[8][3];
#pragma unroll
      for (int o = 0; o < 8; o++)
#pragma unroll
        for (int c = 0; c < 3; c++) {
          float a = 0.f;
#pragma unroll
          for (int i = 0; i < 8; i++) a += fv[i][c] * Wq1[i * 8 + o];
          qv[o][c] = a * QV_S;
        }
#pragma unroll
      for (int j = 0; j < 8; j++)
#pragma unroll
        for (int c = 0; c < 3; c++) {
          float a = 0.f;
#pragma unroll
          for (int i = 0; i < 8; i++) a += qv[i][c] * Wd11[i * 8 + j];
          out[16 + j * 3 + c] = a * D11_S;
        }
    }

    float4* op = reinterpret_cast<float4*>(qd + (size_t)n * DIM);
#pragma unroll
    for (int i = 0; i < 10; i++)
      op[i] = make_float4(out[4 * i], out[4 * i + 1], out[4 * i + 2], out[4 * i + 3]);

  } else if (blk < PREP_NODE_BLKS + PREP_BV_BLKS) {
    int t = (blk - PREP_NODE_BLKS) * 256 + threadIdx.x;
    int col = t / BKP, kp = t % BKP;
    float val = 0.f;
    if (kp < 384 && col < 24) {
      if (kp < 256) {
        int r = kp >> 4, i = kp & 15;
        if (col < 16) val = A_PATH * w2v[r * 576 + i * 16 + col];
        else          val = A_PATH * w2v[r * 576 + 384 + i * 8 + (col - 16)];
      } else {
        int k2 = kp - 256; int r = k2 >> 3, i = k2 & 7;
        if (col < 16) val = A_PATH * INV_SQRT3 * w2v[r * 576 + 256 + i * 16 + col];
        else          val = A_PATH * w2v[r * 576 + 512 + i * 8 + (col - 16)];
      }
    }
    _Float16 hv = (_Float16)val;
    Btv[t] = __builtin_bit_cast(unsigned short, hv);

  } else {
    int t = (blk - PREP_NODE_BLKS - PREP_BV_BLKS) * 256 + threadIdx.x;
    float val = 0.f;
    if (t < 16 * K0P) {
      int r = t / K0P, k = t % K0P;
      if (k < 256)      { int i = k >> 4, o = k & 15; val = w2k[r * 576 + i * 16 + o]; }
      else if (k < 320) { int kk = k - 256; int i = kk >> 3, o = kk & 7;
                          val = w2k[r * 576 + 512 + i * 8 + o]; }
    } else {
      int t2 = t - 16 * K0P;
      int r = t2 / KCP, k = t2 % KCP;
      if (k < 128)      { int i = k >> 4, o = k & 15;
                          val = INV_SQRT3 * w2k[r * 576 + 256 + i * 16 + o]; }
      else if (k < 256) { int kk = k - 128; int i = kk >> 3, o = kk & 7;
                          val = w2k[r * 576 + 384 + i * 8 + o]; }
    }
    _Float16 hv = (_Float16)val;
    Btk[t] = __builtin_bit_cast(unsigned short, hv);
  }
}

// ---------------------------------------------------------------------------
// qq via MFMA (round-11 verified, unchanged)
// ---------------------------------------------------------------------------
__global__ __launch_bounds__(256) void qq_mfma_kernel(
    const float* __restrict__ f,
    const float* __restrict__ qd,
    const unsigned short* __restrict__ Btk,
    float* __restrict__ qq)
{
  __shared__ __attribute__((aligned(16))) unsigned short BL[BKTOT];
  __shared__ float fsT[16][65];
  __shared__ float fvT[24][65];
  __shared__ float qd0T[16][65];
  __shared__ float qdvT[24][65];

  const int tid  = threadIdx.x;
  const int base = blockIdx.x * 64;

  {
    const char* src = (const char*)Btk;
    char* dst = (char*)BL;
#pragma unroll
    for (int k2 = 0; k2 < 4; k2++) {
      int off = (k2 * 256 + tid) * 16;
      gload_lds16(src + off, dst + off);
    }
    if (tid < 160) {
      int off = (1024 + tid) * 16;
      gload_lds16(src + off, dst + off);
    }
  }

  const int m = tid & 63;
  const int q = tid >> 6;
  const int n = base + m;

  if (q == 0) {
    const float4* f4 = reinterpret_cast<const float4*>(f + (size_t)n * DIM);
    float v[40];
#pragma unroll
    for (int i = 0; i < 10; i++) {
      float4 t = f4[i];
      v[4 * i] = t.x; v[4 * i + 1] = t.y; v[4 * i + 2] = t.z; v[4 * i + 3] = t.w;
    }
#pragma unroll
    for (int i = 0; i < 16; i++) fsT[i][m] = v[i];
#pragma unroll
    for (int k = 0; k < 24; k++) fvT[(k % 3) * 8 + (k / 3)][m] = v[16 + k];
  } else if (q == 1) {
    const float4* q4 = reinterpret_cast<const float4*>(qd + (size_t)n * DIM);
    float v[40];
#pragma unroll
    for (int i = 0; i < 10; i++) {
      float4 t = q4[i];
      v[4 * i] = t.x; v[4 * i + 1] = t.y; v[4 * i + 2] = t.z; v[4 * i + 3] = t.w;
    }
#pragma unroll
    for (int i = 0; i < 16; i++) qd0T[i][m] = v[i];
#pragma unroll
    for (int k = 0; k < 24; k++) qdvT[(k % 3) * 8 + (k / 3)][m] = v[16 + k];
  }
  __syncthreads();

  const int w    = tid >> 6;
  const int l    = tid & 63;
  const int row  = l & 15;
  const int kb   = l >> 4;
  const int mrow = w * 16 + row;
  const int col  = l & 15;

  f32x4 p0  = {0.f, 0.f, 0.f, 0.f};
  f32x4 pcA = {0.f, 0.f, 0.f, 0.f}, pcB = {0.f, 0.f, 0.f, 0.f}, pcC = {0.f, 0.f, 0.f, 0.f};

#pragma unroll
  for (int s = 0; s < 10; s++) {
    f16x8 a;
    if (s < 8) {
      const int i  = 2 * s + (kb >> 1);
      const int o0 = (kb & 1) * 8;
      const float fsv = fsT[i][mrow];
#pragma unroll
      for (int j = 0; j < 8; j++) a[j] = (_Float16)(fsv * qd0T[o0 + j][mrow]);
    } else {
      const int i = (s - 8) * 4 + kb;
      const float fv0 = fvT[i][mrow], fv1 = fvT[8 + i][mrow], fv2 = fvT[16 + i][mrow];
#pragma unroll
      for (int j = 0; j < 8; j++)
        a[j] = (_Float16)(fv0 * qdvT[j][mrow] + fv1 * qdvT[8 + j][mrow]
                          + fv2 * qdvT[16 + j][mrow]);
    }
    const int k0 = s * 32 + kb * 8;
    f16x8 b = *reinterpret_cast<const f16x8*>(&BL[col * K0P + k0]);
    p0 = __builtin_amdgcn_mfma_f32_16x16x32_f16(a, b, p0, 0, 0, 0);
  }

#pragma unroll
  for (int c = 0; c < 3; c++) {
    f32x4* pc = (c == 0) ? &pcA : (c == 1) ? &pcB : &pcC;
#pragma unroll
    for (int s = 0; s < 8; s++) {
      f16x8 a;
      if (s < 4) {
        const int i  = 2 * s + (kb >> 1);
        const int o0 = (kb & 1) * 8;
        const float fvv = fvT[c * 8 + i][mrow];
#pragma unroll
        for (int j = 0; j < 8; j++) a[j] = (_Float16)(fvv * qd0T[o0 + j][mrow]);
      } else {
        const int i = (s - 4) * 4 + kb;
        const float fsv = fsT[i][mrow];
#pragma unroll
        for (int j = 0; j < 8; j++) a[j] = (_Float16)(fsv * qdvT[c * 8 + j][mrow]);
      }
      const int k0 = s * 32 + kb * 8;
      f16x8 b = *reinterpret_cast<const f16x8*>(&BL[16 * K0P + col * KCP + k0]);
      *pc = __builtin_amdgcn_mfma_f32_16x16x32_f16(a, b, *pc, 0, 0, 0);
    }
  }

#pragma unroll
  for (int j = 0; j < 4; j++) {
    const int me = w * 16 + kb * 4 + j;
    float4 outv = make_float4(A_PATH * p0[j], A_PATH * pcA[j],
                              A_PATH * pcB[j], A_PATH * pcC[j]);
    reinterpret_cast<float4*>(qq)[(size_t)(base + me) * 16 + col] = outv;
  }
}

// ---------------------------------------------------------------------------
// hist (now also zeroes out) + scan (zeroes z)
// ---------------------------------------------------------------------------
__global__ __launch_bounds__(256) void hist_kernel(const int* __restrict__ ei,
                                                   int* __restrict__ cnt,
                                                   float* __restrict__ out)
{
  const int e = blockIdx.x * 256 + threadIdx.x;
#pragma unroll
  for (int i = 0; i < 3; i++) {
    int idx = e + i * NE;
    if (idx < NN * DIM) out[idx] = 0.f;
  }
  atomicAdd(&cnt[ei[NE + e]], 1);
}

__global__ __launch_bounds__(1024) void scan_kernel(const int* __restrict__ cnt,
                                                    int* __restrict__ off,
                                                    float* __restrict__ z)
{
  __shared__ int part[1024];
  const int t = threadIdx.x;
  const int base = t * 16;
  int loc[16];
  int s = 0;
#pragma unroll
  for (int k = 0; k < 16; k++) { loc[k] = s; s += cnt[base + k]; }
  part[t] = s;
  __syncthreads();
  for (int d = 1; d < 1024; d <<= 1) {
    int v = (t >= d) ? part[t - d] : 0;
    __syncthreads();
    part[t] += v;
    __syncthreads();
  }
  int excl = (t == 0) ? 0 : part[t - 1];
#pragma unroll
  for (int k = 0; k < 16; k++) {
    off[base + k] = excl + loc[k];
    z[base + k] = 0.f;
  }
}

// ---------------------------------------------------------------------------
// edge_kernel (round-15 verified; out-zeroing moved to hist)
// ---------------------------------------------------------------------------
__global__ __launch_bounds__(256) void edge_kernel(
    const int*   __restrict__ ei,
    const float* __restrict__ elen,
    const float* __restrict__ esh,
    const float* __restrict__ emb,
    const float* __restrict__ w1k,    // fck_w1
    const float* __restrict__ w1v,    // fcv_w1
    const float* __restrict__ qq,
    int*   __restrict__ off,
    float4* __restrict__ edata,       // [NE][4] float4 (64B per edge, by rank)
    float* __restrict__ z)
{
  const int gid = blockIdx.x * 256 + threadIdx.x;

  const int src = ei[gid];
  const int dst = ei[NE + gid];
  const int rk = atomicAdd(&off[dst], 1);

  float el[10];
  const float2* e2 = reinterpret_cast<const float2*>(emb + (size_t)gid * 10);
#pragma unroll
  for (int b = 0; b < 5; b++) { float2 t = e2[b]; el[2 * b] = t.x; el[2 * b + 1] = t.y; }

  // K-side radial h (round-9 verified math)
  float h[16];
#pragma unroll
  for (int j = 0; j < 16; j++) {
    float a = 0.f;
#pragma unroll
    for (int b = 0; b < 10; b++) a += el[b] * w1k[b * 16 + j];
    a *= INV_SQRT_NB;
    float sig = 1.0f / (1.0f + __expf(-a));
    h[j] = a * sig * H_SCALE;
  }

  float4 sh4 = reinterpret_cast<const float4*>(esh)[gid];
  const float4* q4 = reinterpret_cast<const float4*>(qq + (size_t)dst * 64);
  float s = 0.f;
#pragma unroll
  for (int r = 0; r < 16; r++) {
    float4 qv = q4[r];
    s += h[r] * (sh4.x * qv.x + sh4.y * qv.y + sh4.z * qv.z + sh4.w * qv.w);
  }

  float len = elen[gid];
  float x = 10.0f * (1.0f - len * (1.0f / 1.3f));
  float cut = (x > 0.f) ? __expf(-1.0f / x) : 0.f;
  float ev = cut * __expf(s);
  atomicAdd(&z[dst], ev);

  // V-side radial h (identical formula, fcv_w1), fp16
  f16x8 hv0, hv1;
#pragma unroll
  for (int j = 0; j < 16; j++) {
    float a = 0.f;
#pragma unroll
    for (int b = 0; b < 10; b++) a += el[b] * w1v[b * 16 + j];
    a *= INV_SQRT_NB;
    float sig = 1.0f / (1.0f + __expf(-a));
    _Float16 hh = (_Float16)(a * sig * H_SCALE);
    if (j < 8) hv0[j] = hh; else hv1[j - 8] = hh;
  }

  float4* ep = edata + (size_t)rk * 4;
  ep[0] = __builtin_bit_cast(float4, hv0);
  ep[1] = __builtin_bit_cast(float4, hv1);
  ep[2] = sh4;
  ep[3] = make_float4(__int_as_float(src), __int_as_float(dst), ev, 0.f);
}

// ---------------------------------------------------------------------------
// V-pass via fp16 MFMA. Round-16 change: 128 edges/block (512 threads,
// 8 waves) as two independent 64-edge halves sharing one BtL stage.
// Per-half logic byte-identical to round-15 (half h's tid<64 group is
// exactly wave 4h, preserving ballot semantics). h_s now fp16 (values are
// already fp16 from edata — lossless).
// ---------------------------------------------------------------------------
__global__ __launch_bounds__(512) void v_mfma_kernel(
    const float* __restrict__ f,
    const float4* __restrict__ edata,   // by rank, 4 float4 per edge
    const float* __restrict__ z,
    const unsigned short* __restrict__ Bt,
    float* __restrict__ fout)
{
  __shared__ __attribute__((aligned(16))) unsigned short BtL[32][BKP];  // 25088
  __shared__ __attribute__((aligned(16))) _Float16 h_s[2][64][18];      // 4608
  __shared__ __attribute__((aligned(16))) _Float16 feE[2][64][FEP];     // 10240
  __shared__ float scal[2][64][5];                                      // 2560
  __shared__ int   nid[2][64];                                          // 512
  __shared__ float rows[2][64][41];                                     // 20992
  __shared__ int seg_start[2][64], seg_len[2][64], seg_nid[2][64];      // 1536
  __shared__ int nseg_s[2];

  const int tid = threadIdx.x;

  // stage Bt once for both halves (25088 B = 1568 x16B; 512*3=1536 + 32)
  {
    const char* src = (const char*)Bt;
    char* dst = (char*)&BtL[0][0];
#pragma unroll
    for (int k = 0; k < 3; k++) {
      int off = (k * 512 + tid) * 16;
      gload_lds16(src + off, dst + off);
    }
    if (tid < 32) {
      int off = (1536 + tid) * 16;
      gload_lds16(src + off, dst + off);
    }
  }

  const int hf  = tid >> 8;          // half 0/1
  const int t2  = tid & 255;
  const int m   = t2 & 63;
  const int q   = t2 >> 6;
  const int base = blockIdx.x * 128 + hf * 64;
  const float4* ed = edata + (size_t)(base + m) * 4;

  if (q == 0) {
    float4 v3 = ed[3];
    float4 sh4 = ed[2];
    int dn = __float_as_int(v3.y);
    float zz = z[dn]; zz = (zz == 0.f) ? 1.f : zz;
    float ev = v3.z;
    float wgt = sqrtf(fmaxf(ev / zz, 0.f));
    scal[hf][m][0] = sh4.x; scal[hf][m][1] = sh4.y;
    scal[hf][m][2] = sh4.z; scal[hf][m][3] = sh4.w;
    scal[hf][m][4] = wgt;
    nid[hf][m] = dn;
  } else if (q == 3) {
    int sn = __float_as_int(ed[3].x);
    const float4* f4 = reinterpret_cast<const float4*>(f + (size_t)sn * DIM);
    float v[40];
#pragma unroll
    for (int i = 0; i < 10; i++) {
      float4 t = f4[i];
      v[4 * i] = t.x; v[4 * i + 1] = t.y; v[4 * i + 2] = t.z; v[4 * i + 3] = t.w;
    }
#pragma unroll
    for (int i = 0; i < 16; i++) feE[hf][m][i] = (_Float16)v[i];
#pragma unroll
    for (int k = 0; k < 24; k++)
      feE[hf][m][16 + (k % 3) * 8 + (k / 3)] = (_Float16)v[16 + k];
  } else if (q == 1) {
    f16x8 h0 = __builtin_bit_cast(f16x8, ed[0]);
    f16x8 h1 = __builtin_bit_cast(f16x8, ed[1]);
#pragma unroll
    for (int j = 0; j < 8; j++) {
      h_s[hf][m][j]     = h0[j];
      h_s[hf][m][8 + j] = h1[j];
    }
  }
  __syncthreads();

  const int w    = t2 >> 6;
  const int l    = t2 & 63;
  const int row  = l & 15;
  const int kb   = l >> 4;
  const int mrow = w * 16 + row;
  const int col  = l & 15;

  const int i0 = (kb & 1) * 8;
  f16x8 afs = *reinterpret_cast<const f16x8*>(&feE[hf][mrow][i0]);
  f16x8 afv0 = *reinterpret_cast<const f16x8*>(&feE[hf][mrow][16]);
  f16x8 afv1 = *reinterpret_cast<const f16x8*>(&feE[hf][mrow][24]);
  f16x8 afv2 = *reinterpret_cast<const f16x8*>(&feE[hf][mrow][32]);

  f32x4 pfs0 = {0.f, 0.f, 0.f, 0.f}, pfs1 = {0.f, 0.f, 0.f, 0.f};
  f32x4 pc0_0 = {0.f, 0.f, 0.f, 0.f}, pc0_1 = {0.f, 0.f, 0.f, 0.f}, pc0_2 = {0.f, 0.f, 0.f, 0.f};
  f32x4 pc1_0 = {0.f, 0.f, 0.f, 0.f}, pc1_1 = {0.f, 0.f, 0.f, 0.f}, pc1_2 = {0.f, 0.f, 0.f, 0.f};

  // fs path: K=256, 8 K-steps. k = s*32 + kb*8 + j; r = k>>4, i = k&15.
#pragma unroll
  for (int s = 0; s < 8; s++) {
    const int r  = 2 * s + (kb >> 1);
    const _Float16 hr = h_s[hf][mrow][r];
    f16x8 a;
#pragma unroll
    for (int j = 0; j < 8; j++) a[j] = hr * afs[j];
    const int k0 = s * 32 + kb * 8;
    f16x8 b0 = *reinterpret_cast<const f16x8*>(&BtL[col][k0]);
    f16x8 b1 = *reinterpret_cast<const f16x8*>(&BtL[16 + col][k0]);
    pfs0 = __builtin_amdgcn_mfma_f32_16x16x32_f16(a, b0, pfs0, 0, 0, 0);
    pfs1 = __builtin_amdgcn_mfma_f32_16x16x32_f16(a, b1, pfs1, 0, 0, 0);
  }

  // fv path: K=128 per c, 4 K-steps; r = 4s+kb.
#pragma unroll
  for (int s = 0; s < 4; s++) {
    const int r = 4 * s + kb;
    const _Float16 hr = h_s[hf][mrow][r];
    const int k0 = 256 + s * 32 + kb * 8;
    f16x8 b0 = *reinterpret_cast<const f16x8*>(&BtL[col][k0]);
    f16x8 b1 = *reinterpret_cast<const f16x8*>(&BtL[16 + col][k0]);
#pragma unroll
    for (int c = 0; c < 3; c++) {
      const f16x8 av = (c == 0) ? afv0 : (c == 1) ? afv1 : afv2;
      f16x8 a;
#pragma unroll
      for (int j = 0; j < 8; j++) a[j] = hr * av[j];
      f32x4* p0 = (c == 0) ? &pc0_0 : (c == 1) ? &pc0_1 : &pc0_2;
      f32x4* p1 = (c == 0) ? &pc1_0 : (c == 1) ? &pc1_1 : &pc1_2;
      *p0 = __builtin_amdgcn_mfma_f32_16x16x32_f16(a, b0, *p0, 0, 0, 0);
      *p1 = __builtin_amdgcn_mfma_f32_16x16x32_f16(a, b1, *p1, 0, 0, 0);
    }
  }

  // ---- epilogue: combine with per-edge sh scalars, weighted rows -> LDS ----
#pragma unroll
  for (int j = 0; j < 4; j++) {
    const int me = w * 16 + kb * 4 + j;          // D row = (l>>4)*4 + reg
    const float sh0 = scal[hf][me][0], sh1 = scal[hf][me][1];
    const float sh2 = scal[hf][me][2], sh3 = scal[hf][me][3];
    const float wg = scal[hf][me][4];
    float vsc = sh0 * pfs0[j] + sh1 * pc0_0[j] + sh2 * pc0_1[j] + sh3 * pc0_2[j];
    rows[hf][me][col] = wg * vsc;
    if (col < 8) {
      rows[hf][me][16 + col * 3 + 0] = wg * (sh1 * pfs1[j] + sh0 * pc1_0[j]);
      rows[hf][me][16 + col * 3 + 1] = wg * (sh2 * pfs1[j] + sh0 * pc1_1[j]);
      rows[hf][me][16 + col * 3 + 2] = wg * (sh3 * pfs1[j] + sh0 * pc1_2[j]);
    }
  }
  __syncthreads();

  // ---- per-half segmented reduction over sorted dst ----
  if (t2 < 64) {   // exactly wave (4*hf): full-wave ballot within the half
    bool head = (m == 0) || (nid[hf][m] != nid[hf][m - 1]);
    unsigned long long mask = __ballot(head);
    if (t2 == 0) nseg_s[hf] = __popcll(mask);
    if (head) {
      int idx = __popcll(mask & ((1ull << m) - 1ull));
      unsigned long long higher = (m == 63) ? 0ull : (mask >> (m + 1));
      int len = higher ? __ffsll((long long)higher) : (64 - m);
      seg_start[hf][idx] = m; seg_len[hf][idx] = len; seg_nid[hf][idx] = nid[hf][m];
    }
  }
  __syncthreads();

  const int nseg = nseg_s[hf];
  const int d = t2 & 63;
  const int g = t2 >> 6;
  if (d < DIM) {
    for (int s = g; s < nseg; s += 4) {
      const int st = seg_start[hf][s], ln = seg_len[hf][s];
      float acc = 0.f;
      for (int k2 = 0; k2 < ln; k2++) acc += rows[hf][st + k2][d];
      float* fo = &fout[(size_t)seg_nid[hf][s] * DIM + d];
      if (s > 0 && s < nseg - 1) *fo = acc;   // node fully inside this half
      else atomicAdd(fo, acc);                // may span half/block boundary
    }
  }
}

extern "C" void kernel_launch(void* const* d_in, const int* in_sizes, int n_in,
                              void* d_out, int out_size, void* d_ws, size_t ws_size,
                              hipStream_t stream) {
  const float* f      = (const float*)d_in[0];
  const int*   ei     = (const int*)d_in[1];
  const float* elen   = (const float*)d_in[2];
  const float* esh    = (const float*)d_in[3];
  const float* emb    = (const float*)d_in[4];
  const float* Wq0    = (const float*)d_in[5];
  const float* Wq1    = (const float*)d_in[6];
  const float* fck_w1 = (const float*)d_in[7];
  const float* fck_w2 = (const float*)d_in[8];
  const float* fcv_w1 = (const float*)d_in[9];
  const float* fcv_w2 = (const float*)d_in[10];
  const float* Wd00   = (const float*)d_in[11];
  const float* Wd11   = (const float*)d_in[12];

  float* out = (float*)d_out;

  char* ws = (char*)d_ws;
  float* qq       = (float*)ws;  ws += (size_t)NN * 64 * 4;
  float* qd       = (float*)ws;  ws += (size_t)NN * DIM * 4;
  float* z        = (float*)ws;  ws += (size_t)NN * 4;
  int*   cnt      = (int*)ws;    ws += (size_t)NN * 4;
  int*   off      = (int*)ws;    ws += (size_t)NN * 4;
  ws = (char*)(((size_t)ws + 63) & ~(size_t)63);
  float4* edata   = (float4*)ws; ws += (size_t)NE * 64;      // 16.8 MB
  unsigned short* Btv = (unsigned short*)ws;  ws += (size_t)32 * BKP * 2;
  unsigned short* Btk = (unsigned short*)ws;  ws += (size_t)BKTOT * 2;

  prep_kernel<<<PREP_NODE_BLKS + PREP_BV_BLKS + PREP_BK_BLKS, 256, 0, stream>>>(
      f, Wq0, Wq1, Wd00, Wd11, fcv_w2, fck_w2, qd, Btv, Btk, cnt);
  hist_kernel<<<NE / 256, 256, 0, stream>>>(ei, cnt, out);
  scan_kernel<<<1, 1024, 0, stream>>>(cnt, off, z);
  qq_mfma_kernel<<<NN / 64, 256, 0, stream>>>(f, qd, Btk, qq);
  edge_kernel<<<NE / 256, 256, 0, stream>>>(ei, elen, esh, emb, fck_w1, fcv_w1,
                                            qq, off, edata, z);
  v_mfma_kernel<<<NE / 128, 512, 0, stream>>>(f, edata, z, Btv, out);
}